// Round 6
// baseline (332.508 us; speedup 1.0000x reference)
//
#include <hip/hip_runtime.h>
#include <hip/hip_bf16.h>

#define NN 50000
#define EE 400000
#define EP 450000   // EE + NN self-loops

typedef __attribute__((ext_vector_type(8))) short short8;
typedef __attribute__((ext_vector_type(4))) float f32x4;

__device__ __forceinline__ float us2f(unsigned short u) {
    unsigned int x = ((unsigned int)u) << 16;
    union { unsigned int i; float f; } c; c.i = x; return c.f;
}
__device__ __forceinline__ unsigned short f2bfu(float f) {   // f32 -> bf16 bits, RNE
    union { float f; unsigned int u; } c; c.f = f;
    unsigned int r = c.u + 0x7FFFu + ((c.u >> 16) & 1u);
    return (unsigned short)(r >> 16);
}
__device__ __forceinline__ float lrelu_exp(float x) {
    x = x > 0.f ? x : 0.2f * x;
    return __expf(x);
}

// Packed MFMA-fragment index for a [M x K] bf16 matrix consumed as A (or B with
// n in place of m) by mfma_f32_16x16x32_bf16:
//   idx(m,k) = ((m>>4)*(K/32) + (k>>5))*512 + ((k&31)>>3)*128 + (m&15)*8 + (k&7)

// ---------------------------------------------------------------------------
// prep: fused deg histogram + W1/W2 f32->bf16 packed convert + usd precompute.
// Block ranges: [0,1758) deg, [1758,2270) cvt, [2270,2274) usd.
// ---------------------------------------------------------------------------
#define DEGB 1758
#define CVTB 512
__global__ void prep_kernel(const int* __restrict__ ei, int* __restrict__ deg,
                            const float* __restrict__ W1, const float* __restrict__ W2,
                            __hip_bfloat16* __restrict__ pw1, __hip_bfloat16* __restrict__ pw2,
                            const float* __restrict__ a1s, const float* __restrict__ a1d,
                            float* __restrict__ usd) {
    int b = blockIdx.x;
    if (b < DEGB) {
        int e = b * 256 + threadIdx.x;
        if (e >= EP) return;
        int dst = (e < EE) ? ei[EE + e] : e - EE;
        atomicAdd(&deg[dst], 1);
    } else if (b < DEGB + CVTB) {
        int i = (b - DEGB) * 256 + threadIdx.x;
        if (i < 65536) {
            int n = i >> 7, k = i & 127;   // K=128, NK=4
            int idx = ((n >> 4) * 4 + (k >> 5)) * 512 + ((k & 31) >> 3) * 128 + (n & 15) * 8 + (k & 7);
            pw1[idx] = __float2bfloat16(W1[i]);
        } else {
            int j = i - 65536;
            int n = j >> 9, k = j & 511;   // K=512, NK=16
            int idx = ((n >> 4) * 16 + (k >> 5)) * 512 + ((k & 31) >> 3) * 128 + (n & 15) * 8 + (k & 7);
            pw2[idx] = __float2bfloat16(W2[j]);
        }
    } else {
        int t = (b - DEGB - CVTB) * 256 + threadIdx.x;
        if (t >= 1024) return;
        int row = t >> 7, k = t & 127;
        int hh = row & 3;
        const float* av = (row < 4) ? (a1s + hh * 128) : (a1d + hh * 128);
        const float* wp = W1 + (size_t)(hh * 128) * 128 + k;
        float acc = 0.f;
        for (int c = 0; c < 128; c++) acc += av[c] * wp[(size_t)c * 128];
        usd[t] = acc;
    }
}

// ---------------------------------------------------------------------------
// Fused: x (f32) -> xb (bf16) convert + s1/d1 = x . usd (f32 dots, butterfly
// reduce over the 4 quads). One wave owns 16 rows, lane (r,quad) holds 32 cols.
// ---------------------------------------------------------------------------
__global__ void cvtx_sd(const float* __restrict__ x, const float* __restrict__ usd,
                        __hip_bfloat16* __restrict__ xb,
                        float* __restrict__ s, float* __restrict__ d, int M) {
    __shared__ float us_s[1024];
    for (int i = threadIdx.x; i < 1024; i += 256) us_s[i] = usd[i];
    __syncthreads();
    int wave = threadIdx.x >> 6, lane = threadIdx.x & 63;
    int m0 = blockIdx.x * 64 + wave * 16;
    int r = lane & 15, quad = lane >> 4;
    int am = m0 + r; if (am >= M) am = M - 1;
    const float* xp = x + (size_t)am * 128 + quad * 8;
    float xv[32];
#pragma unroll
    for (int kk = 0; kk < 4; kk++) {
        float4 a = *(const float4*)(xp + kk * 32);
        float4 bq = *(const float4*)(xp + kk * 32 + 4);
        xv[kk*8+0]=a.x;  xv[kk*8+1]=a.y;  xv[kk*8+2]=a.z;  xv[kk*8+3]=a.w;
        xv[kk*8+4]=bq.x; xv[kk*8+5]=bq.y; xv[kk*8+6]=bq.z; xv[kk*8+7]=bq.w;
        short8 o;
        o[0]=(short)f2bfu(a.x);  o[1]=(short)f2bfu(a.y);
        o[2]=(short)f2bfu(a.z);  o[3]=(short)f2bfu(a.w);
        o[4]=(short)f2bfu(bq.x); o[5]=(short)f2bfu(bq.y);
        o[6]=(short)f2bfu(bq.z); o[7]=(short)f2bfu(bq.w);
        *(short8*)(xb + (size_t)am * 128 + quad * 8 + kk * 32) = o;
    }
    float acc[8];
#pragma unroll
    for (int o = 0; o < 8; o++) {
        const float* up = us_s + o * 128 + quad * 8;
        float a = 0.f;
#pragma unroll
        for (int kk = 0; kk < 4; kk++)
#pragma unroll
            for (int j = 0; j < 8; j++) a += xv[kk*8+j] * up[kk*32+j];
        acc[o] = a;
    }
#pragma unroll
    for (int o = 0; o < 8; o++) {
        acc[o] += __shfl_xor(acc[o], 16, 64);
        acc[o] += __shfl_xor(acc[o], 32, 64);
    }
    int m = m0 + r;
    if (quad == 0 && m < M) {
#pragma unroll
        for (int hh = 0; hh < 4; hh++) { s[m*4+hh] = acc[hh]; d[m*4+hh] = acc[4+hh]; }
    }
}

// ---------------------------------------------------------------------------
// Two-level multi-block scan of deg -> offsets
// ---------------------------------------------------------------------------
#define SCB 49   // scan blocks, 1024 elements each (49*1024 = 50176 >= NN)
__global__ void scan1_kernel(const int* __restrict__ deg, int* __restrict__ bsum) {
    __shared__ int red[256];
    int b = blockIdx.x, t = threadIdx.x;
    int base = b * 1024 + t * 4;
    int s = 0;
    if (base + 3 < NN) { int4 v = *(const int4*)(deg + base); s = v.x + v.y + v.z + v.w; }
    else { for (int i = base; i < NN; i++) s += deg[i]; }
    red[t] = s;
    __syncthreads();
    for (int off = 128; off > 0; off >>= 1) {
        if (t < off) red[t] += red[t + off];
        __syncthreads();
    }
    if (t == 0) bsum[b] = red[0];
}

__global__ void scan2_kernel(const int* __restrict__ deg, const int* __restrict__ bsum,
                             int* __restrict__ offsets) {
    __shared__ int lsum[256];
    int b = blockIdx.x, t = threadIdx.x;
    int boff = 0;
    for (int i = 0; i < b; i++) boff += bsum[i];       // <=48 cached loads
    int base = b * 1024 + t * 4;
    int4 v = {0, 0, 0, 0};
    if (base + 3 < NN) v = *(const int4*)(deg + base);
    else {
        if (base < NN)     v.x = deg[base];
        if (base + 1 < NN) v.y = deg[base + 1];
        if (base + 2 < NN) v.z = deg[base + 2];
        if (base + 3 < NN) v.w = deg[base + 3];
    }
    int s = v.x + v.y + v.z + v.w;
    lsum[t] = s;
    __syncthreads();
    for (int off = 1; off < 256; off <<= 1) {
        int val = (t >= off) ? lsum[t - off] : 0;
        __syncthreads();
        lsum[t] += val;
        __syncthreads();
    }
    int ex = boff + (t ? lsum[t - 1] : 0);
    if (base < NN)     offsets[base]     = ex;
    if (base + 1 < NN) offsets[base + 1] = ex + v.x;
    if (base + 2 < NN) offsets[base + 2] = ex + v.x + v.y;
    if (base + 3 < NN) offsets[base + 3] = ex + v.x + v.y + v.z;
    if (b == SCB - 1 && t == 255) offsets[NN] = boff + lsum[255];
}

// ---------------------------------------------------------------------------
// fill: CSR scatter + fused layer-1 edge weights (s1/d1 already computed).
// elist[j]=src, dstlist[j]=dst, welist4[j] = exp(lrelu(s1[src]+d1[dst])) x4.
// ---------------------------------------------------------------------------
__global__ void fill_kernel(const int* __restrict__ ei, const int* __restrict__ offsets,
                            int* __restrict__ cursor,
                            const float* __restrict__ s1, const float* __restrict__ d1,
                            int* __restrict__ elist, int* __restrict__ dstlist,
                            float* __restrict__ welist) {
    int e = blockIdx.x * blockDim.x + threadIdx.x;
    if (e >= EP) return;
    int src, dst;
    if (e < EE) { src = ei[e]; dst = ei[EE + e]; } else { src = dst = e - EE; }
    int pos = atomicAdd(&cursor[dst], 1);
    int j = offsets[dst] + pos;
    elist[j] = src;
    dstlist[j] = dst;
    float4 sv = *(const float4*)(s1 + (size_t)src * 4);
    float4 dv = *(const float4*)(d1 + (size_t)dst * 4);
    float4 w;
    w.x = lrelu_exp(sv.x + dv.x);
    w.y = lrelu_exp(sv.y + dv.y);
    w.z = lrelu_exp(sv.z + dv.z);
    w.w = lrelu_exp(sv.w + dv.w);
    *(float4*)(welist + (size_t)j * 4) = w;
}

// ---------------------------------------------------------------------------
// Edge-parallel weight precompute for layers 2 (H=4) and 3 (H=1).
// ---------------------------------------------------------------------------
__global__ void edge_w4(const int* __restrict__ elist, const int* __restrict__ dstlist,
                        const float* __restrict__ s, const float* __restrict__ d,
                        float* __restrict__ wout) {
    int j = blockIdx.x * blockDim.x + threadIdx.x;
    if (j >= EP) return;
    int src = elist[j], dst = dstlist[j];
    float4 sv = *(const float4*)(s + (size_t)src * 4);
    float4 dv = *(const float4*)(d + (size_t)dst * 4);
    float4 w;
    w.x = lrelu_exp(sv.x + dv.x);
    w.y = lrelu_exp(sv.y + dv.y);
    w.z = lrelu_exp(sv.z + dv.z);
    w.w = lrelu_exp(sv.w + dv.w);
    *(float4*)(wout + (size_t)j * 4) = w;
}

__global__ void edge_w1(const int* __restrict__ elist, const int* __restrict__ dstlist,
                        const float* __restrict__ s, const float* __restrict__ d,
                        float* __restrict__ wout) {
    int j = blockIdx.x * blockDim.x + threadIdx.x;
    if (j >= EP) return;
    wout[j] = lrelu_exp(s[elist[j]] + d[dstlist[j]]);
}

// ---------------------------------------------------------------------------
// Layer-1 gather, NODE-PER-WAVE: lane owns 2 x-channels x all 4 heads.
// x-row read fully coalesced 256B/edge, zero redundancy, zero divergence.
// elist/welist loads are wave-uniform -> scalar path. Packed output.
// ---------------------------------------------------------------------------
__global__ void gather_agg(const int* __restrict__ elist, const int* __restrict__ offsets,
                           const float* __restrict__ wl,
                           const __hip_bfloat16* __restrict__ xb,
                           __hip_bfloat16* __restrict__ pagg) {
    int wid = blockIdx.x * 4 + (threadIdx.x >> 6);
    if (wid >= NN) return;
    int lane = threadIdx.x & 63;
    int node = wid;
    int j0 = __builtin_amdgcn_readfirstlane(offsets[node]);
    int j1 = __builtin_amdgcn_readfirstlane(offsets[node + 1]);
    float den0 = 0.f, den1 = 0.f, den2 = 0.f, den3 = 0.f;
    float a00=0.f,a01=0.f,a10=0.f,a11=0.f,a20=0.f,a21=0.f,a30=0.f,a31=0.f;
    const unsigned short* xp = (const unsigned short*)xb + lane * 2;
    int j = j0;
    for (; j + 4 <= j1; j += 4) {
        int sA = elist[j], sB = elist[j+1], sC = elist[j+2], sD = elist[j+3];
        float4 wA = *(const float4*)(wl + (size_t)j * 4);
        float4 wB = *(const float4*)(wl + (size_t)(j+1) * 4);
        float4 wC = *(const float4*)(wl + (size_t)(j+2) * 4);
        float4 wD = *(const float4*)(wl + (size_t)(j+3) * 4);
        unsigned int xA = *(const unsigned int*)(xp + (size_t)sA * 128);
        unsigned int xB = *(const unsigned int*)(xp + (size_t)sB * 128);
        unsigned int xC = *(const unsigned int*)(xp + (size_t)sC * 128);
        unsigned int xD = *(const unsigned int*)(xp + (size_t)sD * 128);
        float xA0 = us2f((unsigned short)xA), xA1 = us2f((unsigned short)(xA >> 16));
        float xB0 = us2f((unsigned short)xB), xB1 = us2f((unsigned short)(xB >> 16));
        float xC0 = us2f((unsigned short)xC), xC1 = us2f((unsigned short)(xC >> 16));
        float xD0 = us2f((unsigned short)xD), xD1 = us2f((unsigned short)(xD >> 16));
        den0 += (wA.x + wB.x) + (wC.x + wD.x);
        den1 += (wA.y + wB.y) + (wC.y + wD.y);
        den2 += (wA.z + wB.z) + (wC.z + wD.z);
        den3 += (wA.w + wB.w) + (wC.w + wD.w);
        a00 += wA.x*xA0 + wB.x*xB0 + wC.x*xC0 + wD.x*xD0;
        a01 += wA.x*xA1 + wB.x*xB1 + wC.x*xC1 + wD.x*xD1;
        a10 += wA.y*xA0 + wB.y*xB0 + wC.y*xC0 + wD.y*xD0;
        a11 += wA.y*xA1 + wB.y*xB1 + wC.y*xC1 + wD.y*xD1;
        a20 += wA.z*xA0 + wB.z*xB0 + wC.z*xC0 + wD.z*xD0;
        a21 += wA.z*xA1 + wB.z*xB1 + wC.z*xC1 + wD.z*xD1;
        a30 += wA.w*xA0 + wB.w*xB0 + wC.w*xC0 + wD.w*xD0;
        a31 += wA.w*xA1 + wB.w*xB1 + wC.w*xC1 + wD.w*xD1;
    }
    for (; j < j1; j++) {
        int sE = elist[j];
        float4 w = *(const float4*)(wl + (size_t)j * 4);
        unsigned int xv = *(const unsigned int*)(xp + (size_t)sE * 128);
        float x0 = us2f((unsigned short)xv), x1 = us2f((unsigned short)(xv >> 16));
        den0 += w.x; den1 += w.y; den2 += w.z; den3 += w.w;
        a00 += w.x*x0; a01 += w.x*x1; a10 += w.y*x0; a11 += w.y*x1;
        a20 += w.z*x0; a21 += w.z*x1; a30 += w.w*x0; a31 += w.w*x1;
    }
    int c0 = lane * 2;
    int fq = c0 >> 5;                 // within-head frag index
    size_t tb = (size_t)(node >> 4) * 16 * 512 + (size_t)((c0 & 31) >> 3) * 128
              + (size_t)(node & 15) * 8 + (c0 & 7);
    unsigned short* pb = (unsigned short*)pagg + tb;
    float i0 = 1.f/den0, i1 = 1.f/den1, i2 = 1.f/den2, i3 = 1.f/den3;
    *(unsigned int*)(pb + (size_t)(0*4 + fq) * 512) =
        (unsigned int)f2bfu(a00*i0) | ((unsigned int)f2bfu(a01*i0) << 16);
    *(unsigned int*)(pb + (size_t)(1*4 + fq) * 512) =
        (unsigned int)f2bfu(a10*i1) | ((unsigned int)f2bfu(a11*i1) << 16);
    *(unsigned int*)(pb + (size_t)(2*4 + fq) * 512) =
        (unsigned int)f2bfu(a20*i2) | ((unsigned int)f2bfu(a21*i2) << 16);
    *(unsigned int*)(pb + (size_t)(3*4 + fq) * 512) =
        (unsigned int)f2bfu(a30*i3) | ((unsigned int)f2bfu(a31*i3) << 16);
}

// ---------------------------------------------------------------------------
// Block-diagonal GEMM for layer-1 output, wave-per-head, packed in/out:
//   act[n, hh*128+oc] = ELU( sum_c aggn[n,hh,c] * W1[hh*128+oc, c] + b1 )
// ---------------------------------------------------------------------------
__global__ void gemm_bdiag(const __hip_bfloat16* __restrict__ pA,
                           const __hip_bfloat16* __restrict__ pW1,
                           const float* __restrict__ b,
                           __hip_bfloat16* __restrict__ pact, int M) {
    int hh = threadIdx.x >> 6, lane = threadIdx.x & 63;
    int m0 = blockIdx.x * 16;
    int r = lane & 15, quad = lane >> 4;
    short8 afrag[4];
    const __hip_bfloat16* ap = pA + ((size_t)(m0 >> 4) * 16 + hh * 4) * 512 + lane * 8;
#pragma unroll
    for (int kk = 0; kk < 4; kk++) afrag[kk] = *(const short8*)(ap + kk * 512);
#pragma unroll
    for (int nb = 0; nb < 128; nb += 16) {
        const __hip_bfloat16* bp = pW1 + ((size_t)(hh * 8 + (nb >> 4)) * 4) * 512 + lane * 8;
        f32x4 acc = {0.f, 0.f, 0.f, 0.f};
#pragma unroll
        for (int kk = 0; kk < 4; kk++) {
            short8 bfr = *(const short8*)(bp + kk * 512);
            acc = __builtin_amdgcn_mfma_f32_16x16x32_bf16(afrag[kk], bfr, acc, 0, 0, 0);
        }
        int n0 = hh * 128 + nb;
        float bias = b[n0 + r];
        // packed store: k = n0 + r, m = m0 + quad*4 + i
        int kk2 = (n0 + r) >> 5;
        int sub = ((nb & 16) + r) >> 3;
        __hip_bfloat16* op = pact + ((size_t)(m0 >> 4) * 16 + kk2) * 512
                           + sub * 128 + (r & 7);
#pragma unroll
        for (int i = 0; i < 4; i++) {
            float v = acc[i] + bias;
            v = v > 0.f ? v : (__expf(v) - 1.0f);
            op[(quad * 4 + i) * 8] = __float2bfloat16(v);
        }
    }
}

// ---------------------------------------------------------------------------
// Layer-2 GEMM, wave-per-head, packed A and W; streams af/b0/b1 per k.
// Fused s2/d2 epilogue. h2 written row-major [N][128].
// ---------------------------------------------------------------------------
__global__ void gemm_l2(const __hip_bfloat16* __restrict__ pA,
                        const __hip_bfloat16* __restrict__ pW2,
                        const float* __restrict__ as_, const float* __restrict__ ad_,
                        __hip_bfloat16* __restrict__ Cb,
                        float* __restrict__ s, float* __restrict__ d, int M) {
    int hh = threadIdx.x >> 6, lane = threadIdx.x & 63;
    int m0 = blockIdx.x * 16;
    int r = lane & 15, quad = lane >> 4;
    const __hip_bfloat16* ap  = pA + (size_t)(m0 >> 4) * 16 * 512 + lane * 8;
    const __hip_bfloat16* bp0 = pW2 + (size_t)(hh * 2) * 16 * 512 + lane * 8;
    const __hip_bfloat16* bp1 = bp0 + 16 * 512;
    f32x4 acc0 = {0.f, 0.f, 0.f, 0.f}, acc1 = {0.f, 0.f, 0.f, 0.f};
#pragma unroll
    for (int kk = 0; kk < 16; kk++) {
        short8 af = *(const short8*)(ap + kk * 512);
        short8 b0 = *(const short8*)(bp0 + kk * 512);
        short8 b1 = *(const short8*)(bp1 + kk * 512);
        acc0 = __builtin_amdgcn_mfma_f32_16x16x32_bf16(af, b0, acc0, 0, 0, 0);
        acc1 = __builtin_amdgcn_mfma_f32_16x16x32_bf16(af, b1, acc1, 0, 0, 0);
    }
    int n0 = hh * 32;
    float as0 = as_[n0 + r],      ad0 = ad_[n0 + r];
    float as1 = as_[n0 + 16 + r], ad1 = ad_[n0 + 16 + r];
    float sacc[4], dacc[4];
#pragma unroll
    for (int i = 0; i < 4; i++) {
        int m = m0 + quad * 4 + i;
        Cb[(size_t)m * 128 + n0 + r]      = __float2bfloat16(acc0[i]);
        Cb[(size_t)m * 128 + n0 + 16 + r] = __float2bfloat16(acc1[i]);
        sacc[i] = acc0[i] * as0 + acc1[i] * as1;
        dacc[i] = acc0[i] * ad0 + acc1[i] * ad1;
    }
#pragma unroll
    for (int mask = 1; mask <= 8; mask <<= 1) {
#pragma unroll
        for (int i = 0; i < 4; i++) {
            sacc[i] += __shfl_xor(sacc[i], mask, 64);
            dacc[i] += __shfl_xor(dacc[i], mask, 64);
        }
    }
    if (r == 0) {
#pragma unroll
        for (int i = 0; i < 4; i++) {
            int m = m0 + quad * 4 + i;
            s[m * 4 + hh] = sacc[i]; d[m * 4 + hh] = dacc[i];
        }
    }
}

// ---------------------------------------------------------------------------
// Layer-2 gather: node-per-wave, lane owns 2 channels; weights from welist.
// ---------------------------------------------------------------------------
__global__ void gather_l2(const int* __restrict__ elist, const int* __restrict__ offsets,
                          const float* __restrict__ wl,
                          const __hip_bfloat16* __restrict__ h,
                          const float* __restrict__ b,
                          __hip_bfloat16* __restrict__ act) {
    int gid = blockIdx.x * blockDim.x + threadIdx.x;
    if (gid >= NN * 64) return;
    int node = gid >> 6;
    int lane = gid & 63;
    int c0 = lane * 2;
    int hh = lane >> 4;                 // C=32 -> head = c0/32
    int j0 = __builtin_amdgcn_readfirstlane(offsets[node]);
    int j1 = __builtin_amdgcn_readfirstlane(offsets[node + 1]);
    float den = 0.f, acc0 = 0.f, acc1 = 0.f;
    const unsigned short* hp = (const unsigned short*)h + c0;
    int j = j0;
    for (; j + 4 <= j1; j += 4) {
        int sA = elist[j], sB = elist[j+1], sC = elist[j+2], sD = elist[j+3];
        float wA = wl[(size_t)j*4 + hh],     wB = wl[(size_t)(j+1)*4 + hh];
        float wC = wl[(size_t)(j+2)*4 + hh], wD = wl[(size_t)(j+3)*4 + hh];
        unsigned int vA = *(const unsigned int*)(hp + (size_t)sA * 128);
        unsigned int vB = *(const unsigned int*)(hp + (size_t)sB * 128);
        unsigned int vC = *(const unsigned int*)(hp + (size_t)sC * 128);
        unsigned int vD = *(const unsigned int*)(hp + (size_t)sD * 128);
        den += (wA + wB) + (wC + wD);
        acc0 += wA * us2f((unsigned short)vA) + wB * us2f((unsigned short)vB)
              + wC * us2f((unsigned short)vC) + wD * us2f((unsigned short)vD);
        acc1 += wA * us2f((unsigned short)(vA >> 16)) + wB * us2f((unsigned short)(vB >> 16))
              + wC * us2f((unsigned short)(vC >> 16)) + wD * us2f((unsigned short)(vD >> 16));
    }
    for (; j < j1; j++) {
        int sE = elist[j];
        float w = wl[(size_t)j*4 + hh];
        unsigned int v = *(const unsigned int*)(hp + (size_t)sE * 128);
        den += w;
        acc0 += w * us2f((unsigned short)v);
        acc1 += w * us2f((unsigned short)(v >> 16));
    }
    float inv = 1.0f / den;
    float v0 = acc0 * inv + b[c0];
    float v1 = acc1 * inv + b[c0 + 1];
    v0 = v0 > 0.f ? v0 : (__expf(v0) - 1.0f);
    v1 = v1 > 0.f ? v1 : (__expf(v1) - 1.0f);
    *(unsigned int*)((unsigned short*)act + (size_t)node * 128 + c0) =
        (unsigned int)f2bfu(v0) | ((unsigned int)f2bfu(v1) << 16);
}

// ---------------------------------------------------------------------------
// Layer-3 gather: 8 lanes/node, lane owns 1 channel; weights from welist.
// ---------------------------------------------------------------------------
__global__ void gather_l3(const int* __restrict__ elist, const int* __restrict__ offsets,
                          const float* __restrict__ wl,
                          const __hip_bfloat16* __restrict__ h,
                          const float* __restrict__ b,
                          __hip_bfloat16* __restrict__ act) {
    int gid = blockIdx.x * blockDim.x + threadIdx.x;
    if (gid >= NN * 8) return;
    int node = gid >> 3, t = gid & 7;
    int j0 = offsets[node], j1 = offsets[node + 1];
    float den = 0.f, acc = 0.f;
    const unsigned short* hp = (const unsigned short*)h + t;
    int j = j0;
    for (; j + 4 <= j1; j += 4) {
        int sA = elist[j], sB = elist[j+1], sC = elist[j+2], sD = elist[j+3];
        float wA = wl[j], wB = wl[j+1], wC = wl[j+2], wD = wl[j+3];
        float xA = us2f(hp[(size_t)sA * 8]);
        float xB = us2f(hp[(size_t)sB * 8]);
        float xC = us2f(hp[(size_t)sC * 8]);
        float xD = us2f(hp[(size_t)sD * 8]);
        den += (wA + wB) + (wC + wD);
        acc += wA * xA + wB * xB + wC * xC + wD * xD;
    }
    for (; j < j1; j++) {
        int sE = elist[j];
        float w = wl[j];
        den += w;
        acc += w * us2f(hp[(size_t)sE * 8]);
    }
    float v = acc / den + b[t];
    v = v > 0.f ? v : (__expf(v) - 1.0f);
    act[(size_t)node * 8 + t] = __float2bfloat16(v);
}

// ---------------------------------------------------------------------------
// Tiny GEMM for layer 3 + fused s/d. Split-K: 8 lanes per node, lane t owns
// k-slice [t*16, t*16+16) for ALL 8 outputs; butterfly reduce over 8 lanes.
// ---------------------------------------------------------------------------
__global__ void gemm8_kernel(const __hip_bfloat16* __restrict__ A,
                             const float* __restrict__ W,
                             const float* __restrict__ a3s, const float* __restrict__ a3d,
                             __hip_bfloat16* __restrict__ Cb,
                             float* __restrict__ s, float* __restrict__ d) {
    int gid = blockIdx.x * blockDim.x + threadIdx.x;
    if (gid >= NN * 8) return;
    int n = gid >> 3, t = gid & 7;
    const unsigned short* ap = (const unsigned short*)A + (size_t)n * 128 + t * 16;
    short8 v0 = *(const short8*)ap;
    short8 v1 = *(const short8*)(ap + 8);
    float xf[16];
#pragma unroll
    for (int j = 0; j < 8; j++) { xf[j] = us2f((unsigned short)v0[j]); xf[8+j] = us2f((unsigned short)v1[j]); }
    float acc[8];
#pragma unroll
    for (int c = 0; c < 8; c++) {
        const float* wp = W + c * 128 + t * 16;
        float a = 0.f;
#pragma unroll
        for (int j = 0; j < 16; j++) a += xf[j] * wp[j];
        acc[c] = a;
    }
#pragma unroll
    for (int mask = 1; mask <= 4; mask <<= 1)
#pragma unroll
        for (int c = 0; c < 8; c++) acc[c] += __shfl_xor(acc[c], mask, 64);
    Cb[n * 8 + t] = __float2bfloat16(acc[t]);
    if (t == 0) {
        float sv = 0.f, dvv = 0.f;
#pragma unroll
        for (int c = 0; c < 8; c++) { sv += acc[c] * a3s[c]; dvv += acc[c] * a3d[c]; }
        s[n] = sv; d[n] = dvv;
    }
}

// ---------------------------------------------------------------------------
// Final edge MLP: z[19] = [h3[src], h3[dst], ea, yr, qt] -> fc1(relu) -> fc2
// ---------------------------------------------------------------------------
__global__ void mlp_kernel(const int* __restrict__ ei,
                           const __hip_bfloat16* __restrict__ act3,
                           const float* __restrict__ ea,
                           const float* __restrict__ yr,
                           const float* __restrict__ qt,
                           const float* __restrict__ fc1w,
                           const float* __restrict__ fc1b,
                           const float* __restrict__ fc2w,
                           const float* __restrict__ fc2b,
                           float* __restrict__ outp) {
    __shared__ float w1[16 * 19], b1s[16], w2[16];
    for (int i = threadIdx.x; i < 16 * 19; i += blockDim.x) w1[i] = fc1w[i];
    if (threadIdx.x < 16) {
        b1s[threadIdx.x] = fc1b[threadIdx.x];
        w2[threadIdx.x] = fc2w[threadIdx.x];
    }
    __syncthreads();
    int e = blockIdx.x * blockDim.x + threadIdx.x;
    if (e >= EE) return;
    int src = ei[e], dst = ei[EE + e];
    short8 hs = *(const short8*)(act3 + (size_t)src * 8);
    short8 hd = *(const short8*)(act3 + (size_t)dst * 8);
    float z[19];
#pragma unroll
    for (int i = 0; i < 8; i++) z[i] = us2f((unsigned short)hs[i]);
#pragma unroll
    for (int i = 0; i < 8; i++) z[8 + i] = us2f((unsigned short)hd[i]);
    z[16] = ea[e]; z[17] = yr[e]; z[18] = qt[e];
    float acc2 = fc2b[0];
#pragma unroll
    for (int j = 0; j < 16; j++) {
        float a = b1s[j];
#pragma unroll
        for (int i = 0; i < 19; i++) a += z[i] * w1[j * 19 + i];
        a = a > 0.f ? a : 0.f;
        acc2 += a * w2[j];
    }
    outp[e] = acc2;
}

// ---------------------------------------------------------------------------
extern "C" void kernel_launch(void* const* d_in, const int* in_sizes, int n_in,
                              void* d_out, int out_size, void* d_ws, size_t ws_size,
                              hipStream_t stream) {
    const float* x    = (const float*)d_in[0];
    const int*   ei   = (const int*)d_in[1];
    const float* ea   = (const float*)d_in[2];
    const float* yr   = (const float*)d_in[3];
    const float* qt   = (const float*)d_in[4];
    const float* W1   = (const float*)d_in[5];
    const float* a1s  = (const float*)d_in[6];
    const float* a1d  = (const float*)d_in[7];
    const float* b1   = (const float*)d_in[8];
    const float* W2   = (const float*)d_in[9];
    const float* a2s  = (const float*)d_in[10];
    const float* a2d  = (const float*)d_in[11];
    const float* b2   = (const float*)d_in[12];
    const float* W3   = (const float*)d_in[13];
    const float* a3s  = (const float*)d_in[14];
    const float* a3d  = (const float*)d_in[15];
    const float* b3   = (const float*)d_in[16];
    const float* fc1w = (const float*)d_in[17];
    const float* fc1b = (const float*)d_in[18];
    const float* fc2w = (const float*)d_in[19];
    const float* fc2b = (const float*)d_in[20];
    float* outp = (float*)d_out;

    char* ws = (char*)d_ws;
    __hip_bfloat16* h_buf   = (__hip_bfloat16*)(ws);                 // N*512 bf16: pagg / h2 / h3
    __hip_bfloat16* act_buf = (__hip_bfloat16*)(ws + 51200000);      // N*512 bf16: xb / pact1 / act2 / act3
    float* s_buf   = (float*)(ws + 102400000);                       // N*4 f32: s1/s2/s3
    float* d_buf   = (float*)(ws + 103200000);                       // N*4 f32: d1/d2/d3
    int*   deg     = (int*)  (ws + 104000000);                       // N ints
    int*   cursor  = (int*)  (ws + 104200000);                       // N ints (contiguous w/ deg)
    int*   offsets = (int*)  (ws + 104400000);                       // N+1 ints
    int*   elist   = (int*)  (ws + 104600016);                       // EP ints (1.8 MB)
    __hip_bfloat16* pw1 = (__hip_bfloat16*)(ws + 106400016);         // 512*128 bf16 packed
    __hip_bfloat16* pw2 = (__hip_bfloat16*)(ws + 106531088);         // 128*512 bf16 packed
    float* usd  = (float*)(ws + 106662160);                          // 8*128 f32 (4 KB)
    int*   bsum = (int*)  (ws + 106666256);                          // SCB ints
    float* welist = (float*)(ws + 106666512);                        // EP*4 f32 (7.2 MB)
    int*   dstlist = (int*)(ws + 113866512);                         // EP ints (1.8 MB)
    __hip_bfloat16* xb = act_buf;                                    // N*128 bf16, dead after gather_agg

    // ---- prep (deg + weight pack + usd) + CSR scan ----
    hipMemsetAsync(deg, 0, 2 * NN * sizeof(int), stream);            // deg + cursor
    prep_kernel<<<DEGB + CVTB + 4, 256, 0, stream>>>(ei, deg, W1, W2, pw1, pw2, a1s, a1d, usd);
    scan1_kernel<<<SCB, 256, 0, stream>>>(deg, bsum);
    scan2_kernel<<<SCB, 256, 0, stream>>>(deg, bsum, offsets);
    cvtx_sd<<<(NN + 63) / 64, 256, 0, stream>>>(x, usd, xb, s_buf, d_buf, NN);
    fill_kernel<<<(EP + 255) / 256, 256, 0, stream>>>(ei, offsets, cursor, s_buf, d_buf,
                                                      elist, dstlist, welist);

    // ---- Layer 1: gather raw x (node-per-wave, packed out) + bdiag GEMM ----
    gather_agg<<<(NN + 3) / 4, 256, 0, stream>>>(elist, offsets, welist, xb, h_buf);
    gemm_bdiag<<<(NN + 15) / 16, 256, 0, stream>>>(h_buf, pw1, b1, act_buf, NN);

    // ---- Layer 2: GEMM -> edge weights -> gather ----
    gemm_l2<<<(NN + 15) / 16, 256, 0, stream>>>(
        act_buf, pw2, a2s, a2d, h_buf, s_buf, d_buf, NN);
    edge_w4<<<(EP + 255) / 256, 256, 0, stream>>>(elist, dstlist, s_buf, d_buf, welist);
    gather_l2<<<(NN * 64 + 255) / 256, 256, 0, stream>>>(
        elist, offsets, welist, h_buf, b2, act_buf);

    // ---- Layer 3: GEMM -> edge weights -> gather ----
    gemm8_kernel<<<(NN * 8 + 255) / 256, 256, 0, stream>>>(
        act_buf, W3, a3s, a3d, h_buf, s_buf, d_buf);
    edge_w1<<<(EP + 255) / 256, 256, 0, stream>>>(elist, dstlist, s_buf, d_buf, welist);
    gather_l3<<<(NN * 8 + 255) / 256, 256, 0, stream>>>(
        elist, offsets, welist, h_buf, b3, act_buf);

    // ---- Final edge MLP ----
    mlp_kernel<<<(EE + 255) / 256, 256, 0, stream>>>(ei, act_buf, ea, yr, qt,
                                                     fc1w, fc1b, fc2w, fc2b, outp);
}

// Round 7
// 308.383 us; speedup vs baseline: 1.0782x; 1.0782x over previous
//
#include <hip/hip_runtime.h>
#include <hip/hip_bf16.h>

#define NN 50000
#define EE 400000
#define EP 450000   // EE + NN self-loops

typedef __attribute__((ext_vector_type(8))) short short8;
typedef __attribute__((ext_vector_type(4))) float f32x4;

__device__ __forceinline__ float us2f(unsigned short u) {
    unsigned int x = ((unsigned int)u) << 16;
    union { unsigned int i; float f; } c; c.i = x; return c.f;
}
__device__ __forceinline__ unsigned short f2bfu(float f) {   // f32 -> bf16 bits, RNE
    union { float f; unsigned int u; } c; c.f = f;
    unsigned int r = c.u + 0x7FFFu + ((c.u >> 16) & 1u);
    return (unsigned short)(r >> 16);
}
__device__ __forceinline__ unsigned int pack2bf(float lo, float hi) {
    return (unsigned int)f2bfu(lo) | ((unsigned int)f2bfu(hi) << 16);
}
__device__ __forceinline__ float lrelu_exp(float x) {
    x = x > 0.f ? x : 0.2f * x;
    return __expf(x);
}

// Packed MFMA-fragment index for a [M x K] bf16 matrix consumed as A (or B with
// n in place of m) by mfma_f32_16x16x32_bf16:
//   idx(m,k) = ((m>>4)*(K/32) + (k>>5))*512 + ((k&31)>>3)*128 + (m&15)*8 + (k&7)

// ---------------------------------------------------------------------------
// prep: fused deg histogram + W1/W2 f32->bf16 packed convert + usd precompute.
// ---------------------------------------------------------------------------
#define DEGB 1758
#define CVTB 512
__global__ void prep_kernel(const int* __restrict__ ei, int* __restrict__ deg,
                            const float* __restrict__ W1, const float* __restrict__ W2,
                            __hip_bfloat16* __restrict__ pw1, __hip_bfloat16* __restrict__ pw2,
                            const float* __restrict__ a1s, const float* __restrict__ a1d,
                            float* __restrict__ usd) {
    int b = blockIdx.x;
    if (b < DEGB) {
        int e = b * 256 + threadIdx.x;
        if (e >= EP) return;
        int dst = (e < EE) ? ei[EE + e] : e - EE;
        atomicAdd(&deg[dst], 1);
    } else if (b < DEGB + CVTB) {
        int i = (b - DEGB) * 256 + threadIdx.x;
        if (i < 65536) {
            int n = i >> 7, k = i & 127;   // K=128, NK=4
            int idx = ((n >> 4) * 4 + (k >> 5)) * 512 + ((k & 31) >> 3) * 128 + (n & 15) * 8 + (k & 7);
            pw1[idx] = __float2bfloat16(W1[i]);
        } else {
            int j = i - 65536;
            int n = j >> 9, k = j & 511;   // K=512, NK=16
            int idx = ((n >> 4) * 16 + (k >> 5)) * 512 + ((k & 31) >> 3) * 128 + (n & 15) * 8 + (k & 7);
            pw2[idx] = __float2bfloat16(W2[j]);
        }
    } else {
        int t = (b - DEGB - CVTB) * 256 + threadIdx.x;
        if (t >= 1024) return;
        int row = t >> 7, k = t & 127;
        int hh = row & 3;
        const float* av = (row < 4) ? (a1s + hh * 128) : (a1d + hh * 128);
        const float* wp = W1 + (size_t)(hh * 128) * 128 + k;
        float acc = 0.f;
        for (int c = 0; c < 128; c++) acc += av[c] * wp[(size_t)c * 128];
        usd[t] = acc;
    }
}

// ---------------------------------------------------------------------------
// Fused: x (f32) -> xb (bf16) convert + s1/d1 = x . usd.
// ---------------------------------------------------------------------------
__global__ void cvtx_sd(const float* __restrict__ x, const float* __restrict__ usd,
                        __hip_bfloat16* __restrict__ xb,
                        float* __restrict__ s, float* __restrict__ d, int M) {
    __shared__ float us_s[1024];
    for (int i = threadIdx.x; i < 1024; i += 256) us_s[i] = usd[i];
    __syncthreads();
    int wave = threadIdx.x >> 6, lane = threadIdx.x & 63;
    int m0 = blockIdx.x * 64 + wave * 16;
    int r = lane & 15, quad = lane >> 4;
    int am = m0 + r; if (am >= M) am = M - 1;
    const float* xp = x + (size_t)am * 128 + quad * 8;
    float xv[32];
#pragma unroll
    for (int kk = 0; kk < 4; kk++) {
        float4 a = *(const float4*)(xp + kk * 32);
        float4 bq = *(const float4*)(xp + kk * 32 + 4);
        xv[kk*8+0]=a.x;  xv[kk*8+1]=a.y;  xv[kk*8+2]=a.z;  xv[kk*8+3]=a.w;
        xv[kk*8+4]=bq.x; xv[kk*8+5]=bq.y; xv[kk*8+6]=bq.z; xv[kk*8+7]=bq.w;
        short8 o;
        o[0]=(short)f2bfu(a.x);  o[1]=(short)f2bfu(a.y);
        o[2]=(short)f2bfu(a.z);  o[3]=(short)f2bfu(a.w);
        o[4]=(short)f2bfu(bq.x); o[5]=(short)f2bfu(bq.y);
        o[6]=(short)f2bfu(bq.z); o[7]=(short)f2bfu(bq.w);
        *(short8*)(xb + (size_t)am * 128 + quad * 8 + kk * 32) = o;
    }
    float acc[8];
#pragma unroll
    for (int o = 0; o < 8; o++) {
        const float* up = us_s + o * 128 + quad * 8;
        float a = 0.f;
#pragma unroll
        for (int kk = 0; kk < 4; kk++)
#pragma unroll
            for (int j = 0; j < 8; j++) a += xv[kk*8+j] * up[kk*32+j];
        acc[o] = a;
    }
#pragma unroll
    for (int o = 0; o < 8; o++) {
        acc[o] += __shfl_xor(acc[o], 16, 64);
        acc[o] += __shfl_xor(acc[o], 32, 64);
    }
    int m = m0 + r;
    if (quad == 0 && m < M) {
#pragma unroll
        for (int hh = 0; hh < 4; hh++) { s[m*4+hh] = acc[hh]; d[m*4+hh] = acc[4+hh]; }
    }
}

// ---------------------------------------------------------------------------
// Two-level multi-block scan of deg -> offsets
// ---------------------------------------------------------------------------
#define SCB 49
__global__ void scan1_kernel(const int* __restrict__ deg, int* __restrict__ bsum) {
    __shared__ int red[256];
    int b = blockIdx.x, t = threadIdx.x;
    int base = b * 1024 + t * 4;
    int s = 0;
    if (base + 3 < NN) { int4 v = *(const int4*)(deg + base); s = v.x + v.y + v.z + v.w; }
    else { for (int i = base; i < NN; i++) s += deg[i]; }
    red[t] = s;
    __syncthreads();
    for (int off = 128; off > 0; off >>= 1) {
        if (t < off) red[t] += red[t + off];
        __syncthreads();
    }
    if (t == 0) bsum[b] = red[0];
}

__global__ void scan2_kernel(const int* __restrict__ deg, const int* __restrict__ bsum,
                             int* __restrict__ offsets) {
    __shared__ int lsum[256];
    int b = blockIdx.x, t = threadIdx.x;
    int boff = 0;
    for (int i = 0; i < b; i++) boff += bsum[i];
    int base = b * 1024 + t * 4;
    int4 v = {0, 0, 0, 0};
    if (base + 3 < NN) v = *(const int4*)(deg + base);
    else {
        if (base < NN)     v.x = deg[base];
        if (base + 1 < NN) v.y = deg[base + 1];
        if (base + 2 < NN) v.z = deg[base + 2];
        if (base + 3 < NN) v.w = deg[base + 3];
    }
    int s = v.x + v.y + v.z + v.w;
    lsum[t] = s;
    __syncthreads();
    for (int off = 1; off < 256; off <<= 1) {
        int val = (t >= off) ? lsum[t - off] : 0;
        __syncthreads();
        lsum[t] += val;
        __syncthreads();
    }
    int ex = boff + (t ? lsum[t - 1] : 0);
    if (base < NN)     offsets[base]     = ex;
    if (base + 1 < NN) offsets[base + 1] = ex + v.x;
    if (base + 2 < NN) offsets[base + 2] = ex + v.x + v.y;
    if (base + 3 < NN) offsets[base + 3] = ex + v.x + v.y + v.z;
    if (b == SCB - 1 && t == 255) offsets[NN] = boff + lsum[255];
}

// ---------------------------------------------------------------------------
// fill: CSR scatter + fused layer-1 edge weights.
// ---------------------------------------------------------------------------
__global__ void fill_kernel(const int* __restrict__ ei, const int* __restrict__ offsets,
                            int* __restrict__ cursor,
                            const float* __restrict__ s1, const float* __restrict__ d1,
                            int* __restrict__ elist, int* __restrict__ dstlist,
                            float* __restrict__ welist) {
    int e = blockIdx.x * blockDim.x + threadIdx.x;
    if (e >= EP) return;
    int src, dst;
    if (e < EE) { src = ei[e]; dst = ei[EE + e]; } else { src = dst = e - EE; }
    int pos = atomicAdd(&cursor[dst], 1);
    int j = offsets[dst] + pos;
    elist[j] = src;
    dstlist[j] = dst;
    float4 sv = *(const float4*)(s1 + (size_t)src * 4);
    float4 dv = *(const float4*)(d1 + (size_t)dst * 4);
    float4 w;
    w.x = lrelu_exp(sv.x + dv.x);
    w.y = lrelu_exp(sv.y + dv.y);
    w.z = lrelu_exp(sv.z + dv.z);
    w.w = lrelu_exp(sv.w + dv.w);
    *(float4*)(welist + (size_t)j * 4) = w;
}

// ---------------------------------------------------------------------------
// Edge-parallel weight precompute for layers 2 (H=4) and 3 (H=1).
// ---------------------------------------------------------------------------
__global__ void edge_w4(const int* __restrict__ elist, const int* __restrict__ dstlist,
                        const float* __restrict__ s, const float* __restrict__ d,
                        float* __restrict__ wout) {
    int j = blockIdx.x * blockDim.x + threadIdx.x;
    if (j >= EP) return;
    int src = elist[j], dst = dstlist[j];
    float4 sv = *(const float4*)(s + (size_t)src * 4);
    float4 dv = *(const float4*)(d + (size_t)dst * 4);
    float4 w;
    w.x = lrelu_exp(sv.x + dv.x);
    w.y = lrelu_exp(sv.y + dv.y);
    w.z = lrelu_exp(sv.z + dv.z);
    w.w = lrelu_exp(sv.w + dv.w);
    *(float4*)(wout + (size_t)j * 4) = w;
}

__global__ void edge_w1(const int* __restrict__ elist, const int* __restrict__ dstlist,
                        const float* __restrict__ s, const float* __restrict__ d,
                        float* __restrict__ wout) {
    int j = blockIdx.x * blockDim.x + threadIdx.x;
    if (j >= EP) return;
    wout[j] = lrelu_exp(s[elist[j]] + d[dstlist[j]]);
}

// ---------------------------------------------------------------------------
// Layer-1 FUSED gather + block-diagonal GEMM. One block = 16 nodes = 16 waves.
// Phase 1: wave w gathers node (blk*16+w) -> normalized bf16 fragments in LDS
//          (swizzled row' = row ^ (sub<<2), frag stride 520 -> <=2-way banks).
// Phase 2: wave w = (head hh=w>>2, group g=w&3) computes 2 n-tiles x 4 MFMA
//          from LDS A-frags + packed W1, writes packed pact1 (K=512 layout).
// Removes the 102 MB pagg global round-trip.
// ---------------------------------------------------------------------------
__global__ __launch_bounds__(1024) void l1_fused(
        const int* __restrict__ elist, const int* __restrict__ offsets,
        const float* __restrict__ wl,
        const __hip_bfloat16* __restrict__ xb,
        const __hip_bfloat16* __restrict__ pW1,
        const float* __restrict__ b,
        __hip_bfloat16* __restrict__ pact) {
    __shared__ unsigned short frag[16 * 520];          // 16.6 KB
    int w = threadIdx.x >> 6, lane = threadIdx.x & 63;
    int m0 = blockIdx.x * 16;
    int node = m0 + w;                                  // NN % 16 == 0, always valid

    // ---- phase 1: gather (node-per-wave) ----
    int j0 = __builtin_amdgcn_readfirstlane(offsets[node]);
    int j1 = __builtin_amdgcn_readfirstlane(offsets[node + 1]);
    float den0 = 0.f, den1 = 0.f, den2 = 0.f, den3 = 0.f;
    float a00=0.f,a01=0.f,a10=0.f,a11=0.f,a20=0.f,a21=0.f,a30=0.f,a31=0.f;
    const unsigned short* xp = (const unsigned short*)xb + lane * 2;
    int j = j0;
    for (; j + 4 <= j1; j += 4) {
        int sA = elist[j], sB = elist[j+1], sC = elist[j+2], sD = elist[j+3];
        float4 wA = *(const float4*)(wl + (size_t)j * 4);
        float4 wB = *(const float4*)(wl + (size_t)(j+1) * 4);
        float4 wC = *(const float4*)(wl + (size_t)(j+2) * 4);
        float4 wD = *(const float4*)(wl + (size_t)(j+3) * 4);
        unsigned int xA = *(const unsigned int*)(xp + (size_t)sA * 128);
        unsigned int xB = *(const unsigned int*)(xp + (size_t)sB * 128);
        unsigned int xC = *(const unsigned int*)(xp + (size_t)sC * 128);
        unsigned int xD = *(const unsigned int*)(xp + (size_t)sD * 128);
        float xA0 = us2f((unsigned short)xA), xA1 = us2f((unsigned short)(xA >> 16));
        float xB0 = us2f((unsigned short)xB), xB1 = us2f((unsigned short)(xB >> 16));
        float xC0 = us2f((unsigned short)xC), xC1 = us2f((unsigned short)(xC >> 16));
        float xD0 = us2f((unsigned short)xD), xD1 = us2f((unsigned short)(xD >> 16));
        den0 += (wA.x + wB.x) + (wC.x + wD.x);
        den1 += (wA.y + wB.y) + (wC.y + wD.y);
        den2 += (wA.z + wB.z) + (wC.z + wD.z);
        den3 += (wA.w + wB.w) + (wC.w + wD.w);
        a00 += wA.x*xA0 + wB.x*xB0 + wC.x*xC0 + wD.x*xD0;
        a01 += wA.x*xA1 + wB.x*xB1 + wC.x*xC1 + wD.x*xD1;
        a10 += wA.y*xA0 + wB.y*xB0 + wC.y*xC0 + wD.y*xD0;
        a11 += wA.y*xA1 + wB.y*xB1 + wC.y*xC1 + wD.y*xD1;
        a20 += wA.z*xA0 + wB.z*xB0 + wC.z*xC0 + wD.z*xD0;
        a21 += wA.z*xA1 + wB.z*xB1 + wC.z*xC1 + wD.z*xD1;
        a30 += wA.w*xA0 + wB.w*xB0 + wC.w*xC0 + wD.w*xD0;
        a31 += wA.w*xA1 + wB.w*xB1 + wC.w*xC1 + wD.w*xD1;
    }
    for (; j < j1; j++) {
        int sE = elist[j];
        float4 ww = *(const float4*)(wl + (size_t)j * 4);
        unsigned int xv = *(const unsigned int*)(xp + (size_t)sE * 128);
        float x0 = us2f((unsigned short)xv), x1 = us2f((unsigned short)(xv >> 16));
        den0 += ww.x; den1 += ww.y; den2 += ww.z; den3 += ww.w;
        a00 += ww.x*x0; a01 += ww.x*x1; a10 += ww.y*x0; a11 += ww.y*x1;
        a20 += ww.z*x0; a21 += ww.z*x1; a30 += ww.w*x0; a31 += ww.w*x1;
    }
    {
        int c0 = lane * 2;
        int fq = c0 >> 5;                    // within-head frag index
        int sub = (c0 & 31) >> 3;
        int rowp = w ^ (sub << 2);           // bank swizzle (bijective per sub)
        float i0 = 1.f/den0, i1 = 1.f/den1, i2 = 1.f/den2, i3 = 1.f/den3;
        unsigned int* f32p = (unsigned int*)frag;
        int base = (fq * 520 + sub * 128 + rowp * 8 + (c0 & 7)) >> 1;  // uint idx
        f32p[base]             = pack2bf(a00*i0, a01*i0);   // hh=0 frag fq
        f32p[base + 4 * 260]   = pack2bf(a10*i1, a11*i1);   // hh=1
        f32p[base + 8 * 260]   = pack2bf(a20*i2, a21*i2);   // hh=2
        f32p[base + 12 * 260]  = pack2bf(a30*i3, a31*i3);   // hh=3
    }
    __syncthreads();

    // ---- phase 2: block-diagonal GEMM from LDS ----
    int hh = w >> 2, g = w & 3;
    int r = lane & 15, quad = lane >> 4;
    int lsub = lane >> 4, lrow = lane & 15;
    int prow = lrow ^ (lsub << 2);
    const unsigned short* fb = frag + lsub * 128 + prow * 8;
    short8 afrag[4];
#pragma unroll
    for (int kk = 0; kk < 4; kk++)
        afrag[kk] = *(const short8*)(fb + (hh * 4 + kk) * 520);
#pragma unroll
    for (int t = 0; t < 2; t++) {
        int nb = g * 32 + t * 16;
        const __hip_bfloat16* bp = pW1 + ((size_t)(hh * 8 + (nb >> 4)) * 4) * 512 + lane * 8;
        f32x4 acc = {0.f, 0.f, 0.f, 0.f};
#pragma unroll
        for (int kk = 0; kk < 4; kk++) {
            short8 bfr = *(const short8*)(bp + kk * 512);
            acc = __builtin_amdgcn_mfma_f32_16x16x32_bf16(afrag[kk], bfr, acc, 0, 0, 0);
        }
        int n0 = hh * 128 + nb;
        float bias = b[n0 + r];
        int kk2 = (n0 + r) >> 5;
        int sub2 = ((nb & 16) + r) >> 3;
        __hip_bfloat16* op = pact + ((size_t)blockIdx.x * 16 + kk2) * 512
                           + sub2 * 128 + (r & 7);
#pragma unroll
        for (int i = 0; i < 4; i++) {
            float v = acc[i] + bias;
            v = v > 0.f ? v : (__expf(v) - 1.0f);
            op[(quad * 4 + i) * 8] = __float2bfloat16(v);
        }
    }
}

// ---------------------------------------------------------------------------
// Layer-2 GEMM, wave-per-head, packed A and W; fused s2/d2 epilogue.
// h2 written row-major [N][128].
// ---------------------------------------------------------------------------
__global__ void gemm_l2(const __hip_bfloat16* __restrict__ pA,
                        const __hip_bfloat16* __restrict__ pW2,
                        const float* __restrict__ as_, const float* __restrict__ ad_,
                        __hip_bfloat16* __restrict__ Cb,
                        float* __restrict__ s, float* __restrict__ d, int M) {
    int hh = threadIdx.x >> 6, lane = threadIdx.x & 63;
    int m0 = blockIdx.x * 16;
    int r = lane & 15, quad = lane >> 4;
    const __hip_bfloat16* ap  = pA + (size_t)(m0 >> 4) * 16 * 512 + lane * 8;
    const __hip_bfloat16* bp0 = pW2 + (size_t)(hh * 2) * 16 * 512 + lane * 8;
    const __hip_bfloat16* bp1 = bp0 + 16 * 512;
    f32x4 acc0 = {0.f, 0.f, 0.f, 0.f}, acc1 = {0.f, 0.f, 0.f, 0.f};
#pragma unroll
    for (int kk = 0; kk < 16; kk++) {
        short8 af = *(const short8*)(ap + kk * 512);
        short8 b0 = *(const short8*)(bp0 + kk * 512);
        short8 b1 = *(const short8*)(bp1 + kk * 512);
        acc0 = __builtin_amdgcn_mfma_f32_16x16x32_bf16(af, b0, acc0, 0, 0, 0);
        acc1 = __builtin_amdgcn_mfma_f32_16x16x32_bf16(af, b1, acc1, 0, 0, 0);
    }
    int n0 = hh * 32;
    float as0 = as_[n0 + r],      ad0 = ad_[n0 + r];
    float as1 = as_[n0 + 16 + r], ad1 = ad_[n0 + 16 + r];
    float sacc[4], dacc[4];
#pragma unroll
    for (int i = 0; i < 4; i++) {
        int m = m0 + quad * 4 + i;
        Cb[(size_t)m * 128 + n0 + r]      = __float2bfloat16(acc0[i]);
        Cb[(size_t)m * 128 + n0 + 16 + r] = __float2bfloat16(acc1[i]);
        sacc[i] = acc0[i] * as0 + acc1[i] * as1;
        dacc[i] = acc0[i] * ad0 + acc1[i] * ad1;
    }
#pragma unroll
    for (int mask = 1; mask <= 8; mask <<= 1) {
#pragma unroll
        for (int i = 0; i < 4; i++) {
            sacc[i] += __shfl_xor(sacc[i], mask, 64);
            dacc[i] += __shfl_xor(dacc[i], mask, 64);
        }
    }
    if (r == 0) {
#pragma unroll
        for (int i = 0; i < 4; i++) {
            int m = m0 + quad * 4 + i;
            s[m * 4 + hh] = sacc[i]; d[m * 4 + hh] = dacc[i];
        }
    }
}

// ---------------------------------------------------------------------------
// Layer-2 gather FUSED with layer-3 GEMM: node-per-wave; lane owns 2 act2
// channels (never materialized to global). After gather+ELU, lane computes
// its 2-channel partial of h3 = act2 . W3^T (8 outputs) and a 64-lane
// butterfly reduce yields h3 + s3/d3 directly. Removes act2 + gemm8.
// ---------------------------------------------------------------------------
__global__ void gather_l2_g8(const int* __restrict__ elist, const int* __restrict__ offsets,
                             const float* __restrict__ wl,
                             const __hip_bfloat16* __restrict__ h,
                             const float* __restrict__ b,
                             const float* __restrict__ W3,
                             const float* __restrict__ a3s, const float* __restrict__ a3d,
                             __hip_bfloat16* __restrict__ h3,
                             float* __restrict__ s, float* __restrict__ d) {
    int gid = blockIdx.x * blockDim.x + threadIdx.x;
    if (gid >= NN * 64) return;
    int node = gid >> 6;
    int lane = gid & 63;
    int c0 = lane * 2;
    int hh = lane >> 4;
    int j0 = __builtin_amdgcn_readfirstlane(offsets[node]);
    int j1 = __builtin_amdgcn_readfirstlane(offsets[node + 1]);
    float den = 0.f, acc0 = 0.f, acc1 = 0.f;
    const unsigned short* hp = (const unsigned short*)h + c0;
    int j = j0;
    for (; j + 4 <= j1; j += 4) {
        int sA = elist[j], sB = elist[j+1], sC = elist[j+2], sD = elist[j+3];
        float wA = wl[(size_t)j*4 + hh],     wB = wl[(size_t)(j+1)*4 + hh];
        float wC = wl[(size_t)(j+2)*4 + hh], wD = wl[(size_t)(j+3)*4 + hh];
        unsigned int vA = *(const unsigned int*)(hp + (size_t)sA * 128);
        unsigned int vB = *(const unsigned int*)(hp + (size_t)sB * 128);
        unsigned int vC = *(const unsigned int*)(hp + (size_t)sC * 128);
        unsigned int vD = *(const unsigned int*)(hp + (size_t)sD * 128);
        den += (wA + wB) + (wC + wD);
        acc0 += wA * us2f((unsigned short)vA) + wB * us2f((unsigned short)vB)
              + wC * us2f((unsigned short)vC) + wD * us2f((unsigned short)vD);
        acc1 += wA * us2f((unsigned short)(vA >> 16)) + wB * us2f((unsigned short)(vB >> 16))
              + wC * us2f((unsigned short)(vC >> 16)) + wD * us2f((unsigned short)(vD >> 16));
    }
    for (; j < j1; j++) {
        int sE = elist[j];
        float ww = wl[(size_t)j*4 + hh];
        unsigned int v = *(const unsigned int*)(hp + (size_t)sE * 128);
        den += ww;
        acc0 += ww * us2f((unsigned short)v);
        acc1 += ww * us2f((unsigned short)(v >> 16));
    }
    float inv = 1.0f / den;
    float v0 = acc0 * inv + b[c0];
    float v1 = acc1 * inv + b[c0 + 1];
    v0 = v0 > 0.f ? v0 : (__expf(v0) - 1.0f);
    v1 = v1 > 0.f ? v1 : (__expf(v1) - 1.0f);
    // fused layer-3 GEMM: part[c] = v0*W3[c][c0] + v1*W3[c][c0+1], reduce over lanes
    float part[8];
#pragma unroll
    for (int c = 0; c < 8; c++) {
        float2 wv = *(const float2*)(W3 + c * 128 + c0);
        part[c] = v0 * wv.x + v1 * wv.y;
    }
#pragma unroll
    for (int mask = 1; mask < 64; mask <<= 1) {
#pragma unroll
        for (int c = 0; c < 8; c++) part[c] += __shfl_xor(part[c], mask, 64);
    }
    if (lane < 8) h3[(size_t)node * 8 + lane] = __float2bfloat16(part[lane]);
    if (lane == 0) {
        float sv = 0.f, dv = 0.f;
#pragma unroll
        for (int c = 0; c < 8; c++) { sv += part[c] * a3s[c]; dv += part[c] * a3d[c]; }
        s[node] = sv; d[node] = dv;
    }
}

// ---------------------------------------------------------------------------
// Layer-3 gather: 8 lanes/node, lane owns 1 channel; weights from welist.
// ---------------------------------------------------------------------------
__global__ void gather_l3(const int* __restrict__ elist, const int* __restrict__ offsets,
                          const float* __restrict__ wl,
                          const __hip_bfloat16* __restrict__ h,
                          const float* __restrict__ b,
                          __hip_bfloat16* __restrict__ act) {
    int gid = blockIdx.x * blockDim.x + threadIdx.x;
    if (gid >= NN * 8) return;
    int node = gid >> 3, t = gid & 7;
    int j0 = offsets[node], j1 = offsets[node + 1];
    float den = 0.f, acc = 0.f;
    const unsigned short* hp = (const unsigned short*)h + t;
    int j = j0;
    for (; j + 4 <= j1; j += 4) {
        int sA = elist[j], sB = elist[j+1], sC = elist[j+2], sD = elist[j+3];
        float wA = wl[j], wB = wl[j+1], wC = wl[j+2], wD = wl[j+3];
        float xA = us2f(hp[(size_t)sA * 8]);
        float xB = us2f(hp[(size_t)sB * 8]);
        float xC = us2f(hp[(size_t)sC * 8]);
        float xD = us2f(hp[(size_t)sD * 8]);
        den += (wA + wB) + (wC + wD);
        acc += wA * xA + wB * xB + wC * xC + wD * xD;
    }
    for (; j < j1; j++) {
        int sE = elist[j];
        float w = wl[j];
        den += w;
        acc += w * us2f(hp[(size_t)sE * 8]);
    }
    float v = acc / den + b[t];
    v = v > 0.f ? v : (__expf(v) - 1.0f);
    act[(size_t)node * 8 + t] = __float2bfloat16(v);
}

// ---------------------------------------------------------------------------
// Final edge MLP: z[19] = [h3[src], h3[dst], ea, yr, qt] -> fc1(relu) -> fc2
// ---------------------------------------------------------------------------
__global__ void mlp_kernel(const int* __restrict__ ei,
                           const __hip_bfloat16* __restrict__ act3,
                           const float* __restrict__ ea,
                           const float* __restrict__ yr,
                           const float* __restrict__ qt,
                           const float* __restrict__ fc1w,
                           const float* __restrict__ fc1b,
                           const float* __restrict__ fc2w,
                           const float* __restrict__ fc2b,
                           float* __restrict__ outp) {
    __shared__ float w1[16 * 19], b1s[16], w2[16];
    for (int i = threadIdx.x; i < 16 * 19; i += blockDim.x) w1[i] = fc1w[i];
    if (threadIdx.x < 16) {
        b1s[threadIdx.x] = fc1b[threadIdx.x];
        w2[threadIdx.x] = fc2w[threadIdx.x];
    }
    __syncthreads();
    int e = blockIdx.x * blockDim.x + threadIdx.x;
    if (e >= EE) return;
    int src = ei[e], dst = ei[EE + e];
    short8 hs = *(const short8*)(act3 + (size_t)src * 8);
    short8 hd = *(const short8*)(act3 + (size_t)dst * 8);
    float z[19];
#pragma unroll
    for (int i = 0; i < 8; i++) z[i] = us2f((unsigned short)hs[i]);
#pragma unroll
    for (int i = 0; i < 8; i++) z[8 + i] = us2f((unsigned short)hd[i]);
    z[16] = ea[e]; z[17] = yr[e]; z[18] = qt[e];
    float acc2 = fc2b[0];
#pragma unroll
    for (int j = 0; j < 16; j++) {
        float a = b1s[j];
#pragma unroll
        for (int i = 0; i < 19; i++) a += z[i] * w1[j * 19 + i];
        a = a > 0.f ? a : 0.f;
        acc2 += a * w2[j];
    }
    outp[e] = acc2;
}

// ---------------------------------------------------------------------------
extern "C" void kernel_launch(void* const* d_in, const int* in_sizes, int n_in,
                              void* d_out, int out_size, void* d_ws, size_t ws_size,
                              hipStream_t stream) {
    const float* x    = (const float*)d_in[0];
    const int*   ei   = (const int*)d_in[1];
    const float* ea   = (const float*)d_in[2];
    const float* yr   = (const float*)d_in[3];
    const float* qt   = (const float*)d_in[4];
    const float* W1   = (const float*)d_in[5];
    const float* a1s  = (const float*)d_in[6];
    const float* a1d  = (const float*)d_in[7];
    const float* b1   = (const float*)d_in[8];
    const float* W2   = (const float*)d_in[9];
    const float* a2s  = (const float*)d_in[10];
    const float* a2d  = (const float*)d_in[11];
    const float* b2   = (const float*)d_in[12];
    const float* W3   = (const float*)d_in[13];
    const float* a3s  = (const float*)d_in[14];
    const float* a3d  = (const float*)d_in[15];
    const float* b3   = (const float*)d_in[16];
    const float* fc1w = (const float*)d_in[17];
    const float* fc1b = (const float*)d_in[18];
    const float* fc2w = (const float*)d_in[19];
    const float* fc2b = (const float*)d_in[20];
    float* outp = (float*)d_out;

    char* ws = (char*)d_ws;
    __hip_bfloat16* h_buf   = (__hip_bfloat16*)(ws);                 // N*512 bf16: pact1 / h3
    __hip_bfloat16* act_buf = (__hip_bfloat16*)(ws + 51200000);      // N*512 bf16: xb / h2 / act3
    float* s_buf   = (float*)(ws + 102400000);                       // N*4 f32: s1/s2/s3
    float* d_buf   = (float*)(ws + 103200000);                       // N*4 f32: d1/d2/d3
    int*   deg     = (int*)  (ws + 104000000);                       // N ints
    int*   cursor  = (int*)  (ws + 104200000);                       // N ints (contiguous w/ deg)
    int*   offsets = (int*)  (ws + 104400000);                       // N+1 ints
    int*   elist   = (int*)  (ws + 104600016);                       // EP ints (1.8 MB)
    __hip_bfloat16* pw1 = (__hip_bfloat16*)(ws + 106400016);         // 512*128 bf16 packed
    __hip_bfloat16* pw2 = (__hip_bfloat16*)(ws + 106531088);         // 128*512 bf16 packed
    float* usd  = (float*)(ws + 106662160);                          // 8*128 f32 (4 KB)
    int*   bsum = (int*)  (ws + 106666256);                          // SCB ints
    float* welist = (float*)(ws + 106666512);                        // EP*4 f32 (7.2 MB)
    int*   dstlist = (int*)(ws + 113866512);                         // EP ints (1.8 MB)
    __hip_bfloat16* xb = act_buf;                                    // N*128 bf16, dead after l1_fused

    // ---- prep (deg + weight pack + usd) + CSR scan ----
    hipMemsetAsync(deg, 0, 2 * NN * sizeof(int), stream);            // deg + cursor
    prep_kernel<<<DEGB + CVTB + 4, 256, 0, stream>>>(ei, deg, W1, W2, pw1, pw2, a1s, a1d, usd);
    scan1_kernel<<<SCB, 256, 0, stream>>>(deg, bsum);
    scan2_kernel<<<SCB, 256, 0, stream>>>(deg, bsum, offsets);
    cvtx_sd<<<(NN + 63) / 64, 256, 0, stream>>>(x, usd, xb, s_buf, d_buf, NN);
    fill_kernel<<<(EP + 255) / 256, 256, 0, stream>>>(ei, offsets, cursor, s_buf, d_buf,
                                                      elist, dstlist, welist);

    // ---- Layer 1: fused gather + block-diag GEMM (pact1 -> h_buf) ----
    l1_fused<<<NN / 16, 1024, 0, stream>>>(elist, offsets, welist, xb, pw1, b1, h_buf);

    // ---- Layer 2: GEMM (pact1 -> h2 in act_buf) -> edge weights ----
    gemm_l2<<<(NN + 15) / 16, 256, 0, stream>>>(
        h_buf, pw2, a2s, a2d, act_buf, s_buf, d_buf, NN);
    edge_w4<<<(EP + 255) / 256, 256, 0, stream>>>(elist, dstlist, s_buf, d_buf, welist);

    // ---- Layer-2 gather fused with layer-3 GEMM (h3 -> h_buf, s3/d3) ----
    gather_l2_g8<<<(NN * 64 + 255) / 256, 256, 0, stream>>>(
        elist, offsets, welist, act_buf, b2, W3, a3s, a3d, h_buf, s_buf, d_buf);

    // ---- Layer 3: edge weights -> gather (act3 -> act_buf) ----
    edge_w1<<<(EP + 255) / 256, 256, 0, stream>>>(elist, dstlist, s_buf, d_buf, welist);
    gather_l3<<<(NN * 8 + 255) / 256, 256, 0, stream>>>(
        elist, offsets, welist, h_buf, b3, act_buf);

    // ---- Final edge MLP ----
    mlp_kernel<<<(EE + 255) / 256, 256, 0, stream>>>(ei, act_buf, ea, yr, qt,
                                                     fc1w, fc1b, fc2w, fc2b, outp);
}

// Round 9
// 298.793 us; speedup vs baseline: 1.1128x; 1.0321x over previous
//
#include <hip/hip_runtime.h>
#include <hip/hip_bf16.h>

#define NN 50000
#define EE 400000
#define EP 450000   // EE + NN self-loops

typedef __attribute__((ext_vector_type(8))) short short8;
typedef __attribute__((ext_vector_type(4))) float f32x4;

__device__ __forceinline__ float us2f(unsigned short u) {
    unsigned int x = ((unsigned int)u) << 16;
    union { unsigned int i; float f; } c; c.i = x; return c.f;
}
__device__ __forceinline__ unsigned short f2bfu(float f) {   // f32 -> bf16 bits, RNE
    union { float f; unsigned int u; } c; c.f = f;
    unsigned int r = c.u + 0x7FFFu + ((c.u >> 16) & 1u);
    return (unsigned short)(r >> 16);
}
__device__ __forceinline__ unsigned int pack2bf(float lo, float hi) {
    return (unsigned int)f2bfu(lo) | ((unsigned int)f2bfu(hi) << 16);
}
__device__ __forceinline__ float lrelu_exp(float x) {
    x = x > 0.f ? x : 0.2f * x;
    return __expf(x);
}

// Packed MFMA-fragment index for a [M x K] bf16 matrix consumed as A (or B with
// n in place of m) by mfma_f32_16x16x32_bf16:
//   idx(m,k) = ((m>>4)*(K/32) + (k>>5))*512 + ((k&31)>>3)*128 + (m&15)*8 + (k&7)

// ---------------------------------------------------------------------------
// prep: fused deg histogram + W1/W2 f32->bf16 packed convert + usd precompute.
// ---------------------------------------------------------------------------
#define DEGB 1758
#define CVTB 512
__global__ void prep_kernel(const int* __restrict__ ei, int* __restrict__ deg,
                            const float* __restrict__ W1, const float* __restrict__ W2,
                            __hip_bfloat16* __restrict__ pw1, __hip_bfloat16* __restrict__ pw2,
                            const float* __restrict__ a1s, const float* __restrict__ a1d,
                            float* __restrict__ usd) {
    int b = blockIdx.x;
    if (b < DEGB) {
        int e = b * 256 + threadIdx.x;
        if (e >= EP) return;
        int dst = (e < EE) ? ei[EE + e] : e - EE;
        atomicAdd(&deg[dst], 1);
    } else if (b < DEGB + CVTB) {
        int i = (b - DEGB) * 256 + threadIdx.x;
        if (i < 65536) {
            int n = i >> 7, k = i & 127;   // K=128, NK=4
            int idx = ((n >> 4) * 4 + (k >> 5)) * 512 + ((k & 31) >> 3) * 128 + (n & 15) * 8 + (k & 7);
            pw1[idx] = __float2bfloat16(W1[i]);
        } else {
            int j = i - 65536;
            int n = j >> 9, k = j & 511;   // K=512, NK=16
            int idx = ((n >> 4) * 16 + (k >> 5)) * 512 + ((k & 31) >> 3) * 128 + (n & 15) * 8 + (k & 7);
            pw2[idx] = __float2bfloat16(W2[j]);
        }
    } else {
        int t = (b - DEGB - CVTB) * 256 + threadIdx.x;
        if (t >= 1024) return;
        int row = t >> 7, k = t & 127;
        int hh = row & 3;
        const float* av = (row < 4) ? (a1s + hh * 128) : (a1d + hh * 128);
        const float* wp = W1 + (size_t)(hh * 128) * 128 + k;
        float acc = 0.f;
        for (int c = 0; c < 128; c++) acc += av[c] * wp[(size_t)c * 128];
        usd[t] = acc;
    }
}

// ---------------------------------------------------------------------------
// Fused: x (f32) -> xb (bf16) convert + s1/d1 = x . usd.
// ---------------------------------------------------------------------------
__global__ void cvtx_sd(const float* __restrict__ x, const float* __restrict__ usd,
                        __hip_bfloat16* __restrict__ xb,
                        float* __restrict__ s, float* __restrict__ d, int M) {
    __shared__ float us_s[1024];
    for (int i = threadIdx.x; i < 1024; i += 256) us_s[i] = usd[i];
    __syncthreads();
    int wave = threadIdx.x >> 6, lane = threadIdx.x & 63;
    int m0 = blockIdx.x * 64 + wave * 16;
    int r = lane & 15, quad = lane >> 4;
    int am = m0 + r; if (am >= M) am = M - 1;
    const float* xp = x + (size_t)am * 128 + quad * 8;
    float xv[32];
#pragma unroll
    for (int kk = 0; kk < 4; kk++) {
        float4 a = *(const float4*)(xp + kk * 32);
        float4 bq = *(const float4*)(xp + kk * 32 + 4);
        xv[kk*8+0]=a.x;  xv[kk*8+1]=a.y;  xv[kk*8+2]=a.z;  xv[kk*8+3]=a.w;
        xv[kk*8+4]=bq.x; xv[kk*8+5]=bq.y; xv[kk*8+6]=bq.z; xv[kk*8+7]=bq.w;
        short8 o;
        o[0]=(short)f2bfu(a.x);  o[1]=(short)f2bfu(a.y);
        o[2]=(short)f2bfu(a.z);  o[3]=(short)f2bfu(a.w);
        o[4]=(short)f2bfu(bq.x); o[5]=(short)f2bfu(bq.y);
        o[6]=(short)f2bfu(bq.z); o[7]=(short)f2bfu(bq.w);
        *(short8*)(xb + (size_t)am * 128 + quad * 8 + kk * 32) = o;
    }
    float acc[8];
#pragma unroll
    for (int o = 0; o < 8; o++) {
        const float* up = us_s + o * 128 + quad * 8;
        float a = 0.f;
#pragma unroll
        for (int kk = 0; kk < 4; kk++)
#pragma unroll
            for (int j = 0; j < 8; j++) a += xv[kk*8+j] * up[kk*32+j];
        acc[o] = a;
    }
#pragma unroll
    for (int o = 0; o < 8; o++) {
        acc[o] += __shfl_xor(acc[o], 16, 64);
        acc[o] += __shfl_xor(acc[o], 32, 64);
    }
    int m = m0 + r;
    if (quad == 0 && m < M) {
#pragma unroll
        for (int hh = 0; hh < 4; hh++) { s[m*4+hh] = acc[hh]; d[m*4+hh] = acc[4+hh]; }
    }
}

// ---------------------------------------------------------------------------
// Two-level multi-block scan of deg -> offsets
// ---------------------------------------------------------------------------
#define SCB 49
__global__ void scan1_kernel(const int* __restrict__ deg, int* __restrict__ bsum) {
    __shared__ int red[256];
    int b = blockIdx.x, t = threadIdx.x;
    int base = b * 1024 + t * 4;
    int s = 0;
    if (base + 3 < NN) { int4 v = *(const int4*)(deg + base); s = v.x + v.y + v.z + v.w; }
    else { for (int i = base; i < NN; i++) s += deg[i]; }
    red[t] = s;
    __syncthreads();
    for (int off = 128; off > 0; off >>= 1) {
        if (t < off) red[t] += red[t + off];
        __syncthreads();
    }
    if (t == 0) bsum[b] = red[0];
}

__global__ void scan2_kernel(const int* __restrict__ deg, const int* __restrict__ bsum,
                             int* __restrict__ offsets) {
    __shared__ int lsum[256];
    int b = blockIdx.x, t = threadIdx.x;
    int boff = 0;
    for (int i = 0; i < b; i++) boff += bsum[i];
    int base = b * 1024 + t * 4;
    int4 v = {0, 0, 0, 0};
    if (base + 3 < NN) v = *(const int4*)(deg + base);
    else {
        if (base < NN)     v.x = deg[base];
        if (base + 1 < NN) v.y = deg[base + 1];
        if (base + 2 < NN) v.z = deg[base + 2];
        if (base + 3 < NN) v.w = deg[base + 3];
    }
    int s = v.x + v.y + v.z + v.w;
    lsum[t] = s;
    __syncthreads();
    for (int off = 1; off < 256; off <<= 1) {
        int val = (t >= off) ? lsum[t - off] : 0;
        __syncthreads();
        lsum[t] += val;
        __syncthreads();
    }
    int ex = boff + (t ? lsum[t - 1] : 0);
    if (base < NN)     offsets[base]     = ex;
    if (base + 1 < NN) offsets[base + 1] = ex + v.x;
    if (base + 2 < NN) offsets[base + 2] = ex + v.x + v.y;
    if (base + 3 < NN) offsets[base + 3] = ex + v.x + v.y + v.z;
    if (b == SCB - 1 && t == 255) offsets[NN] = boff + lsum[255];
}

// ---------------------------------------------------------------------------
// fill: CSR scatter + fused layer-1 edge weights (s1/d1 already computed).
// ---------------------------------------------------------------------------
__global__ void fill_kernel(const int* __restrict__ ei, const int* __restrict__ offsets,
                            int* __restrict__ cursor,
                            const float* __restrict__ s1, const float* __restrict__ d1,
                            int* __restrict__ elist, float* __restrict__ welist) {
    int e = blockIdx.x * blockDim.x + threadIdx.x;
    if (e >= EP) return;
    int src, dst;
    if (e < EE) { src = ei[e]; dst = ei[EE + e]; } else { src = dst = e - EE; }
    int pos = atomicAdd(&cursor[dst], 1);
    int j = offsets[dst] + pos;
    elist[j] = src;
    float4 sv = *(const float4*)(s1 + (size_t)src * 4);
    float4 dv = *(const float4*)(d1 + (size_t)dst * 4);
    float4 w;
    w.x = lrelu_exp(sv.x + dv.x);
    w.y = lrelu_exp(sv.y + dv.y);
    w.z = lrelu_exp(sv.z + dv.z);
    w.w = lrelu_exp(sv.w + dv.w);
    *(float4*)(welist + (size_t)j * 4) = w;
}

// ---------------------------------------------------------------------------
// Edge accumulate helper for layer-1 gather (4 heads x 2 channels per lane).
// ---------------------------------------------------------------------------
__device__ __forceinline__ void acc_edge(float (&den)[4], float (&acc)[8],
                                         float4 w, unsigned int x) {
    float x0 = us2f((unsigned short)x), x1 = us2f((unsigned short)(x >> 16));
    den[0] += w.x; den[1] += w.y; den[2] += w.z; den[3] += w.w;
    acc[0] += w.x * x0; acc[1] += w.x * x1;
    acc[2] += w.y * x0; acc[3] += w.y * x1;
    acc[4] += w.z * x0; acc[5] += w.z * x1;
    acc[6] += w.w * x0; acc[7] += w.w * x1;
}

// ---------------------------------------------------------------------------
// Layer-1 FUSED gather + block-diagonal GEMM. 512 threads = 8 waves = 16 nodes.
// Phase 1: wave w gathers nodes (blk*16 + 2w, +2w+1) via dual-pointer loop
//          (CSR ranges are adjacent) -> 4 independent edge chains in flight.
//          Normalized bf16 fragments -> LDS (swizzled, stride 520).
// Phase 2: wave w = (head hh=w>>1, half=w&1) computes 4 n-tiles x 4 MFMA,
//          writes packed pact1 (K=512 layout). 50000/16 = 3125 blocks exact.
// ---------------------------------------------------------------------------
__global__ void l1_fused(
        const int* __restrict__ elist, const int* __restrict__ offsets,
        const float* __restrict__ wl,
        const __hip_bfloat16* __restrict__ xb,
        const __hip_bfloat16* __restrict__ pW1,
        const float* __restrict__ b,
        __hip_bfloat16* __restrict__ pact) {
    __shared__ unsigned short frag[16 * 520];          // 16.6 KB
    int w = threadIdx.x >> 6, lane = threadIdx.x & 63;
    int m0 = blockIdx.x * 16;
    int nA = m0 + 2 * w;                                // rows 2w, 2w+1

    int ja  = __builtin_amdgcn_readfirstlane(offsets[nA]);
    int jA1 = __builtin_amdgcn_readfirstlane(offsets[nA + 1]);
    int jB1 = __builtin_amdgcn_readfirstlane(offsets[nA + 2]);
    int jb = jA1;

    float dA[4] = {0.f,0.f,0.f,0.f}, dB[4] = {0.f,0.f,0.f,0.f};
    float aA[8] = {0.f,0.f,0.f,0.f,0.f,0.f,0.f,0.f};
    float aB[8] = {0.f,0.f,0.f,0.f,0.f,0.f,0.f,0.f};
    const unsigned short* xp = (const unsigned short*)xb + lane * 2;
    const float4* wl4 = (const float4*)wl;

    // dual-chain main loop: 2 edges of A + 2 edges of B in flight
    while (ja + 2 <= jA1 && jb + 2 <= jB1) {
        int s0 = elist[ja], s1 = elist[ja + 1];
        int s2 = elist[jb], s3 = elist[jb + 1];
        float4 w0 = wl4[ja], w1 = wl4[ja + 1];
        float4 w2 = wl4[jb], w3 = wl4[jb + 1];
        unsigned int x0 = *(const unsigned int*)(xp + (size_t)s0 * 128);
        unsigned int x1 = *(const unsigned int*)(xp + (size_t)s1 * 128);
        unsigned int x2 = *(const unsigned int*)(xp + (size_t)s2 * 128);
        unsigned int x3 = *(const unsigned int*)(xp + (size_t)s3 * 128);
        acc_edge(dA, aA, w0, x0); acc_edge(dA, aA, w1, x1);
        acc_edge(dB, aB, w2, x2); acc_edge(dB, aB, w3, x3);
        ja += 2; jb += 2;
    }
    while (ja + 2 <= jA1) {
        int s0 = elist[ja], s1 = elist[ja + 1];
        float4 w0 = wl4[ja], w1 = wl4[ja + 1];
        unsigned int x0 = *(const unsigned int*)(xp + (size_t)s0 * 128);
        unsigned int x1 = *(const unsigned int*)(xp + (size_t)s1 * 128);
        acc_edge(dA, aA, w0, x0); acc_edge(dA, aA, w1, x1);
        ja += 2;
    }
    while (jb + 2 <= jB1) {
        int s0 = elist[jb], s1 = elist[jb + 1];
        float4 w0 = wl4[jb], w1 = wl4[jb + 1];
        unsigned int x0 = *(const unsigned int*)(xp + (size_t)s0 * 128);
        unsigned int x1 = *(const unsigned int*)(xp + (size_t)s1 * 128);
        acc_edge(dB, aB, w0, x0); acc_edge(dB, aB, w1, x1);
        jb += 2;
    }
    if (ja < jA1) {
        int s0 = elist[ja]; float4 w0 = wl4[ja];
        unsigned int x0 = *(const unsigned int*)(xp + (size_t)s0 * 128);
        acc_edge(dA, aA, w0, x0);
    }
    if (jb < jB1) {
        int s0 = elist[jb]; float4 w0 = wl4[jb];
        unsigned int x0 = *(const unsigned int*)(xp + (size_t)s0 * 128);
        acc_edge(dB, aB, w0, x0);
    }

    // store both nodes' normalized fragments to LDS (swizzled)
    {
        int c0 = lane * 2;
        int fq = c0 >> 5;
        int sub = (c0 & 31) >> 3;
        unsigned int* f32p = (unsigned int*)frag;
        int base0 = fq * 260 + sub * 64 + (c0 & 7) / 2;   // uint units (520sh=260u,128sh=64u,8sh=4u)
        {
            int rowp = (2 * w) ^ (sub << 2);
            int base = base0 + rowp * 4;
            float i0 = 1.f/dA[0], i1 = 1.f/dA[1], i2 = 1.f/dA[2], i3 = 1.f/dA[3];
            f32p[base]            = pack2bf(aA[0]*i0, aA[1]*i0);
            f32p[base + 4 * 260]  = pack2bf(aA[2]*i1, aA[3]*i1);
            f32p[base + 8 * 260]  = pack2bf(aA[4]*i2, aA[5]*i2);
            f32p[base + 12 * 260] = pack2bf(aA[6]*i3, aA[7]*i3);
        }
        {
            int rowp = (2 * w + 1) ^ (sub << 2);
            int base = base0 + rowp * 4;
            float i0 = 1.f/dB[0], i1 = 1.f/dB[1], i2 = 1.f/dB[2], i3 = 1.f/dB[3];
            f32p[base]            = pack2bf(aB[0]*i0, aB[1]*i0);
            f32p[base + 4 * 260]  = pack2bf(aB[2]*i1, aB[3]*i1);
            f32p[base + 8 * 260]  = pack2bf(aB[4]*i2, aB[5]*i2);
            f32p[base + 12 * 260] = pack2bf(aB[6]*i3, aB[7]*i3);
        }
    }
    __syncthreads();

    // ---- phase 2: block-diagonal GEMM from LDS ----
    int hh = w >> 1, half = w & 1;
    int r = lane & 15, quad = lane >> 4;
    int lsub = lane >> 4, lrow = lane & 15;
    int prow = lrow ^ (lsub << 2);
    const unsigned short* fb = frag + lsub * 128 + prow * 8;
    short8 afrag[4];
#pragma unroll
    for (int kk = 0; kk < 4; kk++)
        afrag[kk] = *(const short8*)(fb + (hh * 4 + kk) * 520);
#pragma unroll
    for (int t = 0; t < 4; t++) {
        int nb = half * 64 + t * 16;
        const __hip_bfloat16* bp = pW1 + ((size_t)(hh * 8 + (nb >> 4)) * 4) * 512 + lane * 8;
        f32x4 acc = {0.f, 0.f, 0.f, 0.f};
#pragma unroll
        for (int kk = 0; kk < 4; kk++) {
            short8 bfr = *(const short8*)(bp + kk * 512);
            acc = __builtin_amdgcn_mfma_f32_16x16x32_bf16(afrag[kk], bfr, acc, 0, 0, 0);
        }
        int n0 = hh * 128 + nb;
        float bias = b[n0 + r];
        int kk2 = (n0 + r) >> 5;
        int sub2 = ((nb & 16) + r) >> 3;
        __hip_bfloat16* op = pact + ((size_t)blockIdx.x * 16 + kk2) * 512
                           + sub2 * 128 + (r & 7);
#pragma unroll
        for (int i = 0; i < 4; i++) {
            float v = acc[i] + bias;
            v = v > 0.f ? v : (__expf(v) - 1.0f);
            op[(quad * 4 + i) * 8] = __float2bfloat16(v);
        }
    }
}

// ---------------------------------------------------------------------------
// Layer-2 GEMM, wave-per-head, packed A and W; fused s2/d2 epilogue.
// h2 written row-major [N][128].
// ---------------------------------------------------------------------------
__global__ void gemm_l2(const __hip_bfloat16* __restrict__ pA,
                        const __hip_bfloat16* __restrict__ pW2,
                        const float* __restrict__ as_, const float* __restrict__ ad_,
                        __hip_bfloat16* __restrict__ Cb,
                        float* __restrict__ s, float* __restrict__ d, int M) {
    int hh = threadIdx.x >> 6, lane = threadIdx.x & 63;
    int m0 = blockIdx.x * 16;
    int r = lane & 15, quad = lane >> 4;
    const __hip_bfloat16* ap  = pA + (size_t)(m0 >> 4) * 16 * 512 + lane * 8;
    const __hip_bfloat16* bp0 = pW2 + (size_t)(hh * 2) * 16 * 512 + lane * 8;
    const __hip_bfloat16* bp1 = bp0 + 16 * 512;
    f32x4 acc0 = {0.f, 0.f, 0.f, 0.f}, acc1 = {0.f, 0.f, 0.f, 0.f};
#pragma unroll
    for (int kk = 0; kk < 16; kk++) {
        short8 af = *(const short8*)(ap + kk * 512);
        short8 b0 = *(const short8*)(bp0 + kk * 512);
        short8 b1 = *(const short8*)(bp1 + kk * 512);
        acc0 = __builtin_amdgcn_mfma_f32_16x16x32_bf16(af, b0, acc0, 0, 0, 0);
        acc1 = __builtin_amdgcn_mfma_f32_16x16x32_bf16(af, b1, acc1, 0, 0, 0);
    }
    int n0 = hh * 32;
    float as0 = as_[n0 + r],      ad0 = ad_[n0 + r];
    float as1 = as_[n0 + 16 + r], ad1 = ad_[n0 + 16 + r];
    float sacc[4], dacc[4];
#pragma unroll
    for (int i = 0; i < 4; i++) {
        int m = m0 + quad * 4 + i;
        Cb[(size_t)m * 128 + n0 + r]      = __float2bfloat16(acc0[i]);
        Cb[(size_t)m * 128 + n0 + 16 + r] = __float2bfloat16(acc1[i]);
        sacc[i] = acc0[i] * as0 + acc1[i] * as1;
        dacc[i] = acc0[i] * ad0 + acc1[i] * ad1;
    }
#pragma unroll
    for (int mask = 1; mask <= 8; mask <<= 1) {
#pragma unroll
        for (int i = 0; i < 4; i++) {
            sacc[i] += __shfl_xor(sacc[i], mask, 64);
            dacc[i] += __shfl_xor(dacc[i], mask, 64);
        }
    }
    if (r == 0) {
#pragma unroll
        for (int i = 0; i < 4; i++) {
            int m = m0 + quad * 4 + i;
            s[m * 4 + hh] = sacc[i]; d[m * 4 + hh] = dacc[i];
        }
    }
}

// ---------------------------------------------------------------------------
// Layer-2 gather FUSED with layer-3 GEMM: node-per-wave; lane owns 2 act2
// channels. Edge weights computed INLINE from s2/d2 (no welist round-trip).
// After gather+ELU, fused K=128->8 GEMM via 64-lane butterfly -> h3, s3, d3.
// s3/d3 go to separate buffers (s2/d2 still being read by other blocks).
// ---------------------------------------------------------------------------
__global__ void gather_l2_g8(const int* __restrict__ elist, const int* __restrict__ offsets,
                             const float* __restrict__ s2, const float* __restrict__ d2,
                             const __hip_bfloat16* __restrict__ h,
                             const float* __restrict__ b,
                             const float* __restrict__ W3,
                             const float* __restrict__ a3s, const float* __restrict__ a3d,
                             __hip_bfloat16* __restrict__ h3,
                             float* __restrict__ s3, float* __restrict__ d3) {
    int gid = blockIdx.x * blockDim.x + threadIdx.x;
    if (gid >= NN * 64) return;
    int node = gid >> 6;
    int lane = gid & 63;
    int c0 = lane * 2;
    int hh = lane >> 4;
    int j0 = __builtin_amdgcn_readfirstlane(offsets[node]);
    int j1 = __builtin_amdgcn_readfirstlane(offsets[node + 1]);
    float dv = d2[node * 4 + hh];
    float den = 0.f, acc0 = 0.f, acc1 = 0.f;
    const unsigned short* hp = (const unsigned short*)h + c0;
    int j = j0;
    for (; j + 4 <= j1; j += 4) {
        int sA = elist[j], sB = elist[j+1], sC = elist[j+2], sD = elist[j+3];
        float eA = s2[sA * 4 + hh] + dv, eB = s2[sB * 4 + hh] + dv;
        float eC = s2[sC * 4 + hh] + dv, eD = s2[sD * 4 + hh] + dv;
        unsigned int vA = *(const unsigned int*)(hp + (size_t)sA * 128);
        unsigned int vB = *(const unsigned int*)(hp + (size_t)sB * 128);
        unsigned int vC = *(const unsigned int*)(hp + (size_t)sC * 128);
        unsigned int vD = *(const unsigned int*)(hp + (size_t)sD * 128);
        float wA = lrelu_exp(eA), wB = lrelu_exp(eB);
        float wC = lrelu_exp(eC), wD = lrelu_exp(eD);
        den += (wA + wB) + (wC + wD);
        acc0 += wA * us2f((unsigned short)vA) + wB * us2f((unsigned short)vB)
              + wC * us2f((unsigned short)vC) + wD * us2f((unsigned short)vD);
        acc1 += wA * us2f((unsigned short)(vA >> 16)) + wB * us2f((unsigned short)(vB >> 16))
              + wC * us2f((unsigned short)(vC >> 16)) + wD * us2f((unsigned short)(vD >> 16));
    }
    for (; j < j1; j++) {
        int sE = elist[j];
        float ww = lrelu_exp(s2[sE * 4 + hh] + dv);
        unsigned int v = *(const unsigned int*)(hp + (size_t)sE * 128);
        den += ww;
        acc0 += ww * us2f((unsigned short)v);
        acc1 += ww * us2f((unsigned short)(v >> 16));
    }
    float inv = 1.0f / den;
    float v0 = acc0 * inv + b[c0];
    float v1 = acc1 * inv + b[c0 + 1];
    v0 = v0 > 0.f ? v0 : (__expf(v0) - 1.0f);
    v1 = v1 > 0.f ? v1 : (__expf(v1) - 1.0f);
    // fused layer-3 GEMM: partial over this lane's 2 channels, butterfly-reduce
    float part[8];
#pragma unroll
    for (int c = 0; c < 8; c++) {
        float2 wv = *(const float2*)(W3 + c * 128 + c0);
        part[c] = v0 * wv.x + v1 * wv.y;
    }
#pragma unroll
    for (int mask = 1; mask < 64; mask <<= 1) {
#pragma unroll
        for (int c = 0; c < 8; c++) part[c] += __shfl_xor(part[c], mask, 64);
    }
    if (lane < 8) h3[(size_t)node * 8 + lane] = __float2bfloat16(part[lane]);
    if (lane == 0) {
        float sv = 0.f, dvv = 0.f;
#pragma unroll
        for (int c = 0; c < 8; c++) { sv += part[c] * a3s[c]; dvv += part[c] * a3d[c]; }
        s3[node] = sv; d3[node] = dvv;
    }
}

// ---------------------------------------------------------------------------
// Layer-3 gather: 8 lanes/node, lane owns 1 channel; weights computed inline.
// ---------------------------------------------------------------------------
__global__ void gather_l3(const int* __restrict__ elist, const int* __restrict__ offsets,
                          const float* __restrict__ s3, const float* __restrict__ d3,
                          const __hip_bfloat16* __restrict__ h,
                          const float* __restrict__ b,
                          __hip_bfloat16* __restrict__ act) {
    int gid = blockIdx.x * blockDim.x + threadIdx.x;
    if (gid >= NN * 8) return;
    int node = gid >> 3, t = gid & 7;
    int j0 = offsets[node], j1 = offsets[node + 1];
    float dnode = d3[node];
    float den = 0.f, acc = 0.f;
    const unsigned short* hp = (const unsigned short*)h + t;
    int j = j0;
    for (; j + 4 <= j1; j += 4) {
        int sA = elist[j], sB = elist[j+1], sC = elist[j+2], sD = elist[j+3];
        float wA = lrelu_exp(s3[sA] + dnode), wB = lrelu_exp(s3[sB] + dnode);
        float wC = lrelu_exp(s3[sC] + dnode), wD = lrelu_exp(s3[sD] + dnode);
        float xA = us2f(hp[(size_t)sA * 8]);
        float xB = us2f(hp[(size_t)sB * 8]);
        float xC = us2f(hp[(size_t)sC * 8]);
        float xD = us2f(hp[(size_t)sD * 8]);
        den += (wA + wB) + (wC + wD);
        acc += wA * xA + wB * xB + wC * xC + wD * xD;
    }
    for (; j < j1; j++) {
        int sE = elist[j];
        float w = lrelu_exp(s3[sE] + dnode);
        den += w;
        acc += w * us2f(hp[(size_t)sE * 8]);
    }
    float v = acc / den + b[t];
    v = v > 0.f ? v : (__expf(v) - 1.0f);
    act[(size_t)node * 8 + t] = __float2bfloat16(v);
}

// ---------------------------------------------------------------------------
// Final edge MLP: z[19] = [h3[src], h3[dst], ea, yr, qt] -> fc1(relu) -> fc2
// ---------------------------------------------------------------------------
__global__ void mlp_kernel(const int* __restrict__ ei,
                           const __hip_bfloat16* __restrict__ act3,
                           const float* __restrict__ ea,
                           const float* __restrict__ yr,
                           const float* __restrict__ qt,
                           const float* __restrict__ fc1w,
                           const float* __restrict__ fc1b,
                           const float* __restrict__ fc2w,
                           const float* __restrict__ fc2b,
                           float* __restrict__ outp) {
    __shared__ float w1[16 * 19], b1s[16], w2[16];
    for (int i = threadIdx.x; i < 16 * 19; i += blockDim.x) w1[i] = fc1w[i];
    if (threadIdx.x < 16) {
        b1s[threadIdx.x] = fc1b[threadIdx.x];
        w2[threadIdx.x] = fc2w[threadIdx.x];
    }
    __syncthreads();
    int e = blockIdx.x * blockDim.x + threadIdx.x;
    if (e >= EE) return;
    int src = ei[e], dst = ei[EE + e];
    short8 hs = *(const short8*)(act3 + (size_t)src * 8);
    short8 hd = *(const short8*)(act3 + (size_t)dst * 8);
    float z[19];
#pragma unroll
    for (int i = 0; i < 8; i++) z[i] = us2f((unsigned short)hs[i]);
#pragma unroll
    for (int i = 0; i < 8; i++) z[8 + i] = us2f((unsigned short)hd[i]);
    z[16] = ea[e]; z[17] = yr[e]; z[18] = qt[e];
    float acc2 = fc2b[0];
#pragma unroll
    for (int j = 0; j < 16; j++) {
        float a = b1s[j];
#pragma unroll
        for (int i = 0; i < 19; i++) a += z[i] * w1[j * 19 + i];
        a = a > 0.f ? a : 0.f;
        acc2 += a * w2[j];
    }
    outp[e] = acc2;
}

// ---------------------------------------------------------------------------
extern "C" void kernel_launch(void* const* d_in, const int* in_sizes, int n_in,
                              void* d_out, int out_size, void* d_ws, size_t ws_size,
                              hipStream_t stream) {
    const float* x    = (const float*)d_in[0];
    const int*   ei   = (const int*)d_in[1];
    const float* ea   = (const float*)d_in[2];
    const float* yr   = (const float*)d_in[3];
    const float* qt   = (const float*)d_in[4];
    const float* W1   = (const float*)d_in[5];
    const float* a1s  = (const float*)d_in[6];
    const float* a1d  = (const float*)d_in[7];
    const float* b1   = (const float*)d_in[8];
    const float* W2   = (const float*)d_in[9];
    const float* a2s  = (const float*)d_in[10];
    const float* a2d  = (const float*)d_in[11];
    const float* b2   = (const float*)d_in[12];
    const float* W3   = (const float*)d_in[13];
    const float* a3s  = (const float*)d_in[14];
    const float* a3d  = (const float*)d_in[15];
    const float* b3   = (const float*)d_in[16];
    const float* fc1w = (const float*)d_in[17];
    const float* fc1b = (const float*)d_in[18];
    const float* fc2w = (const float*)d_in[19];
    const float* fc2b = (const float*)d_in[20];
    float* outp = (float*)d_out;

    char* ws = (char*)d_ws;
    __hip_bfloat16* h_buf   = (__hip_bfloat16*)(ws);                 // N*512 bf16: pact1 / h3
    __hip_bfloat16* act_buf = (__hip_bfloat16*)(ws + 51200000);      // N*512 bf16: xb / h2 / act3
    float* s_buf   = (float*)(ws + 102400000);                       // N*4 f32: s1/s2
    float* d_buf   = (float*)(ws + 103200000);                       // N*4 f32: d1/d2
    int*   deg     = (int*)  (ws + 104000000);                       // N ints
    int*   cursor  = (int*)  (ws + 104200000);                       // N ints (contiguous w/ deg)
    int*   offsets = (int*)  (ws + 104400000);                       // N+1 ints
    int*   elist   = (int*)  (ws + 104600016);                       // EP ints (1.8 MB)
    __hip_bfloat16* pw1 = (__hip_bfloat16*)(ws + 106400016);         // 512*128 bf16 packed
    __hip_bfloat16* pw2 = (__hip_bfloat16*)(ws + 106531088);         // 128*512 bf16 packed
    float* usd  = (float*)(ws + 106662160);                          // 8*128 f32 (4 KB)
    int*   bsum = (int*)  (ws + 106666256);                          // SCB ints
    float* welist = (float*)(ws + 106666512);                        // EP*4 f32 (7.2 MB), layer-1 only
    float* s3_buf = (float*)(ws + 113866512);                        // N f32
    float* d3_buf = (float*)(ws + 114071312);                        // N f32
    __hip_bfloat16* xb = act_buf;                                    // N*128 bf16, dead after l1_fused

    // ---- prep (deg + weight pack + usd) + CSR scan ----
    hipMemsetAsync(deg, 0, 2 * NN * sizeof(int), stream);            // deg + cursor
    prep_kernel<<<DEGB + CVTB + 4, 256, 0, stream>>>(ei, deg, W1, W2, pw1, pw2, a1s, a1d, usd);
    scan1_kernel<<<SCB, 256, 0, stream>>>(deg, bsum);
    scan2_kernel<<<SCB, 256, 0, stream>>>(deg, bsum, offsets);
    cvtx_sd<<<(NN + 63) / 64, 256, 0, stream>>>(x, usd, xb, s_buf, d_buf, NN);
    fill_kernel<<<(EP + 255) / 256, 256, 0, stream>>>(ei, offsets, cursor, s_buf, d_buf,
                                                      elist, welist);

    // ---- Layer 1: fused gather + block-diag GEMM (pact1 -> h_buf) ----
    l1_fused<<<NN / 16, 512, 0, stream>>>(elist, offsets, welist, xb, pw1, b1, h_buf);

    // ---- Layer 2: GEMM (pact1 -> h2 in act_buf, s2/d2) ----
    gemm_l2<<<(NN + 15) / 16, 256, 0, stream>>>(
        h_buf, pw2, a2s, a2d, act_buf, s_buf, d_buf, NN);

    // ---- Layer-2 gather (inline w) fused with layer-3 GEMM -> h3, s3, d3 ----
    gather_l2_g8<<<(NN * 64 + 255) / 256, 256, 0, stream>>>(
        elist, offsets, s_buf, d_buf, act_buf, b2, W3, a3s, a3d,
        h_buf, s3_buf, d3_buf);

    // ---- Layer 3: gather (inline w) -> act3 in act_buf ----
    gather_l3<<<(NN * 8 + 255) / 256, 256, 0, stream>>>(
        elist, offsets, s3_buf, d3_buf, h_buf, b3, act_buf);

    // ---- Final edge MLP ----
    mlp_kernel<<<(EE + 255) / 256, 256, 0, stream>>>(ei, act_buf, ea, yr, qt,
                                                     fc1w, fc1b, fc2w, fc2b, outp);
}

// Round 10
// 278.488 us; speedup vs baseline: 1.1940x; 1.0729x over previous
//
#include <hip/hip_runtime.h>
#include <hip/hip_bf16.h>

#define NN 50000
#define EE 400000
#define EP 450000   // EE + NN self-loops

typedef __attribute__((ext_vector_type(8))) short short8;
typedef __attribute__((ext_vector_type(4))) float f32x4;

__device__ __forceinline__ float us2f(unsigned short u) {
    unsigned int x = ((unsigned int)u) << 16;
    union { unsigned int i; float f; } c; c.i = x; return c.f;
}
__device__ __forceinline__ unsigned short f2bfu(float f) {   // f32 -> bf16 bits, RNE
    union { float f; unsigned int u; } c; c.f = f;
    unsigned int r = c.u + 0x7FFFu + ((c.u >> 16) & 1u);
    return (unsigned short)(r >> 16);
}
__device__ __forceinline__ unsigned int pack2bf(float lo, float hi) {
    return (unsigned int)f2bfu(lo) | ((unsigned int)f2bfu(hi) << 16);
}
__device__ __forceinline__ float lrelu_exp(float x) {
    x = x > 0.f ? x : 0.2f * x;
    return __expf(x);
}

// Packed MFMA-fragment index for a [M x K] bf16 matrix consumed as A (or B with
// n in place of m) by mfma_f32_16x16x32_bf16:
//   idx(m,k) = ((m>>4)*(K/32) + (k>>5))*512 + ((k&31)>>3)*128 + (m&15)*8 + (k&7)

// ---------------------------------------------------------------------------
// prep: fused deg histogram + W1/W2 f32->bf16 packed convert + usd precompute.
// ---------------------------------------------------------------------------
#define DEGB 1758
#define CVTB 512
__global__ void prep_kernel(const int* __restrict__ ei, int* __restrict__ deg,
                            const float* __restrict__ W1, const float* __restrict__ W2,
                            __hip_bfloat16* __restrict__ pw1, __hip_bfloat16* __restrict__ pw2,
                            const float* __restrict__ a1s, const float* __restrict__ a1d,
                            float* __restrict__ usd) {
    int b = blockIdx.x;
    if (b < DEGB) {
        int e = b * 256 + threadIdx.x;
        if (e >= EP) return;
        int dst = (e < EE) ? ei[EE + e] : e - EE;
        atomicAdd(&deg[dst], 1);
    } else if (b < DEGB + CVTB) {
        int i = (b - DEGB) * 256 + threadIdx.x;
        if (i < 65536) {
            int n = i >> 7, k = i & 127;   // K=128, NK=4
            int idx = ((n >> 4) * 4 + (k >> 5)) * 512 + ((k & 31) >> 3) * 128 + (n & 15) * 8 + (k & 7);
            pw1[idx] = __float2bfloat16(W1[i]);
        } else {
            int j = i - 65536;
            int n = j >> 9, k = j & 511;   // K=512, NK=16
            int idx = ((n >> 4) * 16 + (k >> 5)) * 512 + ((k & 31) >> 3) * 128 + (n & 15) * 8 + (k & 7);
            pw2[idx] = __float2bfloat16(W2[j]);
        }
    } else {
        int t = (b - DEGB - CVTB) * 256 + threadIdx.x;
        if (t >= 1024) return;
        int row = t >> 7, k = t & 127;
        int hh = row & 3;
        const float* av = (row < 4) ? (a1s + hh * 128) : (a1d + hh * 128);
        const float* wp = W1 + (size_t)(hh * 128) * 128 + k;
        float acc = 0.f;
        for (int c = 0; c < 128; c++) acc += av[c] * wp[(size_t)c * 128];
        usd[t] = acc;
    }
}

// ---------------------------------------------------------------------------
// Fused: x (f32) -> xb (bf16) convert + s1/d1 = x . usd.
// ---------------------------------------------------------------------------
__global__ void cvtx_sd(const float* __restrict__ x, const float* __restrict__ usd,
                        __hip_bfloat16* __restrict__ xb,
                        float* __restrict__ s, float* __restrict__ d, int M) {
    __shared__ float us_s[1024];
    for (int i = threadIdx.x; i < 1024; i += 256) us_s[i] = usd[i];
    __syncthreads();
    int wave = threadIdx.x >> 6, lane = threadIdx.x & 63;
    int m0 = blockIdx.x * 64 + wave * 16;
    int r = lane & 15, quad = lane >> 4;
    int am = m0 + r; if (am >= M) am = M - 1;
    const float* xp = x + (size_t)am * 128 + quad * 8;
    float xv[32];
#pragma unroll
    for (int kk = 0; kk < 4; kk++) {
        float4 a = *(const float4*)(xp + kk * 32);
        float4 bq = *(const float4*)(xp + kk * 32 + 4);
        xv[kk*8+0]=a.x;  xv[kk*8+1]=a.y;  xv[kk*8+2]=a.z;  xv[kk*8+3]=a.w;
        xv[kk*8+4]=bq.x; xv[kk*8+5]=bq.y; xv[kk*8+6]=bq.z; xv[kk*8+7]=bq.w;
        short8 o;
        o[0]=(short)f2bfu(a.x);  o[1]=(short)f2bfu(a.y);
        o[2]=(short)f2bfu(a.z);  o[3]=(short)f2bfu(a.w);
        o[4]=(short)f2bfu(bq.x); o[5]=(short)f2bfu(bq.y);
        o[6]=(short)f2bfu(bq.z); o[7]=(short)f2bfu(bq.w);
        *(short8*)(xb + (size_t)am * 128 + quad * 8 + kk * 32) = o;
    }
    float acc[8];
#pragma unroll
    for (int o = 0; o < 8; o++) {
        const float* up = us_s + o * 128 + quad * 8;
        float a = 0.f;
#pragma unroll
        for (int kk = 0; kk < 4; kk++)
#pragma unroll
            for (int j = 0; j < 8; j++) a += xv[kk*8+j] * up[kk*32+j];
        acc[o] = a;
    }
#pragma unroll
    for (int o = 0; o < 8; o++) {
        acc[o] += __shfl_xor(acc[o], 16, 64);
        acc[o] += __shfl_xor(acc[o], 32, 64);
    }
    int m = m0 + r;
    if (quad == 0 && m < M) {
#pragma unroll
        for (int hh = 0; hh < 4; hh++) { s[m*4+hh] = acc[hh]; d[m*4+hh] = acc[4+hh]; }
    }
}

// ---------------------------------------------------------------------------
// Two-level multi-block scan of deg -> offsets
// ---------------------------------------------------------------------------
#define SCB 49
__global__ void scan1_kernel(const int* __restrict__ deg, int* __restrict__ bsum) {
    __shared__ int red[256];
    int b = blockIdx.x, t = threadIdx.x;
    int base = b * 1024 + t * 4;
    int s = 0;
    if (base + 3 < NN) { int4 v = *(const int4*)(deg + base); s = v.x + v.y + v.z + v.w; }
    else { for (int i = base; i < NN; i++) s += deg[i]; }
    red[t] = s;
    __syncthreads();
    for (int off = 128; off > 0; off >>= 1) {
        if (t < off) red[t] += red[t + off];
        __syncthreads();
    }
    if (t == 0) bsum[b] = red[0];
}

__global__ void scan2_kernel(const int* __restrict__ deg, const int* __restrict__ bsum,
                             int* __restrict__ offsets) {
    __shared__ int lsum[256];
    int b = blockIdx.x, t = threadIdx.x;
    int boff = 0;
    for (int i = 0; i < b; i++) boff += bsum[i];
    int base = b * 1024 + t * 4;
    int4 v = {0, 0, 0, 0};
    if (base + 3 < NN) v = *(const int4*)(deg + base);
    else {
        if (base < NN)     v.x = deg[base];
        if (base + 1 < NN) v.y = deg[base + 1];
        if (base + 2 < NN) v.z = deg[base + 2];
        if (base + 3 < NN) v.w = deg[base + 3];
    }
    int s = v.x + v.y + v.z + v.w;
    lsum[t] = s;
    __syncthreads();
    for (int off = 1; off < 256; off <<= 1) {
        int val = (t >= off) ? lsum[t - off] : 0;
        __syncthreads();
        lsum[t] += val;
        __syncthreads();
    }
    int ex = boff + (t ? lsum[t - 1] : 0);
    if (base < NN)     offsets[base]     = ex;
    if (base + 1 < NN) offsets[base + 1] = ex + v.x;
    if (base + 2 < NN) offsets[base + 2] = ex + v.x + v.y;
    if (base + 3 < NN) offsets[base + 3] = ex + v.x + v.y + v.z;
    if (b == SCB - 1 && t == 255) offsets[NN] = boff + lsum[255];
}

// ---------------------------------------------------------------------------
// fill: CSR scatter + fused layer-1 edge weights (s1/d1 already computed).
// ---------------------------------------------------------------------------
__global__ void fill_kernel(const int* __restrict__ ei, const int* __restrict__ offsets,
                            int* __restrict__ cursor,
                            const float* __restrict__ s1, const float* __restrict__ d1,
                            int* __restrict__ elist, float* __restrict__ welist) {
    int e = blockIdx.x * blockDim.x + threadIdx.x;
    if (e >= EP) return;
    int src, dst;
    if (e < EE) { src = ei[e]; dst = ei[EE + e]; } else { src = dst = e - EE; }
    int pos = atomicAdd(&cursor[dst], 1);
    int j = offsets[dst] + pos;
    elist[j] = src;
    float4 sv = *(const float4*)(s1 + (size_t)src * 4);
    float4 dv = *(const float4*)(d1 + (size_t)dst * 4);
    float4 w;
    w.x = lrelu_exp(sv.x + dv.x);
    w.y = lrelu_exp(sv.y + dv.y);
    w.z = lrelu_exp(sv.z + dv.z);
    w.w = lrelu_exp(sv.w + dv.w);
    *(float4*)(welist + (size_t)j * 4) = w;
}

// ---------------------------------------------------------------------------
// Edge accumulate helper for layer-1 gather (4 heads x 2 channels per lane).
// ---------------------------------------------------------------------------
__device__ __forceinline__ void acc_edge(float (&den)[4], float (&acc)[8],
                                         float4 w, unsigned int x) {
    float x0 = us2f((unsigned short)x), x1 = us2f((unsigned short)(x >> 16));
    den[0] += w.x; den[1] += w.y; den[2] += w.z; den[3] += w.w;
    acc[0] += w.x * x0; acc[1] += w.x * x1;
    acc[2] += w.y * x0; acc[3] += w.y * x1;
    acc[4] += w.z * x0; acc[5] += w.z * x1;
    acc[6] += w.w * x0; acc[7] += w.w * x1;
}

// ---------------------------------------------------------------------------
// Layer-1+2 FUSED: gather + bdiag GEMM (LDS) + layer-2 GEMM. 512 thr = 8 waves.
// Phase 1: wave w gathers nodes (blk*16+2w, +2w+1), dual-pointer loop ->
//          normalized bf16 fragments in LDS frag[] (swizzled, stride 520).
// Phase 2: wave w = (head w>>1, half w&1): 4 n-tiles x 4 MFMA from frag[],
//          ELU -> act1[] in LDS (packed K=512 fragment layout, same swizzle).
// Phase 3: waves 0-3 (= head hh): layer-2 GEMM from act1[] + packed W2,
//          h2 row-major -> global, fused s2/d2 butterfly epilogue.
// Removes pact1 global round-trip (51 MB) and the gemm_l2 dispatch.
// ---------------------------------------------------------------------------
__global__ void l1_fused(
        const int* __restrict__ elist, const int* __restrict__ offsets,
        const float* __restrict__ wl,
        const __hip_bfloat16* __restrict__ xb,
        const __hip_bfloat16* __restrict__ pW1,
        const float* __restrict__ b,
        const __hip_bfloat16* __restrict__ pW2,
        const float* __restrict__ as_, const float* __restrict__ ad_,
        __hip_bfloat16* __restrict__ h2,
        float* __restrict__ s2, float* __restrict__ d2) {
    __shared__ unsigned short frag[16 * 520];          // 16.6 KB
    __shared__ unsigned short act1[16 * 520];          // 16.6 KB
    int w = threadIdx.x >> 6, lane = threadIdx.x & 63;
    int m0 = blockIdx.x * 16;
    int nA = m0 + 2 * w;                                // rows 2w, 2w+1

    int ja  = __builtin_amdgcn_readfirstlane(offsets[nA]);
    int jA1 = __builtin_amdgcn_readfirstlane(offsets[nA + 1]);
    int jB1 = __builtin_amdgcn_readfirstlane(offsets[nA + 2]);
    int jb = jA1;

    float dA[4] = {0.f,0.f,0.f,0.f}, dB[4] = {0.f,0.f,0.f,0.f};
    float aA[8] = {0.f,0.f,0.f,0.f,0.f,0.f,0.f,0.f};
    float aB[8] = {0.f,0.f,0.f,0.f,0.f,0.f,0.f,0.f};
    const unsigned short* xp = (const unsigned short*)xb + lane * 2;
    const float4* wl4 = (const float4*)wl;

    // dual-chain main loop: 2 edges of A + 2 edges of B in flight
    while (ja + 2 <= jA1 && jb + 2 <= jB1) {
        int s0 = elist[ja], s1 = elist[ja + 1];
        int s2i = elist[jb], s3i = elist[jb + 1];
        float4 w0 = wl4[ja], w1 = wl4[ja + 1];
        float4 w2 = wl4[jb], w3 = wl4[jb + 1];
        unsigned int x0 = *(const unsigned int*)(xp + (size_t)s0 * 128);
        unsigned int x1 = *(const unsigned int*)(xp + (size_t)s1 * 128);
        unsigned int x2 = *(const unsigned int*)(xp + (size_t)s2i * 128);
        unsigned int x3 = *(const unsigned int*)(xp + (size_t)s3i * 128);
        acc_edge(dA, aA, w0, x0); acc_edge(dA, aA, w1, x1);
        acc_edge(dB, aB, w2, x2); acc_edge(dB, aB, w3, x3);
        ja += 2; jb += 2;
    }
    while (ja + 2 <= jA1) {
        int s0 = elist[ja], s1 = elist[ja + 1];
        float4 w0 = wl4[ja], w1 = wl4[ja + 1];
        unsigned int x0 = *(const unsigned int*)(xp + (size_t)s0 * 128);
        unsigned int x1 = *(const unsigned int*)(xp + (size_t)s1 * 128);
        acc_edge(dA, aA, w0, x0); acc_edge(dA, aA, w1, x1);
        ja += 2;
    }
    while (jb + 2 <= jB1) {
        int s0 = elist[jb], s1 = elist[jb + 1];
        float4 w0 = wl4[jb], w1 = wl4[jb + 1];
        unsigned int x0 = *(const unsigned int*)(xp + (size_t)s0 * 128);
        unsigned int x1 = *(const unsigned int*)(xp + (size_t)s1 * 128);
        acc_edge(dB, aB, w0, x0); acc_edge(dB, aB, w1, x1);
        jb += 2;
    }
    if (ja < jA1) {
        int s0 = elist[ja]; float4 w0 = wl4[ja];
        unsigned int x0 = *(const unsigned int*)(xp + (size_t)s0 * 128);
        acc_edge(dA, aA, w0, x0);
    }
    if (jb < jB1) {
        int s0 = elist[jb]; float4 w0 = wl4[jb];
        unsigned int x0 = *(const unsigned int*)(xp + (size_t)s0 * 128);
        acc_edge(dB, aB, w0, x0);
    }

    // store both nodes' normalized fragments to LDS (swizzled)
    {
        int c0 = lane * 2;
        int fq = c0 >> 5;
        int sub = (c0 & 31) >> 3;
        unsigned int* f32p = (unsigned int*)frag;
        int base0 = fq * 260 + sub * 64 + (c0 & 7) / 2;   // uint units
        {
            int rowp = (2 * w) ^ (sub << 2);
            int base = base0 + rowp * 4;
            float i0 = 1.f/dA[0], i1 = 1.f/dA[1], i2 = 1.f/dA[2], i3 = 1.f/dA[3];
            f32p[base]            = pack2bf(aA[0]*i0, aA[1]*i0);
            f32p[base + 4 * 260]  = pack2bf(aA[2]*i1, aA[3]*i1);
            f32p[base + 8 * 260]  = pack2bf(aA[4]*i2, aA[5]*i2);
            f32p[base + 12 * 260] = pack2bf(aA[6]*i3, aA[7]*i3);
        }
        {
            int rowp = (2 * w + 1) ^ (sub << 2);
            int base = base0 + rowp * 4;
            float i0 = 1.f/dB[0], i1 = 1.f/dB[1], i2 = 1.f/dB[2], i3 = 1.f/dB[3];
            f32p[base]            = pack2bf(aB[0]*i0, aB[1]*i0);
            f32p[base + 4 * 260]  = pack2bf(aB[2]*i1, aB[3]*i1);
            f32p[base + 8 * 260]  = pack2bf(aB[4]*i2, aB[5]*i2);
            f32p[base + 12 * 260] = pack2bf(aB[6]*i3, aB[7]*i3);
        }
    }
    __syncthreads();

    // ---- phase 2: block-diagonal GEMM from LDS -> act1 in LDS ----
    int hh = w >> 1, half = w & 1;
    int r = lane & 15, quad = lane >> 4;
    int lsub = lane >> 4, lrow = lane & 15;
    int prow = lrow ^ (lsub << 2);
    {
        const unsigned short* fb = frag + lsub * 128 + prow * 8;
        short8 afrag[4];
#pragma unroll
        for (int kk = 0; kk < 4; kk++)
            afrag[kk] = *(const short8*)(fb + (hh * 4 + kk) * 520);
#pragma unroll
        for (int t = 0; t < 4; t++) {
            int nb = half * 64 + t * 16;
            const __hip_bfloat16* bp = pW1 + ((size_t)(hh * 8 + (nb >> 4)) * 4) * 512 + lane * 8;
            f32x4 acc = {0.f, 0.f, 0.f, 0.f};
#pragma unroll
            for (int kk = 0; kk < 4; kk++) {
                short8 bfr = *(const short8*)(bp + kk * 512);
                acc = __builtin_amdgcn_mfma_f32_16x16x32_bf16(afrag[kk], bfr, acc, 0, 0, 0);
            }
            int n0 = hh * 128 + nb;
            float bias = b[n0 + r];
            int kk2 = (n0 + r) >> 5;                 // k-tile in K=512 layout
            int sub2 = ((nb & 16) + r) >> 3;         // k-subgroup
#pragma unroll
            for (int i = 0; i < 4; i++) {
                float v = acc[i] + bias;
                v = v > 0.f ? v : (__expf(v) - 1.0f);
                int rowp2 = (quad * 4 + i) ^ (sub2 << 2);
                act1[kk2 * 520 + sub2 * 128 + rowp2 * 8 + (r & 7)] = f2bfu(v);
            }
        }
    }
    __syncthreads();

    // ---- phase 3: layer-2 GEMM from act1 LDS (waves 0-3, wave = head) ----
    if (w < 4) {
        int h2h = w;                                 // head 0..3
        const __hip_bfloat16* bp0 = pW2 + (size_t)(h2h * 2) * 16 * 512 + lane * 8;
        const __hip_bfloat16* bp1 = bp0 + 16 * 512;
        const unsigned short* ab = act1 + lsub * 128 + prow * 8;
        f32x4 acc0 = {0.f, 0.f, 0.f, 0.f}, acc1 = {0.f, 0.f, 0.f, 0.f};
#pragma unroll
        for (int kk = 0; kk < 16; kk++) {
            short8 af = *(const short8*)(ab + kk * 520);
            short8 b0 = *(const short8*)(bp0 + kk * 512);
            short8 b1 = *(const short8*)(bp1 + kk * 512);
            acc0 = __builtin_amdgcn_mfma_f32_16x16x32_bf16(af, b0, acc0, 0, 0, 0);
            acc1 = __builtin_amdgcn_mfma_f32_16x16x32_bf16(af, b1, acc1, 0, 0, 0);
        }
        int n0 = h2h * 32;
        float as0 = as_[n0 + r],      ad0 = ad_[n0 + r];
        float as1 = as_[n0 + 16 + r], ad1 = ad_[n0 + 16 + r];
        float sacc[4], dacc[4];
#pragma unroll
        for (int i = 0; i < 4; i++) {
            int m = m0 + quad * 4 + i;
            h2[(size_t)m * 128 + n0 + r]      = __float2bfloat16(acc0[i]);
            h2[(size_t)m * 128 + n0 + 16 + r] = __float2bfloat16(acc1[i]);
            sacc[i] = acc0[i] * as0 + acc1[i] * as1;
            dacc[i] = acc0[i] * ad0 + acc1[i] * ad1;
        }
#pragma unroll
        for (int mask = 1; mask <= 8; mask <<= 1) {
#pragma unroll
            for (int i = 0; i < 4; i++) {
                sacc[i] += __shfl_xor(sacc[i], mask, 64);
                dacc[i] += __shfl_xor(dacc[i], mask, 64);
            }
        }
        if (r == 0) {
#pragma unroll
            for (int i = 0; i < 4; i++) {
                int m = m0 + quad * 4 + i;
                s2[m * 4 + h2h] = sacc[i]; d2[m * 4 + h2h] = dacc[i];
            }
        }
    }
}

// ---------------------------------------------------------------------------
// Layer-2 gather FUSED with layer-3 GEMM: node-per-wave; lane owns 2 h2
// channels. Edge weights computed INLINE from s2/d2.
// After gather+ELU, fused K=128->8 GEMM via 64-lane butterfly -> h3, s3, d3.
// ---------------------------------------------------------------------------
__global__ void gather_l2_g8(const int* __restrict__ elist, const int* __restrict__ offsets,
                             const float* __restrict__ s2, const float* __restrict__ d2,
                             const __hip_bfloat16* __restrict__ h,
                             const float* __restrict__ b,
                             const float* __restrict__ W3,
                             const float* __restrict__ a3s, const float* __restrict__ a3d,
                             __hip_bfloat16* __restrict__ h3,
                             float* __restrict__ s3, float* __restrict__ d3) {
    int gid = blockIdx.x * blockDim.x + threadIdx.x;
    if (gid >= NN * 64) return;
    int node = gid >> 6;
    int lane = gid & 63;
    int c0 = lane * 2;
    int hh = lane >> 4;
    int j0 = __builtin_amdgcn_readfirstlane(offsets[node]);
    int j1 = __builtin_amdgcn_readfirstlane(offsets[node + 1]);
    float dv = d2[node * 4 + hh];
    float den = 0.f, acc0 = 0.f, acc1 = 0.f;
    const unsigned short* hp = (const unsigned short*)h + c0;
    int j = j0;
    for (; j + 4 <= j1; j += 4) {
        int sA = elist[j], sB = elist[j+1], sC = elist[j+2], sD = elist[j+3];
        float eA = s2[sA * 4 + hh] + dv, eB = s2[sB * 4 + hh] + dv;
        float eC = s2[sC * 4 + hh] + dv, eD = s2[sD * 4 + hh] + dv;
        unsigned int vA = *(const unsigned int*)(hp + (size_t)sA * 128);
        unsigned int vB = *(const unsigned int*)(hp + (size_t)sB * 128);
        unsigned int vC = *(const unsigned int*)(hp + (size_t)sC * 128);
        unsigned int vD = *(const unsigned int*)(hp + (size_t)sD * 128);
        float wA = lrelu_exp(eA), wB = lrelu_exp(eB);
        float wC = lrelu_exp(eC), wD = lrelu_exp(eD);
        den += (wA + wB) + (wC + wD);
        acc0 += wA * us2f((unsigned short)vA) + wB * us2f((unsigned short)vB)
              + wC * us2f((unsigned short)vC) + wD * us2f((unsigned short)vD);
        acc1 += wA * us2f((unsigned short)(vA >> 16)) + wB * us2f((unsigned short)(vB >> 16))
              + wC * us2f((unsigned short)(vC >> 16)) + wD * us2f((unsigned short)(vD >> 16));
    }
    for (; j < j1; j++) {
        int sE = elist[j];
        float ww = lrelu_exp(s2[sE * 4 + hh] + dv);
        unsigned int v = *(const unsigned int*)(hp + (size_t)sE * 128);
        den += ww;
        acc0 += ww * us2f((unsigned short)v);
        acc1 += ww * us2f((unsigned short)(v >> 16));
    }
    float inv = 1.0f / den;
    float v0 = acc0 * inv + b[c0];
    float v1 = acc1 * inv + b[c0 + 1];
    v0 = v0 > 0.f ? v0 : (__expf(v0) - 1.0f);
    v1 = v1 > 0.f ? v1 : (__expf(v1) - 1.0f);
    // fused layer-3 GEMM: partial over this lane's 2 channels, butterfly-reduce
    float part[8];
#pragma unroll
    for (int c = 0; c < 8; c++) {
        float2 wv = *(const float2*)(W3 + c * 128 + c0);
        part[c] = v0 * wv.x + v1 * wv.y;
    }
#pragma unroll
    for (int mask = 1; mask < 64; mask <<= 1) {
#pragma unroll
        for (int c = 0; c < 8; c++) part[c] += __shfl_xor(part[c], mask, 64);
    }
    if (lane < 8) h3[(size_t)node * 8 + lane] = __float2bfloat16(part[lane]);
    if (lane == 0) {
        float sv = 0.f, dvv = 0.f;
#pragma unroll
        for (int c = 0; c < 8; c++) { sv += part[c] * a3s[c]; dvv += part[c] * a3d[c]; }
        s3[node] = sv; d3[node] = dvv;
    }
}

// ---------------------------------------------------------------------------
// Layer-3 gather: 8 lanes/node, lane owns 1 channel; weights computed inline.
// ---------------------------------------------------------------------------
__global__ void gather_l3(const int* __restrict__ elist, const int* __restrict__ offsets,
                          const float* __restrict__ s3, const float* __restrict__ d3,
                          const __hip_bfloat16* __restrict__ h,
                          const float* __restrict__ b,
                          __hip_bfloat16* __restrict__ act) {
    int gid = blockIdx.x * blockDim.x + threadIdx.x;
    if (gid >= NN * 8) return;
    int node = gid >> 3, t = gid & 7;
    int j0 = offsets[node], j1 = offsets[node + 1];
    float dnode = d3[node];
    float den = 0.f, acc = 0.f;
    const unsigned short* hp = (const unsigned short*)h + t;
    int j = j0;
    for (; j + 4 <= j1; j += 4) {
        int sA = elist[j], sB = elist[j+1], sC = elist[j+2], sD = elist[j+3];
        float wA = lrelu_exp(s3[sA] + dnode), wB = lrelu_exp(s3[sB] + dnode);
        float wC = lrelu_exp(s3[sC] + dnode), wD = lrelu_exp(s3[sD] + dnode);
        float xA = us2f(hp[(size_t)sA * 8]);
        float xB = us2f(hp[(size_t)sB * 8]);
        float xC = us2f(hp[(size_t)sC * 8]);
        float xD = us2f(hp[(size_t)sD * 8]);
        den += (wA + wB) + (wC + wD);
        acc += wA * xA + wB * xB + wC * xC + wD * xD;
    }
    for (; j < j1; j++) {
        int sE = elist[j];
        float w = lrelu_exp(s3[sE] + dnode);
        den += w;
        acc += w * us2f(hp[(size_t)sE * 8]);
    }
    float v = acc / den + b[t];
    v = v > 0.f ? v : (__expf(v) - 1.0f);
    act[(size_t)node * 8 + t] = __float2bfloat16(v);
}

// ---------------------------------------------------------------------------
// Final edge MLP: z[19] = [h3[src], h3[dst], ea, yr, qt] -> fc1(relu) -> fc2
// ---------------------------------------------------------------------------
__global__ void mlp_kernel(const int* __restrict__ ei,
                           const __hip_bfloat16* __restrict__ act3,
                           const float* __restrict__ ea,
                           const float* __restrict__ yr,
                           const float* __restrict__ qt,
                           const float* __restrict__ fc1w,
                           const float* __restrict__ fc1b,
                           const float* __restrict__ fc2w,
                           const float* __restrict__ fc2b,
                           float* __restrict__ outp) {
    __shared__ float w1[16 * 19], b1s[16], w2[16];
    for (int i = threadIdx.x; i < 16 * 19; i += blockDim.x) w1[i] = fc1w[i];
    if (threadIdx.x < 16) {
        b1s[threadIdx.x] = fc1b[threadIdx.x];
        w2[threadIdx.x] = fc2w[threadIdx.x];
    }
    __syncthreads();
    int e = blockIdx.x * blockDim.x + threadIdx.x;
    if (e >= EE) return;
    int src = ei[e], dst = ei[EE + e];
    short8 hs = *(const short8*)(act3 + (size_t)src * 8);
    short8 hd = *(const short8*)(act3 + (size_t)dst * 8);
    float z[19];
#pragma unroll
    for (int i = 0; i < 8; i++) z[i] = us2f((unsigned short)hs[i]);
#pragma unroll
    for (int i = 0; i < 8; i++) z[8 + i] = us2f((unsigned short)hd[i]);
    z[16] = ea[e]; z[17] = yr[e]; z[18] = qt[e];
    float acc2 = fc2b[0];
#pragma unroll
    for (int j = 0; j < 16; j++) {
        float a = b1s[j];
#pragma unroll
        for (int i = 0; i < 19; i++) a += z[i] * w1[j * 19 + i];
        a = a > 0.f ? a : 0.f;
        acc2 += a * w2[j];
    }
    outp[e] = acc2;
}

// ---------------------------------------------------------------------------
extern "C" void kernel_launch(void* const* d_in, const int* in_sizes, int n_in,
                              void* d_out, int out_size, void* d_ws, size_t ws_size,
                              hipStream_t stream) {
    const float* x    = (const float*)d_in[0];
    const int*   ei   = (const int*)d_in[1];
    const float* ea   = (const float*)d_in[2];
    const float* yr   = (const float*)d_in[3];
    const float* qt   = (const float*)d_in[4];
    const float* W1   = (const float*)d_in[5];
    const float* a1s  = (const float*)d_in[6];
    const float* a1d  = (const float*)d_in[7];
    const float* b1   = (const float*)d_in[8];
    const float* W2   = (const float*)d_in[9];
    const float* a2s  = (const float*)d_in[10];
    const float* a2d  = (const float*)d_in[11];
    const float* b2   = (const float*)d_in[12];
    const float* W3   = (const float*)d_in[13];
    const float* a3s  = (const float*)d_in[14];
    const float* a3d  = (const float*)d_in[15];
    const float* b3   = (const float*)d_in[16];
    const float* fc1w = (const float*)d_in[17];
    const float* fc1b = (const float*)d_in[18];
    const float* fc2w = (const float*)d_in[19];
    const float* fc2b = (const float*)d_in[20];
    float* outp = (float*)d_out;

    char* ws = (char*)d_ws;
    __hip_bfloat16* h_buf   = (__hip_bfloat16*)(ws);                 // N*512 bf16: h3
    __hip_bfloat16* act_buf = (__hip_bfloat16*)(ws + 51200000);      // N*512 bf16: xb / act3
    float* s_buf   = (float*)(ws + 102400000);                       // N*4 f32: s1/s2
    float* d_buf   = (float*)(ws + 103200000);                       // N*4 f32: d1/d2
    int*   deg     = (int*)  (ws + 104000000);                       // N ints
    int*   cursor  = (int*)  (ws + 104200000);                       // N ints (contiguous w/ deg)
    int*   offsets = (int*)  (ws + 104400000);                       // N+1 ints
    int*   elist   = (int*)  (ws + 104600016);                       // EP ints (1.8 MB)
    __hip_bfloat16* pw1 = (__hip_bfloat16*)(ws + 106400016);         // 512*128 bf16 packed
    __hip_bfloat16* pw2 = (__hip_bfloat16*)(ws + 106531088);         // 128*512 bf16 packed
    float* usd  = (float*)(ws + 106662160);                          // 8*128 f32 (4 KB)
    int*   bsum = (int*)  (ws + 106666256);                          // SCB ints
    float* welist = (float*)(ws + 106666512);                        // EP*4 f32 (7.2 MB), layer-1 only
    float* s3_buf = (float*)(ws + 113866512);                        // N f32
    float* d3_buf = (float*)(ws + 114071312);                        // N f32
    __hip_bfloat16* h2_buf = (__hip_bfloat16*)(ws + 114276112);      // N*128 bf16 (12.8 MB)
    __hip_bfloat16* xb = act_buf;                                    // N*128 bf16, dead after l1_fused

    // ---- prep (deg + weight pack + usd) + CSR scan ----
    hipMemsetAsync(deg, 0, 2 * NN * sizeof(int), stream);            // deg + cursor
    prep_kernel<<<DEGB + CVTB + 4, 256, 0, stream>>>(ei, deg, W1, W2, pw1, pw2, a1s, a1d, usd);
    scan1_kernel<<<SCB, 256, 0, stream>>>(deg, bsum);
    scan2_kernel<<<SCB, 256, 0, stream>>>(deg, bsum, offsets);
    cvtx_sd<<<(NN + 63) / 64, 256, 0, stream>>>(x, usd, xb, s_buf, d_buf, NN);
    fill_kernel<<<(EP + 255) / 256, 256, 0, stream>>>(ei, offsets, cursor, s_buf, d_buf,
                                                      elist, welist);

    // ---- Layers 1+2 fused: gather + bdiag GEMM (LDS) + l2 GEMM -> h2, s2/d2 ----
    l1_fused<<<NN / 16, 512, 0, stream>>>(elist, offsets, welist, xb, pw1, b1,
                                          pw2, a2s, a2d, h2_buf, s_buf, d_buf);

    // ---- Layer-2 gather (inline w) fused with layer-3 GEMM -> h3, s3, d3 ----
    gather_l2_g8<<<(NN * 64 + 255) / 256, 256, 0, stream>>>(
        elist, offsets, s_buf, d_buf, h2_buf, b2, W3, a3s, a3d,
        h_buf, s3_buf, d3_buf);

    // ---- Layer 3: gather (inline w) -> act3 in act_buf ----
    gather_l3<<<(NN * 8 + 255) / 256, 256, 0, stream>>>(
        elist, offsets, s3_buf, d3_buf, h_buf, b3, act_buf);

    // ---- Final edge MLP ----
    mlp_kernel<<<(EE + 255) / 256, 256, 0, stream>>>(ei, act_buf, ea, yr, qt,
                                                     fc1w, fc1b, fc2w, fc2b, outp);
}

// Round 13
// 273.725 us; speedup vs baseline: 1.2148x; 1.0174x over previous
//
#include <hip/hip_runtime.h>
#include <hip/hip_bf16.h>

#define NN 50000
#define EE 400000
#define EP 450000   // EE + NN self-loops

typedef __attribute__((ext_vector_type(8))) short short8;
typedef __attribute__((ext_vector_type(4))) float f32x4;
typedef __attribute__((ext_vector_type(2))) float f32x2;

__device__ __forceinline__ float us2f(unsigned short u) {
    unsigned int x = ((unsigned int)u) << 16;
    union { unsigned int i; float f; } c; c.i = x; return c.f;
}
__device__ __forceinline__ unsigned short f2bfu(float f) {   // f32 -> bf16 bits, RNE
    union { float f; unsigned int u; } c; c.f = f;
    unsigned int r = c.u + 0x7FFFu + ((c.u >> 16) & 1u);
    return (unsigned short)(r >> 16);
}
__device__ __forceinline__ unsigned int pack2bf(float lo, float hi) {
    return (unsigned int)f2bfu(lo) | ((unsigned int)f2bfu(hi) << 16);
}
__device__ __forceinline__ float lrelu_exp(float x) {
    x = x > 0.f ? x : 0.2f * x;
    return __expf(x);
}

// Packed MFMA-fragment index for a [M x K] bf16 matrix consumed as A (or B with
// n in place of m) by mfma_f32_16x16x32_bf16:
//   idx(m,k) = ((m>>4)*(K/32) + (k>>5))*512 + ((k&31)>>3)*128 + (m&15)*8 + (k&7)

// ---------------------------------------------------------------------------
// prep: fused deg histogram + W1/W2 f32->bf16 packed convert + usd precompute.
// ---------------------------------------------------------------------------
#define DEGB 1758
#define CVTB 512
__global__ void prep_kernel(const int* __restrict__ ei, int* __restrict__ deg,
                            const float* __restrict__ W1, const float* __restrict__ W2,
                            __hip_bfloat16* __restrict__ pw1, __hip_bfloat16* __restrict__ pw2,
                            const float* __restrict__ a1s, const float* __restrict__ a1d,
                            float* __restrict__ usd) {
    int b = blockIdx.x;
    if (b < DEGB) {
        int e = b * 256 + threadIdx.x;
        if (e >= EP) return;
        int dst = (e < EE) ? ei[EE + e] : e - EE;
        atomicAdd(&deg[dst], 1);
    } else if (b < DEGB + CVTB) {
        int i = (b - DEGB) * 256 + threadIdx.x;
        if (i < 65536) {
            int n = i >> 7, k = i & 127;   // K=128, NK=4
            int idx = ((n >> 4) * 4 + (k >> 5)) * 512 + ((k & 31) >> 3) * 128 + (n & 15) * 8 + (k & 7);
            pw1[idx] = __float2bfloat16(W1[i]);
        } else {
            int j = i - 65536;
            int n = j >> 9, k = j & 511;   // K=512, NK=16
            int idx = ((n >> 4) * 16 + (k >> 5)) * 512 + ((k & 31) >> 3) * 128 + (n & 15) * 8 + (k & 7);
            pw2[idx] = __float2bfloat16(W2[j]);
        }
    } else {
        int t = (b - DEGB - CVTB) * 256 + threadIdx.x;
        if (t >= 1024) return;
        int row = t >> 7, k = t & 127;
        int hh = row & 3;
        const float* av = (row < 4) ? (a1s + hh * 128) : (a1d + hh * 128);
        const float* wp = W1 + (size_t)(hh * 128) * 128 + k;
        float acc = 0.f;
        for (int c = 0; c < 128; c++) acc += av[c] * wp[(size_t)c * 128];
        usd[t] = acc;
    }
}

// ---------------------------------------------------------------------------
// Fused: x (f32) -> xb (bf16) convert + s1/d1 = x . usd.
// ---------------------------------------------------------------------------
__global__ void cvtx_sd(const float* __restrict__ x, const float* __restrict__ usd,
                        __hip_bfloat16* __restrict__ xb,
                        float* __restrict__ s, float* __restrict__ d, int M) {
    __shared__ float us_s[1024];
    for (int i = threadIdx.x; i < 1024; i += 256) us_s[i] = usd[i];
    __syncthreads();
    int wave = threadIdx.x >> 6, lane = threadIdx.x & 63;
    int m0 = blockIdx.x * 64 + wave * 16;
    int r = lane & 15, quad = lane >> 4;
    int am = m0 + r; if (am >= M) am = M - 1;
    const float* xp = x + (size_t)am * 128 + quad * 8;
    float xv[32];
#pragma unroll
    for (int kk = 0; kk < 4; kk++) {
        float4 a = *(const float4*)(xp + kk * 32);
        float4 bq = *(const float4*)(xp + kk * 32 + 4);
        xv[kk*8+0]=a.x;  xv[kk*8+1]=a.y;  xv[kk*8+2]=a.z;  xv[kk*8+3]=a.w;
        xv[kk*8+4]=bq.x; xv[kk*8+5]=bq.y; xv[kk*8+6]=bq.z; xv[kk*8+7]=bq.w;
        short8 o;
        o[0]=(short)f2bfu(a.x);  o[1]=(short)f2bfu(a.y);
        o[2]=(short)f2bfu(a.z);  o[3]=(short)f2bfu(a.w);
        o[4]=(short)f2bfu(bq.x); o[5]=(short)f2bfu(bq.y);
        o[6]=(short)f2bfu(bq.z); o[7]=(short)f2bfu(bq.w);
        *(short8*)(xb + (size_t)am * 128 + quad * 8 + kk * 32) = o;
    }
    float acc[8];
#pragma unroll
    for (int o = 0; o < 8; o++) {
        const float* up = us_s + o * 128 + quad * 8;
        float a = 0.f;
#pragma unroll
        for (int kk = 0; kk < 4; kk++)
#pragma unroll
            for (int j = 0; j < 8; j++) a += xv[kk*8+j] * up[kk*32+j];
        acc[o] = a;
    }
#pragma unroll
    for (int o = 0; o < 8; o++) {
        acc[o] += __shfl_xor(acc[o], 16, 64);
        acc[o] += __shfl_xor(acc[o], 32, 64);
    }
    int m = m0 + r;
    if (quad == 0 && m < M) {
#pragma unroll
        for (int hh = 0; hh < 4; hh++) { s[m*4+hh] = acc[hh]; d[m*4+hh] = acc[4+hh]; }
    }
}

// ---------------------------------------------------------------------------
// Two-level multi-block scan of deg -> offsets
// ---------------------------------------------------------------------------
#define SCB 49
__global__ void scan1_kernel(const int* __restrict__ deg, int* __restrict__ bsum) {
    __shared__ int red[256];
    int b = blockIdx.x, t = threadIdx.x;
    int base = b * 1024 + t * 4;
    int s = 0;
    if (base + 3 < NN) { int4 v = *(const int4*)(deg + base); s = v.x + v.y + v.z + v.w; }
    else { for (int i = base; i < NN; i++) s += deg[i]; }
    red[t] = s;
    __syncthreads();
    for (int off = 128; off > 0; off >>= 1) {
        if (t < off) red[t] += red[t + off];
        __syncthreads();
    }
    if (t == 0) bsum[b] = red[0];
}

__global__ void scan2_kernel(const int* __restrict__ deg, const int* __restrict__ bsum,
                             int* __restrict__ offsets) {
    __shared__ int lsum[256];
    int b = blockIdx.x, t = threadIdx.x;
    int boff = 0;
    for (int i = 0; i < b; i++) boff += bsum[i];
    int base = b * 1024 + t * 4;
    int4 v = {0, 0, 0, 0};
    if (base + 3 < NN) v = *(const int4*)(deg + base);
    else {
        if (base < NN)     v.x = deg[base];
        if (base + 1 < NN) v.y = deg[base + 1];
        if (base + 2 < NN) v.z = deg[base + 2];
        if (base + 3 < NN) v.w = deg[base + 3];
    }
    int s = v.x + v.y + v.z + v.w;
    lsum[t] = s;
    __syncthreads();
    for (int off = 1; off < 256; off <<= 1) {
        int val = (t >= off) ? lsum[t - off] : 0;
        __syncthreads();
        lsum[t] += val;
        __syncthreads();
    }
    int ex = boff + (t ? lsum[t - 1] : 0);
    if (base < NN)     offsets[base]     = ex;
    if (base + 1 < NN) offsets[base + 1] = ex + v.x;
    if (base + 2 < NN) offsets[base + 2] = ex + v.x + v.y;
    if (base + 3 < NN) offsets[base + 3] = ex + v.x + v.y + v.z;
    if (b == SCB - 1 && t == 255) offsets[NN] = boff + lsum[255];
}

// ---------------------------------------------------------------------------
// fill: CSR scatter + fused layer-1 edge weights (s1/d1 already computed).
// ---------------------------------------------------------------------------
__global__ void fill_kernel(const int* __restrict__ ei, const int* __restrict__ offsets,
                            int* __restrict__ cursor,
                            const float* __restrict__ s1, const float* __restrict__ d1,
                            int* __restrict__ elist, float* __restrict__ welist) {
    int e = blockIdx.x * blockDim.x + threadIdx.x;
    if (e >= EP) return;
    int src, dst;
    if (e < EE) { src = ei[e]; dst = ei[EE + e]; } else { src = dst = e - EE; }
    int pos = atomicAdd(&cursor[dst], 1);
    int j = offsets[dst] + pos;
    elist[j] = src;
    float4 sv = *(const float4*)(s1 + (size_t)src * 4);
    float4 dv = *(const float4*)(d1 + (size_t)dst * 4);
    float4 w;
    w.x = lrelu_exp(sv.x + dv.x);
    w.y = lrelu_exp(sv.y + dv.y);
    w.z = lrelu_exp(sv.z + dv.z);
    w.w = lrelu_exp(sv.w + dv.w);
    *(float4*)(welist + (size_t)j * 4) = w;
}

// ---------------------------------------------------------------------------
// Edge accumulate, packed over HEAD PAIRS (w01 = heads 0-1, w23 = heads 2-3):
// acc[0]=c0/h01, acc[1]=c0/h23, acc[2]=c1/h01, acc[3]=c1/h23.
// Plain vector C — clang emits v_pk_fma_f32 / v_pk_add_f32 on gfx950.
// ---------------------------------------------------------------------------
__device__ __forceinline__ void acc_edge(f32x2& den01, f32x2& den23, f32x2 (&acc)[4],
                                         float4 w, unsigned int x) {
    float x0 = us2f((unsigned short)x), x1 = us2f((unsigned short)(x >> 16));
    f32x2 w01; w01[0] = w.x; w01[1] = w.y;
    f32x2 w23; w23[0] = w.z; w23[1] = w.w;
    f32x2 x0s; x0s[0] = x0; x0s[1] = x0;
    f32x2 x1s; x1s[0] = x1; x1s[1] = x1;
    acc[0] += w01 * x0s;
    acc[1] += w23 * x0s;
    acc[2] += w01 * x1s;
    acc[3] += w23 * x1s;
    den01 += w01;
    den23 += w23;
}

// ---------------------------------------------------------------------------
// Layer-1+2 FUSED: gather + bdiag GEMM (LDS) + layer-2 GEMM. 512 thr = 8 waves.
// Phase 0: all waves redundantly rank the block's 16 node degrees (shfl rank);
//          wave w gathers nodes rank w and rank 15-w (largest-with-smallest
//          pairing evens out the barrier convoy).
// Phase 1: dual-pointer gather, packed-FMA accumulate, normalized bf16
//          fragments -> LDS frag[] (swizzled, stride 520).
// Phase 2: wave w = (head w>>1, half w&1): 4 n-tiles x 4 MFMA from frag[],
//          ELU -> act1[] in LDS (packed K=512 fragment layout, same swizzle).
// Phase 3: waves 0-3 (= head): layer-2 GEMM from act1[] + packed W2,
//          h2 row-major -> global, fused s2/d2 butterfly epilogue.
// ---------------------------------------------------------------------------
__global__ void l1_fused(
        const int* __restrict__ elist, const int* __restrict__ offsets,
        const float* __restrict__ wl,
        const __hip_bfloat16* __restrict__ xb,
        const __hip_bfloat16* __restrict__ pW1,
        const float* __restrict__ b,
        const __hip_bfloat16* __restrict__ pW2,
        const float* __restrict__ as_, const float* __restrict__ ad_,
        __hip_bfloat16* __restrict__ h2,
        float* __restrict__ s2, float* __restrict__ d2) {
    __shared__ unsigned short frag[16 * 520];          // 16.6 KB
    __shared__ unsigned short act1[16 * 520];          // 16.6 KB
    int w = threadIdx.x >> 6, lane = threadIdx.x & 63;
    int m0 = blockIdx.x * 16;

    // ---- phase 0: degree-sorted pairing (redundant per wave, no barrier) ----
    int li = lane < 16 ? lane : 15;
    int mydeg = offsets[m0 + li + 1] - offsets[m0 + li];
    int rank = 0;
#pragma unroll
    for (int jj = 0; jj < 16; jj++) {
        int od = __shfl(mydeg, jj, 64);
        rank += (od < mydeg) || (od == mydeg && jj < li);
    }
    unsigned long long balA = __ballot(lane < 16 && rank == w);
    unsigned long long balB = __ballot(lane < 16 && rank == 15 - w);
    int iA = (int)__builtin_ctzll(balA);
    int iB = (int)__builtin_ctzll(balB);
    int nodeA = m0 + iA, nodeB = m0 + iB;

    int ja  = __builtin_amdgcn_readfirstlane(offsets[nodeA]);
    int jA1 = __builtin_amdgcn_readfirstlane(offsets[nodeA + 1]);
    int jb  = __builtin_amdgcn_readfirstlane(offsets[nodeB]);
    int jB1 = __builtin_amdgcn_readfirstlane(offsets[nodeB + 1]);

    f32x2 dA01, dA23, dB01, dB23;
    dA01[0]=0.f; dA01[1]=0.f; dA23[0]=0.f; dA23[1]=0.f;
    dB01[0]=0.f; dB01[1]=0.f; dB23[0]=0.f; dB23[1]=0.f;
    f32x2 aA[4], aB[4];
#pragma unroll
    for (int h = 0; h < 4; h++) {
        aA[h][0]=0.f; aA[h][1]=0.f;
        aB[h][0]=0.f; aB[h][1]=0.f;
    }
    const unsigned short* xp = (const unsigned short*)xb + lane * 2;
    const float4* wl4 = (const float4*)wl;

    // dual-chain main loop: 2 edges of A + 2 edges of B in flight
    while (ja + 2 <= jA1 && jb + 2 <= jB1) {
        int s0 = elist[ja], s1 = elist[ja + 1];
        int s2i = elist[jb], s3i = elist[jb + 1];
        float4 w0 = wl4[ja], w1 = wl4[ja + 1];
        float4 w2 = wl4[jb], w3 = wl4[jb + 1];
        unsigned int x0 = *(const unsigned int*)(xp + (size_t)s0 * 128);
        unsigned int x1 = *(const unsigned int*)(xp + (size_t)s1 * 128);
        unsigned int x2 = *(const unsigned int*)(xp + (size_t)s2i * 128);
        unsigned int x3 = *(const unsigned int*)(xp + (size_t)s3i * 128);
        acc_edge(dA01, dA23, aA, w0, x0); acc_edge(dA01, dA23, aA, w1, x1);
        acc_edge(dB01, dB23, aB, w2, x2); acc_edge(dB01, dB23, aB, w3, x3);
        ja += 2; jb += 2;
    }
    while (ja + 2 <= jA1) {
        int s0 = elist[ja], s1 = elist[ja + 1];
        float4 w0 = wl4[ja], w1 = wl4[ja + 1];
        unsigned int x0 = *(const unsigned int*)(xp + (size_t)s0 * 128);
        unsigned int x1 = *(const unsigned int*)(xp + (size_t)s1 * 128);
        acc_edge(dA01, dA23, aA, w0, x0); acc_edge(dA01, dA23, aA, w1, x1);
        ja += 2;
    }
    while (jb + 2 <= jB1) {
        int s0 = elist[jb], s1 = elist[jb + 1];
        float4 w0 = wl4[jb], w1 = wl4[jb + 1];
        unsigned int x0 = *(const unsigned int*)(xp + (size_t)s0 * 128);
        unsigned int x1 = *(const unsigned int*)(xp + (size_t)s1 * 128);
        acc_edge(dB01, dB23, aB, w0, x0); acc_edge(dB01, dB23, aB, w1, x1);
        jb += 2;
    }
    if (ja < jA1) {
        int s0 = elist[ja]; float4 w0 = wl4[ja];
        unsigned int x0 = *(const unsigned int*)(xp + (size_t)s0 * 128);
        acc_edge(dA01, dA23, aA, w0, x0);
    }
    if (jb < jB1) {
        int s0 = elist[jb]; float4 w0 = wl4[jb];
        unsigned int x0 = *(const unsigned int*)(xp + (size_t)s0 * 128);
        acc_edge(dB01, dB23, aB, w0, x0);
    }

    // store both nodes' normalized fragments to LDS (swizzled)
    // acc layout: [0]=c0/h01 [1]=c0/h23 [2]=c1/h01 [3]=c1/h23
    {
        int c0 = lane * 2;
        int fq = c0 >> 5;
        int sub = (c0 & 31) >> 3;
        unsigned int* f32p = (unsigned int*)frag;
        int base0 = fq * 260 + sub * 64 + (c0 & 7) / 2;   // uint units
        {
            int rowp = iA ^ (sub << 2);
            int base = base0 + rowp * 4;
            float i0 = 1.f/dA01[0], i1 = 1.f/dA01[1], i2 = 1.f/dA23[0], i3 = 1.f/dA23[1];
            f32p[base]            = pack2bf(aA[0][0]*i0, aA[2][0]*i0);   // head0: c0,c1
            f32p[base + 4 * 260]  = pack2bf(aA[0][1]*i1, aA[2][1]*i1);   // head1
            f32p[base + 8 * 260]  = pack2bf(aA[1][0]*i2, aA[3][0]*i2);   // head2
            f32p[base + 12 * 260] = pack2bf(aA[1][1]*i3, aA[3][1]*i3);   // head3
        }
        {
            int rowp = iB ^ (sub << 2);
            int base = base0 + rowp * 4;
            float i0 = 1.f/dB01[0], i1 = 1.f/dB01[1], i2 = 1.f/dB23[0], i3 = 1.f/dB23[1];
            f32p[base]            = pack2bf(aB[0][0]*i0, aB[2][0]*i0);
            f32p[base + 4 * 260]  = pack2bf(aB[0][1]*i1, aB[2][1]*i1);
            f32p[base + 8 * 260]  = pack2bf(aB[1][0]*i2, aB[3][0]*i2);
            f32p[base + 12 * 260] = pack2bf(aB[1][1]*i3, aB[3][1]*i3);
        }
    }
    __syncthreads();

    // ---- phase 2: block-diagonal GEMM from LDS -> act1 in LDS ----
    int hh = w >> 1, half = w & 1;
    int r = lane & 15, quad = lane >> 4;
    int lsub = lane >> 4, lrow = lane & 15;
    int prow = lrow ^ (lsub << 2);
    {
        const unsigned short* fb = frag + lsub * 128 + prow * 8;
        short8 afrag[4];
#pragma unroll
        for (int kk = 0; kk < 4; kk++)
            afrag[kk] = *(const short8*)(fb + (hh * 4 + kk) * 520);
#pragma unroll
        for (int t = 0; t < 4; t++) {
            int nb = half * 64 + t * 16;
            const __hip_bfloat16* bp = pW1 + ((size_t)(hh * 8 + (nb >> 4)) * 4) * 512 + lane * 8;
            f32x4 acc = {0.f, 0.f, 0.f, 0.f};
#pragma unroll
            for (int kk = 0; kk < 4; kk++) {
                short8 bfr = *(const short8*)(bp + kk * 512);
                acc = __builtin_amdgcn_mfma_f32_16x16x32_bf16(afrag[kk], bfr, acc, 0, 0, 0);
            }
            int n0 = hh * 128 + nb;
            float bias = b[n0 + r];
            int kk2 = (n0 + r) >> 5;                 // k-tile in K=512 layout
            int sub2 = ((nb & 16) + r) >> 3;         // k-subgroup
#pragma unroll
            for (int i = 0; i < 4; i++) {
                float v = acc[i] + bias;
                v = v > 0.f ? v : (__expf(v) - 1.0f);
                int rowp2 = (quad * 4 + i) ^ (sub2 << 2);
                act1[kk2 * 520 + sub2 * 128 + rowp2 * 8 + (r & 7)] = f2bfu(v);
            }
        }
    }
    __syncthreads();

    // ---- phase 3: layer-2 GEMM from act1 LDS (waves 0-3, wave = head) ----
    if (w < 4) {
        int h2h = w;                                 // head 0..3
        const __hip_bfloat16* bp0 = pW2 + (size_t)(h2h * 2) * 16 * 512 + lane * 8;
        const __hip_bfloat16* bp1 = bp0 + 16 * 512;
        const unsigned short* ab = act1 + lsub * 128 + prow * 8;
        f32x4 acc0 = {0.f, 0.f, 0.f, 0.f}, acc1 = {0.f, 0.f, 0.f, 0.f};
#pragma unroll
        for (int kk = 0; kk < 16; kk++) {
            short8 af = *(const short8*)(ab + kk * 520);
            short8 b0 = *(const short8*)(bp0 + kk * 512);
            short8 b1 = *(const short8*)(bp1 + kk * 512);
            acc0 = __builtin_amdgcn_mfma_f32_16x16x32_bf16(af, b0, acc0, 0, 0, 0);
            acc1 = __builtin_amdgcn_mfma_f32_16x16x32_bf16(af, b1, acc1, 0, 0, 0);
        }
        int n0 = h2h * 32;
        float as0 = as_[n0 + r],      ad0 = ad_[n0 + r];
        float as1 = as_[n0 + 16 + r], ad1 = ad_[n0 + 16 + r];
        float sacc[4], dacc[4];
#pragma unroll
        for (int i = 0; i < 4; i++) {
            int m = m0 + quad * 4 + i;
            h2[(size_t)m * 128 + n0 + r]      = __float2bfloat16(acc0[i]);
            h2[(size_t)m * 128 + n0 + 16 + r] = __float2bfloat16(acc1[i]);
            sacc[i] = acc0[i] * as0 + acc1[i] * as1;
            dacc[i] = acc0[i] * ad0 + acc1[i] * ad1;
        }
#pragma unroll
        for (int mask = 1; mask <= 8; mask <<= 1) {
#pragma unroll
            for (int i = 0; i < 4; i++) {
                sacc[i] += __shfl_xor(sacc[i], mask, 64);
                dacc[i] += __shfl_xor(dacc[i], mask, 64);
            }
        }
        if (r == 0) {
#pragma unroll
            for (int i = 0; i < 4; i++) {
                int m = m0 + quad * 4 + i;
                s2[m * 4 + h2h] = sacc[i]; d2[m * 4 + h2h] = dacc[i];
            }
        }
    }
}

// ---------------------------------------------------------------------------
// Layer-2 gather FUSED with layer-3 GEMM: node-per-wave; lane owns 2 h2
// channels. Edge weights computed INLINE from s2/d2.
// After gather+ELU, fused K=128->8 GEMM via 64-lane butterfly -> h3, s3, d3.
// ---------------------------------------------------------------------------
__global__ void gather_l2_g8(const int* __restrict__ elist, const int* __restrict__ offsets,
                             const float* __restrict__ s2, const float* __restrict__ d2,
                             const __hip_bfloat16* __restrict__ h,
                             const float* __restrict__ b,
                             const float* __restrict__ W3,
                             const float* __restrict__ a3s, const float* __restrict__ a3d,
                             __hip_bfloat16* __restrict__ h3,
                             float* __restrict__ s3, float* __restrict__ d3) {
    int gid = blockIdx.x * blockDim.x + threadIdx.x;
    if (gid >= NN * 64) return;
    int node = gid >> 6;
    int lane = gid & 63;
    int c0 = lane * 2;
    int hh = lane >> 4;
    int j0 = __builtin_amdgcn_readfirstlane(offsets[node]);
    int j1 = __builtin_amdgcn_readfirstlane(offsets[node + 1]);
    float dv = d2[node * 4 + hh];
    float den = 0.f, acc0 = 0.f, acc1 = 0.f;
    const unsigned short* hp = (const unsigned short*)h + c0;
    int j = j0;
    for (; j + 4 <= j1; j += 4) {
        int sA = elist[j], sB = elist[j+1], sC = elist[j+2], sD = elist[j+3];
        float eA = s2[sA * 4 + hh] + dv, eB = s2[sB * 4 + hh] + dv;
        float eC = s2[sC * 4 + hh] + dv, eD = s2[sD * 4 + hh] + dv;
        unsigned int vA = *(const unsigned int*)(hp + (size_t)sA * 128);
        unsigned int vB = *(const unsigned int*)(hp + (size_t)sB * 128);
        unsigned int vC = *(const unsigned int*)(hp + (size_t)sC * 128);
        unsigned int vD = *(const unsigned int*)(hp + (size_t)sD * 128);
        float wA = lrelu_exp(eA), wB = lrelu_exp(eB);
        float wC = lrelu_exp(eC), wD = lrelu_exp(eD);
        den += (wA + wB) + (wC + wD);
        acc0 += wA * us2f((unsigned short)vA) + wB * us2f((unsigned short)vB)
              + wC * us2f((unsigned short)vC) + wD * us2f((unsigned short)vD);
        acc1 += wA * us2f((unsigned short)(vA >> 16)) + wB * us2f((unsigned short)(vB >> 16))
              + wC * us2f((unsigned short)(vC >> 16)) + wD * us2f((unsigned short)(vD >> 16));
    }
    for (; j < j1; j++) {
        int sE = elist[j];
        float ww = lrelu_exp(s2[sE * 4 + hh] + dv);
        unsigned int v = *(const unsigned int*)(hp + (size_t)sE * 128);
        den += ww;
        acc0 += ww * us2f((unsigned short)v);
        acc1 += ww * us2f((unsigned short)(v >> 16));
    }
    float inv = 1.0f / den;
    float v0 = acc0 * inv + b[c0];
    float v1 = acc1 * inv + b[c0 + 1];
    v0 = v0 > 0.f ? v0 : (__expf(v0) - 1.0f);
    v1 = v1 > 0.f ? v1 : (__expf(v1) - 1.0f);
    // fused layer-3 GEMM: partial over this lane's 2 channels, butterfly-reduce
    float part[8];
#pragma unroll
    for (int c = 0; c < 8; c++) {
        float2 wv = *(const float2*)(W3 + c * 128 + c0);
        part[c] = v0 * wv.x + v1 * wv.y;
    }
#pragma unroll
    for (int mask = 1; mask < 64; mask <<= 1) {
#pragma unroll
        for (int c = 0; c < 8; c++) part[c] += __shfl_xor(part[c], mask, 64);
    }
    if (lane < 8) h3[(size_t)node * 8 + lane] = __float2bfloat16(part[lane]);
    if (lane == 0) {
        float sv = 0.f, dvv = 0.f;
#pragma unroll
        for (int c = 0; c < 8; c++) { sv += part[c] * a3s[c]; dvv += part[c] * a3d[c]; }
        s3[node] = sv; d3[node] = dvv;
    }
}

// ---------------------------------------------------------------------------
// Layer-3 gather: 8 lanes/node, lane owns 1 channel; weights computed inline.
// ---------------------------------------------------------------------------
__global__ void gather_l3(const int* __restrict__ elist, const int* __restrict__ offsets,
                          const float* __restrict__ s3, const float* __restrict__ d3,
                          const __hip_bfloat16* __restrict__ h,
                          const float* __restrict__ b,
                          __hip_bfloat16* __restrict__ act) {
    int gid = blockIdx.x * blockDim.x + threadIdx.x;
    if (gid >= NN * 8) return;
    int node = gid >> 3, t = gid & 7;
    int j0 = offsets[node], j1 = offsets[node + 1];
    float dnode = d3[node];
    float den = 0.f, acc = 0.f;
    const unsigned short* hp = (const unsigned short*)h + t;
    int j = j0;
    for (; j + 4 <= j1; j += 4) {
        int sA = elist[j], sB = elist[j+1], sC = elist[j+2], sD = elist[j+3];
        float wA = lrelu_exp(s3[sA] + dnode), wB = lrelu_exp(s3[sB] + dnode);
        float wC = lrelu_exp(s3[sC] + dnode), wD = lrelu_exp(s3[sD] + dnode);
        float xA = us2f(hp[(size_t)sA * 8]);
        float xB = us2f(hp[(size_t)sB * 8]);
        float xC = us2f(hp[(size_t)sC * 8]);
        float xD = us2f(hp[(size_t)sD * 8]);
        den += (wA + wB) + (wC + wD);
        acc += wA * xA + wB * xB + wC * xC + wD * xD;
    }
    for (; j < j1; j++) {
        int sE = elist[j];
        float w = lrelu_exp(s3[sE] + dnode);
        den += w;
        acc += w * us2f(hp[(size_t)sE * 8]);
    }
    float v = acc / den + b[t];
    v = v > 0.f ? v : (__expf(v) - 1.0f);
    act[(size_t)node * 8 + t] = __float2bfloat16(v);
}

// ---------------------------------------------------------------------------
// Final edge MLP: z[19] = [h3[src], h3[dst], ea, yr, qt] -> fc1(relu) -> fc2
// ---------------------------------------------------------------------------
__global__ void mlp_kernel(const int* __restrict__ ei,
                           const __hip_bfloat16* __restrict__ act3,
                           const float* __restrict__ ea,
                           const float* __restrict__ yr,
                           const float* __restrict__ qt,
                           const float* __restrict__ fc1w,
                           const float* __restrict__ fc1b,
                           const float* __restrict__ fc2w,
                           const float* __restrict__ fc2b,
                           float* __restrict__ outp) {
    __shared__ float w1[16 * 19], b1s[16], w2[16];
    for (int i = threadIdx.x; i < 16 * 19; i += blockDim.x) w1[i] = fc1w[i];
    if (threadIdx.x < 16) {
        b1s[threadIdx.x] = fc1b[threadIdx.x];
        w2[threadIdx.x] = fc2w[threadIdx.x];
    }
    __syncthreads();
    int e = blockIdx.x * blockDim.x + threadIdx.x;
    if (e >= EE) return;
    int src = ei[e], dst = ei[EE + e];
    short8 hs = *(const short8*)(act3 + (size_t)src * 8);
    short8 hd = *(const short8*)(act3 + (size_t)dst * 8);
    float z[19];
#pragma unroll
    for (int i = 0; i < 8; i++) z[i] = us2f((unsigned short)hs[i]);
#pragma unroll
    for (int i = 0; i < 8; i++) z[8 + i] = us2f((unsigned short)hd[i]);
    z[16] = ea[e]; z[17] = yr[e]; z[18] = qt[e];
    float acc2 = fc2b[0];
#pragma unroll
    for (int j = 0; j < 16; j++) {
        float a = b1s[j];
#pragma unroll
        for (int i = 0; i < 19; i++) a += z[i] * w1[j * 19 + i];
        a = a > 0.f ? a : 0.f;
        acc2 += a * w2[j];
    }
    outp[e] = acc2;
}

// ---------------------------------------------------------------------------
extern "C" void kernel_launch(void* const* d_in, const int* in_sizes, int n_in,
                              void* d_out, int out_size, void* d_ws, size_t ws_size,
                              hipStream_t stream) {
    const float* x    = (const float*)d_in[0];
    const int*   ei   = (const int*)d_in[1];
    const float* ea   = (const float*)d_in[2];
    const float* yr   = (const float*)d_in[3];
    const float* qt   = (const float*)d_in[4];
    const float* W1   = (const float*)d_in[5];
    const float* a1s  = (const float*)d_in[6];
    const float* a1d  = (const float*)d_in[7];
    const float* b1   = (const float*)d_in[8];
    const float* W2   = (const float*)d_in[9];
    const float* a2s  = (const float*)d_in[10];
    const float* a2d  = (const float*)d_in[11];
    const float* b2   = (const float*)d_in[12];
    const float* W3   = (const float*)d_in[13];
    const float* a3s  = (const float*)d_in[14];
    const float* a3d  = (const float*)d_in[15];
    const float* b3   = (const float*)d_in[16];
    const float* fc1w = (const float*)d_in[17];
    const float* fc1b = (const float*)d_in[18];
    const float* fc2w = (const float*)d_in[19];
    const float* fc2b = (const float*)d_in[20];
    float* outp = (float*)d_out;

    char* ws = (char*)d_ws;
    __hip_bfloat16* h_buf   = (__hip_bfloat16*)(ws);                 // N*512 bf16: h3
    __hip_bfloat16* act_buf = (__hip_bfloat16*)(ws + 51200000);      // N*512 bf16: xb / act3
    float* s_buf   = (float*)(ws + 102400000);                       // N*4 f32: s1/s2
    float* d_buf   = (float*)(ws + 103200000);                       // N*4 f32: d1/d2
    int*   deg     = (int*)  (ws + 104000000);                       // N ints
    int*   cursor  = (int*)  (ws + 104200000);                       // N ints (contiguous w/ deg)
    int*   offsets = (int*)  (ws + 104400000);                       // N+1 ints
    int*   elist   = (int*)  (ws + 104600016);                       // EP ints (1.8 MB)
    __hip_bfloat16* pw1 = (__hip_bfloat16*)(ws + 106400016);         // 512*128 bf16 packed
    __hip_bfloat16* pw2 = (__hip_bfloat16*)(ws + 106531088);         // 128*512 bf16 packed
    float* usd  = (float*)(ws + 106662160);                          // 8*128 f32 (4 KB)
    int*   bsum = (int*)  (ws + 106666256);                          // SCB ints
    float* welist = (float*)(ws + 106666512);                        // EP*4 f32 (7.2 MB), layer-1 only
    float* s3_buf = (float*)(ws + 113866512);                        // N f32
    float* d3_buf = (float*)(ws + 114071312);                        // N f32
    __hip_bfloat16* h2_buf = (__hip_bfloat16*)(ws + 114276112);      // N*128 bf16 (12.8 MB)
    __hip_bfloat16* xb = act_buf;                                    // N*128 bf16, dead after l1_fused

    // ---- prep (deg + weight pack + usd) + CSR scan ----
    hipMemsetAsync(deg, 0, 2 * NN * sizeof(int), stream);            // deg + cursor
    prep_kernel<<<DEGB + CVTB + 4, 256, 0, stream>>>(ei, deg, W1, W2, pw1, pw2, a1s, a1d, usd);
    scan1_kernel<<<SCB, 256, 0, stream>>>(deg, bsum);
    scan2_kernel<<<SCB, 256, 0, stream>>>(deg, bsum, offsets);
    cvtx_sd<<<(NN + 63) / 64, 256, 0, stream>>>(x, usd, xb, s_buf, d_buf, NN);
    fill_kernel<<<(EP + 255) / 256, 256, 0, stream>>>(ei, offsets, cursor, s_buf, d_buf,
                                                      elist, welist);

    // ---- Layers 1+2 fused: gather + bdiag GEMM (LDS) + l2 GEMM -> h2, s2/d2 ----
    l1_fused<<<NN / 16, 512, 0, stream>>>(elist, offsets, welist, xb, pw1, b1,
                                          pw2, a2s, a2d, h2_buf, s_buf, d_buf);

    // ---- Layer-2 gather (inline w) fused with layer-3 GEMM -> h3, s3, d3 ----
    gather_l2_g8<<<(NN * 64 + 255) / 256, 256, 0, stream>>>(
        elist, offsets, s_buf, d_buf, h2_buf, b2, W3, a3s, a3d,
        h_buf, s3_buf, d3_buf);

    // ---- Layer 3: gather (inline w) -> act3 in act_buf ----
    gather_l3<<<(NN * 8 + 255) / 256, 256, 0, stream>>>(
        elist, offsets, s3_buf, d3_buf, h_buf, b3, act_buf);

    // ---- Final edge MLP ----
    mlp_kernel<<<(EE + 255) / 256, 256, 0, stream>>>(ei, act_buf, ea, yr, qt,
                                                     fc1w, fc1b, fc2w, fc2b, outp);
}

// Round 14
// 273.511 us; speedup vs baseline: 1.2157x; 1.0008x over previous
//
#include <hip/hip_runtime.h>
#include <hip/hip_bf16.h>

#define NN 50000
#define EE 400000
#define EP 450000   // EE + NN self-loops

typedef __attribute__((ext_vector_type(8))) short short8;
typedef __attribute__((ext_vector_type(4))) float f32x4;
typedef __attribute__((ext_vector_type(2))) float f32x2;

__device__ __forceinline__ float us2f(unsigned short u) {
    unsigned int x = ((unsigned int)u) << 16;
    union { unsigned int i; float f; } c; c.i = x; return c.f;
}
__device__ __forceinline__ unsigned short f2bfu(float f) {   // f32 -> bf16 bits, RNE
    union { float f; unsigned int u; } c; c.f = f;
    unsigned int r = c.u + 0x7FFFu + ((c.u >> 16) & 1u);
    return (unsigned short)(r >> 16);
}
__device__ __forceinline__ unsigned int pack2bf(float lo, float hi) {
    return (unsigned int)f2bfu(lo) | ((unsigned int)f2bfu(hi) << 16);
}
__device__ __forceinline__ float lrelu_exp(float x) {
    x = x > 0.f ? x : 0.2f * x;
    return __expf(x);
}

// Packed MFMA-fragment index for a [M x K] bf16 matrix consumed as A (or B with
// n in place of m) by mfma_f32_16x16x32_bf16:
//   idx(m,k) = ((m>>4)*(K/32) + (k>>5))*512 + ((k&31)>>3)*128 + (m&15)*8 + (k&7)

// ---------------------------------------------------------------------------
// prep: fused deg histogram + W1/W2 f32->bf16 packed convert + usd precompute.
// ---------------------------------------------------------------------------
#define DEGB 1758
#define CVTB 512
__global__ void prep_kernel(const int* __restrict__ ei, int* __restrict__ deg,
                            const float* __restrict__ W1, const float* __restrict__ W2,
                            __hip_bfloat16* __restrict__ pw1, __hip_bfloat16* __restrict__ pw2,
                            const float* __restrict__ a1s, const float* __restrict__ a1d,
                            float* __restrict__ usd) {
    int b = blockIdx.x;
    if (b < DEGB) {
        int e = b * 256 + threadIdx.x;
        if (e >= EP) return;
        int dst = (e < EE) ? ei[EE + e] : e - EE;
        atomicAdd(&deg[dst], 1);
    } else if (b < DEGB + CVTB) {
        int i = (b - DEGB) * 256 + threadIdx.x;
        if (i < 65536) {
            int n = i >> 7, k = i & 127;   // K=128, NK=4
            int idx = ((n >> 4) * 4 + (k >> 5)) * 512 + ((k & 31) >> 3) * 128 + (n & 15) * 8 + (k & 7);
            pw1[idx] = __float2bfloat16(W1[i]);
        } else {
            int j = i - 65536;
            int n = j >> 9, k = j & 511;   // K=512, NK=16
            int idx = ((n >> 4) * 16 + (k >> 5)) * 512 + ((k & 31) >> 3) * 128 + (n & 15) * 8 + (k & 7);
            pw2[idx] = __float2bfloat16(W2[j]);
        }
    } else {
        int t = (b - DEGB - CVTB) * 256 + threadIdx.x;
        if (t >= 1024) return;
        int row = t >> 7, k = t & 127;
        int hh = row & 3;
        const float* av = (row < 4) ? (a1s + hh * 128) : (a1d + hh * 128);
        const float* wp = W1 + (size_t)(hh * 128) * 128 + k;
        float acc = 0.f;
        for (int c = 0; c < 128; c++) acc += av[c] * wp[(size_t)c * 128];
        usd[t] = acc;
    }
}

// ---------------------------------------------------------------------------
// Fused: x (f32) -> xb (bf16) convert + s1/d1 = x . usd.
// ---------------------------------------------------------------------------
__global__ void cvtx_sd(const float* __restrict__ x, const float* __restrict__ usd,
                        __hip_bfloat16* __restrict__ xb,
                        float* __restrict__ s, float* __restrict__ d, int M) {
    __shared__ float us_s[1024];
    for (int i = threadIdx.x; i < 1024; i += 256) us_s[i] = usd[i];
    __syncthreads();
    int wave = threadIdx.x >> 6, lane = threadIdx.x & 63;
    int m0 = blockIdx.x * 64 + wave * 16;
    int r = lane & 15, quad = lane >> 4;
    int am = m0 + r; if (am >= M) am = M - 1;
    const float* xp = x + (size_t)am * 128 + quad * 8;
    float xv[32];
#pragma unroll
    for (int kk = 0; kk < 4; kk++) {
        float4 a = *(const float4*)(xp + kk * 32);
        float4 bq = *(const float4*)(xp + kk * 32 + 4);
        xv[kk*8+0]=a.x;  xv[kk*8+1]=a.y;  xv[kk*8+2]=a.z;  xv[kk*8+3]=a.w;
        xv[kk*8+4]=bq.x; xv[kk*8+5]=bq.y; xv[kk*8+6]=bq.z; xv[kk*8+7]=bq.w;
        short8 o;
        o[0]=(short)f2bfu(a.x);  o[1]=(short)f2bfu(a.y);
        o[2]=(short)f2bfu(a.z);  o[3]=(short)f2bfu(a.w);
        o[4]=(short)f2bfu(bq.x); o[5]=(short)f2bfu(bq.y);
        o[6]=(short)f2bfu(bq.z); o[7]=(short)f2bfu(bq.w);
        *(short8*)(xb + (size_t)am * 128 + quad * 8 + kk * 32) = o;
    }
    float acc[8];
#pragma unroll
    for (int o = 0; o < 8; o++) {
        const float* up = us_s + o * 128 + quad * 8;
        float a = 0.f;
#pragma unroll
        for (int kk = 0; kk < 4; kk++)
#pragma unroll
            for (int j = 0; j < 8; j++) a += xv[kk*8+j] * up[kk*32+j];
        acc[o] = a;
    }
#pragma unroll
    for (int o = 0; o < 8; o++) {
        acc[o] += __shfl_xor(acc[o], 16, 64);
        acc[o] += __shfl_xor(acc[o], 32, 64);
    }
    int m = m0 + r;
    if (quad == 0 && m < M) {
#pragma unroll
        for (int hh = 0; hh < 4; hh++) { s[m*4+hh] = acc[hh]; d[m*4+hh] = acc[4+hh]; }
    }
}

// ---------------------------------------------------------------------------
// Two-level multi-block scan of deg -> offsets
// ---------------------------------------------------------------------------
#define SCB 49
__global__ void scan1_kernel(const int* __restrict__ deg, int* __restrict__ bsum) {
    __shared__ int red[256];
    int b = blockIdx.x, t = threadIdx.x;
    int base = b * 1024 + t * 4;
    int s = 0;
    if (base + 3 < NN) { int4 v = *(const int4*)(deg + base); s = v.x + v.y + v.z + v.w; }
    else { for (int i = base; i < NN; i++) s += deg[i]; }
    red[t] = s;
    __syncthreads();
    for (int off = 128; off > 0; off >>= 1) {
        if (t < off) red[t] += red[t + off];
        __syncthreads();
    }
    if (t == 0) bsum[b] = red[0];
}

__global__ void scan2_kernel(const int* __restrict__ deg, const int* __restrict__ bsum,
                             int* __restrict__ offsets) {
    __shared__ int lsum[256];
    int b = blockIdx.x, t = threadIdx.x;
    int boff = 0;
    for (int i = 0; i < b; i++) boff += bsum[i];
    int base = b * 1024 + t * 4;
    int4 v = {0, 0, 0, 0};
    if (base + 3 < NN) v = *(const int4*)(deg + base);
    else {
        if (base < NN)     v.x = deg[base];
        if (base + 1 < NN) v.y = deg[base + 1];
        if (base + 2 < NN) v.z = deg[base + 2];
        if (base + 3 < NN) v.w = deg[base + 3];
    }
    int s = v.x + v.y + v.z + v.w;
    lsum[t] = s;
    __syncthreads();
    for (int off = 1; off < 256; off <<= 1) {
        int val = (t >= off) ? lsum[t - off] : 0;
        __syncthreads();
        lsum[t] += val;
        __syncthreads();
    }
    int ex = boff + (t ? lsum[t - 1] : 0);
    if (base < NN)     offsets[base]     = ex;
    if (base + 1 < NN) offsets[base + 1] = ex + v.x;
    if (base + 2 < NN) offsets[base + 2] = ex + v.x + v.y;
    if (base + 3 < NN) offsets[base + 3] = ex + v.x + v.y + v.z;
    if (b == SCB - 1 && t == 255) offsets[NN] = boff + lsum[255];
}

// ---------------------------------------------------------------------------
// fill: CSR scatter + fused layer-1 edge weights (s1/d1 already computed).
// ---------------------------------------------------------------------------
__global__ void fill_kernel(const int* __restrict__ ei, const int* __restrict__ offsets,
                            int* __restrict__ cursor,
                            const float* __restrict__ s1, const float* __restrict__ d1,
                            int* __restrict__ elist, float* __restrict__ welist) {
    int e = blockIdx.x * blockDim.x + threadIdx.x;
    if (e >= EP) return;
    int src, dst;
    if (e < EE) { src = ei[e]; dst = ei[EE + e]; } else { src = dst = e - EE; }
    int pos = atomicAdd(&cursor[dst], 1);
    int j = offsets[dst] + pos;
    elist[j] = src;
    float4 sv = *(const float4*)(s1 + (size_t)src * 4);
    float4 dv = *(const float4*)(d1 + (size_t)dst * 4);
    float4 w;
    w.x = lrelu_exp(sv.x + dv.x);
    w.y = lrelu_exp(sv.y + dv.y);
    w.z = lrelu_exp(sv.z + dv.z);
    w.w = lrelu_exp(sv.w + dv.w);
    *(float4*)(welist + (size_t)j * 4) = w;
}

// ---------------------------------------------------------------------------
// Edge accumulate, packed over HEAD PAIRS (w01 = heads 0-1, w23 = heads 2-3):
// acc[0]=c0/h01, acc[1]=c0/h23, acc[2]=c1/h01, acc[3]=c1/h23.
// Plain vector C — clang emits v_pk_fma_f32 / v_pk_add_f32 on gfx950.
// ---------------------------------------------------------------------------
__device__ __forceinline__ void acc_edge(f32x2& den01, f32x2& den23, f32x2 (&acc)[4],
                                         float4 w, unsigned int x) {
    float x0 = us2f((unsigned short)x), x1 = us2f((unsigned short)(x >> 16));
    f32x2 w01; w01[0] = w.x; w01[1] = w.y;
    f32x2 w23; w23[0] = w.z; w23[1] = w.w;
    f32x2 x0s; x0s[0] = x0; x0s[1] = x0;
    f32x2 x1s; x1s[0] = x1; x1s[1] = x1;
    acc[0] += w01 * x0s;
    acc[1] += w23 * x0s;
    acc[2] += w01 * x1s;
    acc[3] += w23 * x1s;
    den01 += w01;
    den23 += w23;
}

// ---------------------------------------------------------------------------
// Layer-1+2 FUSED: gather + bdiag GEMM (LDS) + layer-2 GEMM. 512 thr = 8 waves.
// Phase 0: degree-sorted pairing (rank w with rank 15-w).
// Phase 1: dual-pointer gather, 4+4 edges in flight, packed-FMA accumulate,
//          normalized bf16 fragments -> LDS frag[] (swizzled, stride 520).
// Phase 2: wave w = (head w>>1, half w&1): 4 n-tiles x 4 MFMA from frag[],
//          ELU -> act1[] in LDS (packed K=512 fragment layout, same swizzle).
// Phase 3: waves 0-3 (= head): layer-2 GEMM from act1[] + packed W2,
//          h2 row-major -> global, fused s2/d2 butterfly epilogue.
// ---------------------------------------------------------------------------
__global__ void l1_fused(
        const int* __restrict__ elist, const int* __restrict__ offsets,
        const float* __restrict__ wl,
        const __hip_bfloat16* __restrict__ xb,
        const __hip_bfloat16* __restrict__ pW1,
        const float* __restrict__ b,
        const __hip_bfloat16* __restrict__ pW2,
        const float* __restrict__ as_, const float* __restrict__ ad_,
        __hip_bfloat16* __restrict__ h2,
        float* __restrict__ s2, float* __restrict__ d2) {
    __shared__ unsigned short frag[16 * 520];          // 16.6 KB
    __shared__ unsigned short act1[16 * 520];          // 16.6 KB
    int w = threadIdx.x >> 6, lane = threadIdx.x & 63;
    int m0 = blockIdx.x * 16;

    // ---- phase 0: degree-sorted pairing (redundant per wave, no barrier) ----
    int li = lane < 16 ? lane : 15;
    int mydeg = offsets[m0 + li + 1] - offsets[m0 + li];
    int rank = 0;
#pragma unroll
    for (int jj = 0; jj < 16; jj++) {
        int od = __shfl(mydeg, jj, 64);
        rank += (od < mydeg) || (od == mydeg && jj < li);
    }
    unsigned long long balA = __ballot(lane < 16 && rank == w);
    unsigned long long balB = __ballot(lane < 16 && rank == 15 - w);
    int iA = (int)__builtin_ctzll(balA);
    int iB = (int)__builtin_ctzll(balB);
    int nodeA = m0 + iA, nodeB = m0 + iB;

    int ja  = __builtin_amdgcn_readfirstlane(offsets[nodeA]);
    int jA1 = __builtin_amdgcn_readfirstlane(offsets[nodeA + 1]);
    int jb  = __builtin_amdgcn_readfirstlane(offsets[nodeB]);
    int jB1 = __builtin_amdgcn_readfirstlane(offsets[nodeB + 1]);

    f32x2 dA01, dA23, dB01, dB23;
    dA01[0]=0.f; dA01[1]=0.f; dA23[0]=0.f; dA23[1]=0.f;
    dB01[0]=0.f; dB01[1]=0.f; dB23[0]=0.f; dB23[1]=0.f;
    f32x2 aA[4], aB[4];
#pragma unroll
    for (int h = 0; h < 4; h++) {
        aA[h][0]=0.f; aA[h][1]=0.f;
        aB[h][0]=0.f; aB[h][1]=0.f;
    }
    const unsigned short* xp = (const unsigned short*)xb + lane * 2;
    const float4* wl4 = (const float4*)wl;

    // 4+4 deep-pipelined main loop: 8 x-loads in flight
    while (ja + 4 <= jA1 && jb + 4 <= jB1) {
        int sA0 = elist[ja],   sA1 = elist[ja+1], sA2 = elist[ja+2], sA3 = elist[ja+3];
        int sB0 = elist[jb],   sB1 = elist[jb+1], sB2 = elist[jb+2], sB3 = elist[jb+3];
        float4 wA0 = wl4[ja],   wA1 = wl4[ja+1], wA2 = wl4[ja+2], wA3 = wl4[ja+3];
        float4 wB0 = wl4[jb],   wB1 = wl4[jb+1], wB2 = wl4[jb+2], wB3 = wl4[jb+3];
        unsigned int xA0 = *(const unsigned int*)(xp + (size_t)sA0 * 128);
        unsigned int xA1 = *(const unsigned int*)(xp + (size_t)sA1 * 128);
        unsigned int xA2 = *(const unsigned int*)(xp + (size_t)sA2 * 128);
        unsigned int xA3 = *(const unsigned int*)(xp + (size_t)sA3 * 128);
        unsigned int xB0 = *(const unsigned int*)(xp + (size_t)sB0 * 128);
        unsigned int xB1 = *(const unsigned int*)(xp + (size_t)sB1 * 128);
        unsigned int xB2 = *(const unsigned int*)(xp + (size_t)sB2 * 128);
        unsigned int xB3 = *(const unsigned int*)(xp + (size_t)sB3 * 128);
        acc_edge(dA01, dA23, aA, wA0, xA0); acc_edge(dA01, dA23, aA, wA1, xA1);
        acc_edge(dA01, dA23, aA, wA2, xA2); acc_edge(dA01, dA23, aA, wA3, xA3);
        acc_edge(dB01, dB23, aB, wB0, xB0); acc_edge(dB01, dB23, aB, wB1, xB1);
        acc_edge(dB01, dB23, aB, wB2, xB2); acc_edge(dB01, dB23, aB, wB3, xB3);
        ja += 4; jb += 4;
    }
    // 2+2 drain
    while (ja + 2 <= jA1 && jb + 2 <= jB1) {
        int sA0 = elist[ja], sA1 = elist[ja + 1];
        int sB0 = elist[jb], sB1 = elist[jb + 1];
        float4 wA0 = wl4[ja], wA1 = wl4[ja + 1];
        float4 wB0 = wl4[jb], wB1 = wl4[jb + 1];
        unsigned int xA0 = *(const unsigned int*)(xp + (size_t)sA0 * 128);
        unsigned int xA1 = *(const unsigned int*)(xp + (size_t)sA1 * 128);
        unsigned int xB0 = *(const unsigned int*)(xp + (size_t)sB0 * 128);
        unsigned int xB1 = *(const unsigned int*)(xp + (size_t)sB1 * 128);
        acc_edge(dA01, dA23, aA, wA0, xA0); acc_edge(dA01, dA23, aA, wA1, xA1);
        acc_edge(dB01, dB23, aB, wB0, xB0); acc_edge(dB01, dB23, aB, wB1, xB1);
        ja += 2; jb += 2;
    }
    while (ja + 2 <= jA1) {
        int sA0 = elist[ja], sA1 = elist[ja + 1];
        float4 wA0 = wl4[ja], wA1 = wl4[ja + 1];
        unsigned int xA0 = *(const unsigned int*)(xp + (size_t)sA0 * 128);
        unsigned int xA1 = *(const unsigned int*)(xp + (size_t)sA1 * 128);
        acc_edge(dA01, dA23, aA, wA0, xA0); acc_edge(dA01, dA23, aA, wA1, xA1);
        ja += 2;
    }
    while (jb + 2 <= jB1) {
        int sB0 = elist[jb], sB1 = elist[jb + 1];
        float4 wB0 = wl4[jb], wB1 = wl4[jb + 1];
        unsigned int xB0 = *(const unsigned int*)(xp + (size_t)sB0 * 128);
        unsigned int xB1 = *(const unsigned int*)(xp + (size_t)sB1 * 128);
        acc_edge(dB01, dB23, aB, wB0, xB0); acc_edge(dB01, dB23, aB, wB1, xB1);
        jb += 2;
    }
    if (ja < jA1) {
        int sA0 = elist[ja]; float4 wA0 = wl4[ja];
        unsigned int xA0 = *(const unsigned int*)(xp + (size_t)sA0 * 128);
        acc_edge(dA01, dA23, aA, wA0, xA0);
    }
    if (jb < jB1) {
        int sB0 = elist[jb]; float4 wB0 = wl4[jb];
        unsigned int xB0 = *(const unsigned int*)(xp + (size_t)sB0 * 128);
        acc_edge(dB01, dB23, aB, wB0, xB0);
    }

    // store both nodes' normalized fragments to LDS (swizzled)
    // acc layout: [0]=c0/h01 [1]=c0/h23 [2]=c1/h01 [3]=c1/h23
    {
        int c0 = lane * 2;
        int fq = c0 >> 5;
        int sub = (c0 & 31) >> 3;
        unsigned int* f32p = (unsigned int*)frag;
        int base0 = fq * 260 + sub * 64 + (c0 & 7) / 2;   // uint units
        {
            int rowp = iA ^ (sub << 2);
            int base = base0 + rowp * 4;
            float i0 = 1.f/dA01[0], i1 = 1.f/dA01[1], i2 = 1.f/dA23[0], i3 = 1.f/dA23[1];
            f32p[base]            = pack2bf(aA[0][0]*i0, aA[2][0]*i0);   // head0: c0,c1
            f32p[base + 4 * 260]  = pack2bf(aA[0][1]*i1, aA[2][1]*i1);   // head1
            f32p[base + 8 * 260]  = pack2bf(aA[1][0]*i2, aA[3][0]*i2);   // head2
            f32p[base + 12 * 260] = pack2bf(aA[1][1]*i3, aA[3][1]*i3);   // head3
        }
        {
            int rowp = iB ^ (sub << 2);
            int base = base0 + rowp * 4;
            float i0 = 1.f/dB01[0], i1 = 1.f/dB01[1], i2 = 1.f/dB23[0], i3 = 1.f/dB23[1];
            f32p[base]            = pack2bf(aB[0][0]*i0, aB[2][0]*i0);
            f32p[base + 4 * 260]  = pack2bf(aB[0][1]*i1, aB[2][1]*i1);
            f32p[base + 8 * 260]  = pack2bf(aB[1][0]*i2, aB[3][0]*i2);
            f32p[base + 12 * 260] = pack2bf(aB[1][1]*i3, aB[3][1]*i3);
        }
    }
    __syncthreads();

    // ---- phase 2: block-diagonal GEMM from LDS -> act1 in LDS ----
    int hh = w >> 1, half = w & 1;
    int r = lane & 15, quad = lane >> 4;
    int lsub = lane >> 4, lrow = lane & 15;
    int prow = lrow ^ (lsub << 2);
    {
        const unsigned short* fb = frag + lsub * 128 + prow * 8;
        short8 afrag[4];
#pragma unroll
        for (int kk = 0; kk < 4; kk++)
            afrag[kk] = *(const short8*)(fb + (hh * 4 + kk) * 520);
#pragma unroll
        for (int t = 0; t < 4; t++) {
            int nb = half * 64 + t * 16;
            const __hip_bfloat16* bp = pW1 + ((size_t)(hh * 8 + (nb >> 4)) * 4) * 512 + lane * 8;
            f32x4 acc = {0.f, 0.f, 0.f, 0.f};
#pragma unroll
            for (int kk = 0; kk < 4; kk++) {
                short8 bfr = *(const short8*)(bp + kk * 512);
                acc = __builtin_amdgcn_mfma_f32_16x16x32_bf16(afrag[kk], bfr, acc, 0, 0, 0);
            }
            int n0 = hh * 128 + nb;
            float bias = b[n0 + r];
            int kk2 = (n0 + r) >> 5;                 // k-tile in K=512 layout
            int sub2 = ((nb & 16) + r) >> 3;         // k-subgroup
#pragma unroll
            for (int i = 0; i < 4; i++) {
                float v = acc[i] + bias;
                v = v > 0.f ? v : (__expf(v) - 1.0f);
                int rowp2 = (quad * 4 + i) ^ (sub2 << 2);
                act1[kk2 * 520 + sub2 * 128 + rowp2 * 8 + (r & 7)] = f2bfu(v);
            }
        }
    }
    __syncthreads();

    // ---- phase 3: layer-2 GEMM from act1 LDS (waves 0-3, wave = head) ----
    if (w < 4) {
        int h2h = w;                                 // head 0..3
        const __hip_bfloat16* bp0 = pW2 + (size_t)(h2h * 2) * 16 * 512 + lane * 8;
        const __hip_bfloat16* bp1 = bp0 + 16 * 512;
        const unsigned short* ab = act1 + lsub * 128 + prow * 8;
        f32x4 acc0 = {0.f, 0.f, 0.f, 0.f}, acc1 = {0.f, 0.f, 0.f, 0.f};
#pragma unroll
        for (int kk = 0; kk < 16; kk++) {
            short8 af = *(const short8*)(ab + kk * 520);
            short8 b0 = *(const short8*)(bp0 + kk * 512);
            short8 b1 = *(const short8*)(bp1 + kk * 512);
            acc0 = __builtin_amdgcn_mfma_f32_16x16x32_bf16(af, b0, acc0, 0, 0, 0);
            acc1 = __builtin_amdgcn_mfma_f32_16x16x32_bf16(af, b1, acc1, 0, 0, 0);
        }
        int n0 = h2h * 32;
        float as0 = as_[n0 + r],      ad0 = ad_[n0 + r];
        float as1 = as_[n0 + 16 + r], ad1 = ad_[n0 + 16 + r];
        float sacc[4], dacc[4];
#pragma unroll
        for (int i = 0; i < 4; i++) {
            int m = m0 + quad * 4 + i;
            h2[(size_t)m * 128 + n0 + r]      = __float2bfloat16(acc0[i]);
            h2[(size_t)m * 128 + n0 + 16 + r] = __float2bfloat16(acc1[i]);
            sacc[i] = acc0[i] * as0 + acc1[i] * as1;
            dacc[i] = acc0[i] * ad0 + acc1[i] * ad1;
        }
#pragma unroll
        for (int mask = 1; mask <= 8; mask <<= 1) {
#pragma unroll
            for (int i = 0; i < 4; i++) {
                sacc[i] += __shfl_xor(sacc[i], mask, 64);
                dacc[i] += __shfl_xor(dacc[i], mask, 64);
            }
        }
        if (r == 0) {
#pragma unroll
            for (int i = 0; i < 4; i++) {
                int m = m0 + quad * 4 + i;
                s2[m * 4 + h2h] = sacc[i]; d2[m * 4 + h2h] = dacc[i];
            }
        }
    }
}

// ---------------------------------------------------------------------------
// Layer-2 gather FUSED with layer-3 GEMM: node-per-wave; lane owns 2 h2
// channels. Edge weights computed INLINE from s2/d2.
// L3 GEMM uses recursive-halving reduce (34 ops vs 96-shfl butterfly):
// masks 32/16/8 split outputs 8->4->2->1, masks 4/2/1 finish the group sum;
// lane's group (bits 5:4:3) maps to output o.
// ---------------------------------------------------------------------------
__global__ void gather_l2_g8(const int* __restrict__ elist, const int* __restrict__ offsets,
                             const float* __restrict__ s2, const float* __restrict__ d2,
                             const __hip_bfloat16* __restrict__ h,
                             const float* __restrict__ b,
                             const float* __restrict__ W3,
                             const float* __restrict__ a3s, const float* __restrict__ a3d,
                             __hip_bfloat16* __restrict__ h3,
                             float* __restrict__ s3, float* __restrict__ d3) {
    int gid = blockIdx.x * blockDim.x + threadIdx.x;
    if (gid >= NN * 64) return;
    int node = gid >> 6;
    int lane = gid & 63;
    int c0 = lane * 2;
    int hh = lane >> 4;
    int j0 = __builtin_amdgcn_readfirstlane(offsets[node]);
    int j1 = __builtin_amdgcn_readfirstlane(offsets[node + 1]);
    float dv = d2[node * 4 + hh];
    float den = 0.f, acc0 = 0.f, acc1 = 0.f;
    const unsigned short* hp = (const unsigned short*)h + c0;
    int j = j0;
    for (; j + 4 <= j1; j += 4) {
        int sA = elist[j], sB = elist[j+1], sC = elist[j+2], sD = elist[j+3];
        float eA = s2[sA * 4 + hh] + dv, eB = s2[sB * 4 + hh] + dv;
        float eC = s2[sC * 4 + hh] + dv, eD = s2[sD * 4 + hh] + dv;
        unsigned int vA = *(const unsigned int*)(hp + (size_t)sA * 128);
        unsigned int vB = *(const unsigned int*)(hp + (size_t)sB * 128);
        unsigned int vC = *(const unsigned int*)(hp + (size_t)sC * 128);
        unsigned int vD = *(const unsigned int*)(hp + (size_t)sD * 128);
        float wA = lrelu_exp(eA), wB = lrelu_exp(eB);
        float wC = lrelu_exp(eC), wD = lrelu_exp(eD);
        den += (wA + wB) + (wC + wD);
        acc0 += wA * us2f((unsigned short)vA) + wB * us2f((unsigned short)vB)
              + wC * us2f((unsigned short)vC) + wD * us2f((unsigned short)vD);
        acc1 += wA * us2f((unsigned short)(vA >> 16)) + wB * us2f((unsigned short)(vB >> 16))
              + wC * us2f((unsigned short)(vC >> 16)) + wD * us2f((unsigned short)(vD >> 16));
    }
    for (; j < j1; j++) {
        int sE = elist[j];
        float ww = lrelu_exp(s2[sE * 4 + hh] + dv);
        unsigned int v = *(const unsigned int*)(hp + (size_t)sE * 128);
        den += ww;
        acc0 += ww * us2f((unsigned short)v);
        acc1 += ww * us2f((unsigned short)(v >> 16));
    }
    float inv = 1.0f / den;
    float v0 = acc0 * inv + b[c0];
    float v1 = acc1 * inv + b[c0 + 1];
    v0 = v0 > 0.f ? v0 : (__expf(v0) - 1.0f);
    v1 = v1 > 0.f ? v1 : (__expf(v1) - 1.0f);
    // fused layer-3 GEMM: partial over this lane's 2 channels
    float part[8];
#pragma unroll
    for (int c = 0; c < 8; c++) {
        float2 wv = *(const float2*)(W3 + c * 128 + c0);
        part[c] = v0 * wv.x + v1 * wv.y;
    }
    // recursive-halving reduce-scatter: 8 -> 4 -> 2 -> 1 values
    float t4[4];
#pragma unroll
    for (int i = 0; i < 4; i++) {
        float send = (lane & 32) ? part[i] : part[4 + i];
        float keep = (lane & 32) ? part[4 + i] : part[i];
        t4[i] = keep + __shfl_xor(send, 32, 64);
    }
    float t2[2];
#pragma unroll
    for (int i = 0; i < 2; i++) {
        float send = (lane & 16) ? t4[i] : t4[2 + i];
        float keep = (lane & 16) ? t4[2 + i] : t4[i];
        t2[i] = keep + __shfl_xor(send, 16, 64);
    }
    float gv;
    {
        float send = (lane & 8) ? t2[0] : t2[1];
        float keep = (lane & 8) ? t2[1] : t2[0];
        gv = keep + __shfl_xor(send, 8, 64);
    }
    gv += __shfl_xor(gv, 4, 64);
    gv += __shfl_xor(gv, 2, 64);
    gv += __shfl_xor(gv, 1, 64);
    int o = ((lane >> 5) & 1) * 4 + ((lane >> 4) & 1) * 2 + ((lane >> 3) & 1);
    if ((lane & 7) == 0) h3[(size_t)node * 8 + o] = __float2bfloat16(gv);
    // s3/d3: sum over the 8 groups (masks 8/16/32 only -> each group once)
    float cs = gv * a3s[o];
    float cd = gv * a3d[o];
    cs += __shfl_xor(cs, 8, 64);  cd += __shfl_xor(cd, 8, 64);
    cs += __shfl_xor(cs, 16, 64); cd += __shfl_xor(cd, 16, 64);
    cs += __shfl_xor(cs, 32, 64); cd += __shfl_xor(cd, 32, 64);
    if (lane == 0) { s3[node] = cs; d3[node] = cd; }
}

// ---------------------------------------------------------------------------
// Layer-3 gather: 8 lanes/node, lane owns 1 channel; weights computed inline.
// ---------------------------------------------------------------------------
__global__ void gather_l3(const int* __restrict__ elist, const int* __restrict__ offsets,
                          const float* __restrict__ s3, const float* __restrict__ d3,
                          const __hip_bfloat16* __restrict__ h,
                          const float* __restrict__ b,
                          __hip_bfloat16* __restrict__ act) {
    int gid = blockIdx.x * blockDim.x + threadIdx.x;
    if (gid >= NN * 8) return;
    int node = gid >> 3, t = gid & 7;
    int j0 = offsets[node], j1 = offsets[node + 1];
    float dnode = d3[node];
    float den = 0.f, acc = 0.f;
    const unsigned short* hp = (const unsigned short*)h + t;
    int j = j0;
    for (; j + 4 <= j1; j += 4) {
        int sA = elist[j], sB = elist[j+1], sC = elist[j+2], sD = elist[j+3];
        float wA = lrelu_exp(s3[sA] + dnode), wB = lrelu_exp(s3[sB] + dnode);
        float wC = lrelu_exp(s3[sC] + dnode), wD = lrelu_exp(s3[sD] + dnode);
        float xA = us2f(hp[(size_t)sA * 8]);
        float xB = us2f(hp[(size_t)sB * 8]);
        float xC = us2f(hp[(size_t)sC * 8]);
        float xD = us2f(hp[(size_t)sD * 8]);
        den += (wA + wB) + (wC + wD);
        acc += wA * xA + wB * xB + wC * xC + wD * xD;
    }
    for (; j < j1; j++) {
        int sE = elist[j];
        float w = lrelu_exp(s3[sE] + dnode);
        den += w;
        acc += w * us2f(hp[(size_t)sE * 8]);
    }
    float v = acc / den + b[t];
    v = v > 0.f ? v : (__expf(v) - 1.0f);
    act[(size_t)node * 8 + t] = __float2bfloat16(v);
}

// ---------------------------------------------------------------------------
// Final edge MLP: z[19] = [h3[src], h3[dst], ea, yr, qt] -> fc1(relu) -> fc2
// ---------------------------------------------------------------------------
__global__ void mlp_kernel(const int* __restrict__ ei,
                           const __hip_bfloat16* __restrict__ act3,
                           const float* __restrict__ ea,
                           const float* __restrict__ yr,
                           const float* __restrict__ qt,
                           const float* __restrict__ fc1w,
                           const float* __restrict__ fc1b,
                           const float* __restrict__ fc2w,
                           const float* __restrict__ fc2b,
                           float* __restrict__ outp) {
    __shared__ float w1[16 * 19], b1s[16], w2[16];
    for (int i = threadIdx.x; i < 16 * 19; i += blockDim.x) w1[i] = fc1w[i];
    if (threadIdx.x < 16) {
        b1s[threadIdx.x] = fc1b[threadIdx.x];
        w2[threadIdx.x] = fc2w[threadIdx.x];
    }
    __syncthreads();
    int e = blockIdx.x * blockDim.x + threadIdx.x;
    if (e >= EE) return;
    int src = ei[e], dst = ei[EE + e];
    short8 hs = *(const short8*)(act3 + (size_t)src * 8);
    short8 hd = *(const short8*)(act3 + (size_t)dst * 8);
    float z[19];
#pragma unroll
    for (int i = 0; i < 8; i++) z[i] = us2f((unsigned short)hs[i]);
#pragma unroll
    for (int i = 0; i < 8; i++) z[8 + i] = us2f((unsigned short)hd[i]);
    z[16] = ea[e]; z[17] = yr[e]; z[18] = qt[e];
    float acc2 = fc2b[0];
#pragma unroll
    for (int j = 0; j < 16; j++) {
        float a = b1s[j];
#pragma unroll
        for (int i = 0; i < 19; i++) a += z[i] * w1[j * 19 + i];
        a = a > 0.f ? a : 0.f;
        acc2 += a * w2[j];
    }
    outp[e] = acc2;
}

// ---------------------------------------------------------------------------
extern "C" void kernel_launch(void* const* d_in, const int* in_sizes, int n_in,
                              void* d_out, int out_size, void* d_ws, size_t ws_size,
                              hipStream_t stream) {
    const float* x    = (const float*)d_in[0];
    const int*   ei   = (const int*)d_in[1];
    const float* ea   = (const float*)d_in[2];
    const float* yr   = (const float*)d_in[3];
    const float* qt   = (const float*)d_in[4];
    const float* W1   = (const float*)d_in[5];
    const float* a1s  = (const float*)d_in[6];
    const float* a1d  = (const float*)d_in[7];
    const float* b1   = (const float*)d_in[8];
    const float* W2   = (const float*)d_in[9];
    const float* a2s  = (const float*)d_in[10];
    const float* a2d  = (const float*)d_in[11];
    const float* b2   = (const float*)d_in[12];
    const float* W3   = (const float*)d_in[13];
    const float* a3s  = (const float*)d_in[14];
    const float* a3d  = (const float*)d_in[15];
    const float* b3   = (const float*)d_in[16];
    const float* fc1w = (const float*)d_in[17];
    const float* fc1b = (const float*)d_in[18];
    const float* fc2w = (const float*)d_in[19];
    const float* fc2b = (const float*)d_in[20];
    float* outp = (float*)d_out;

    char* ws = (char*)d_ws;
    __hip_bfloat16* h_buf   = (__hip_bfloat16*)(ws);                 // N*512 bf16: h3
    __hip_bfloat16* act_buf = (__hip_bfloat16*)(ws + 51200000);      // N*512 bf16: xb / act3
    float* s_buf   = (float*)(ws + 102400000);                       // N*4 f32: s1/s2
    float* d_buf   = (float*)(ws + 103200000);                       // N*4 f32: d1/d2
    int*   deg     = (int*)  (ws + 104000000);                       // N ints
    int*   cursor  = (int*)  (ws + 104200000);                       // N ints (contiguous w/ deg)
    int*   offsets = (int*)  (ws + 104400000);                       // N+1 ints
    int*   elist   = (int*)  (ws + 104600016);                       // EP ints (1.8 MB)
    __hip_bfloat16* pw1 = (__hip_bfloat16*)(ws + 106400016);         // 512*128 bf16 packed
    __hip_bfloat16* pw2 = (__hip_bfloat16*)(ws + 106531088);         // 128*512 bf16 packed
    float* usd  = (float*)(ws + 106662160);                          // 8*128 f32 (4 KB)
    int*   bsum = (int*)  (ws + 106666256);                          // SCB ints
    float* welist = (float*)(ws + 106666512);                        // EP*4 f32 (7.2 MB), layer-1 only
    float* s3_buf = (float*)(ws + 113866512);                        // N f32
    float* d3_buf = (float*)(ws + 114071312);                        // N f32
    __hip_bfloat16* h2_buf = (__hip_bfloat16*)(ws + 114276112);      // N*128 bf16 (12.8 MB)
    __hip_bfloat16* xb = act_buf;                                    // N*128 bf16, dead after l1_fused

    // ---- prep (deg + weight pack + usd) + CSR scan ----
    hipMemsetAsync(deg, 0, 2 * NN * sizeof(int), stream);            // deg + cursor
    prep_kernel<<<DEGB + CVTB + 4, 256, 0, stream>>>(ei, deg, W1, W2, pw1, pw2, a1s, a1d, usd);
    scan1_kernel<<<SCB, 256, 0, stream>>>(deg, bsum);
    scan2_kernel<<<SCB, 256, 0, stream>>>(deg, bsum, offsets);
    cvtx_sd<<<(NN + 63) / 64, 256, 0, stream>>>(x, usd, xb, s_buf, d_buf, NN);
    fill_kernel<<<(EP + 255) / 256, 256, 0, stream>>>(ei, offsets, cursor, s_buf, d_buf,
                                                      elist, welist);

    // ---- Layers 1+2 fused: gather + bdiag GEMM (LDS) + l2 GEMM -> h2, s2/d2 ----
    l1_fused<<<NN / 16, 512, 0, stream>>>(elist, offsets, welist, xb, pw1, b1,
                                          pw2, a2s, a2d, h2_buf, s_buf, d_buf);

    // ---- Layer-2 gather (inline w) fused with layer-3 GEMM -> h3, s3, d3 ----
    gather_l2_g8<<<(NN * 64 + 255) / 256, 256, 0, stream>>>(
        elist, offsets, s_buf, d_buf, h2_buf, b2, W3, a3s, a3d,
        h_buf, s3_buf, d3_buf);

    // ---- Layer 3: gather (inline w) -> act3 in act_buf ----
    gather_l3<<<(NN * 8 + 255) / 256, 256, 0, stream>>>(
        elist, offsets, s3_buf, d3_buf, h_buf, b3, act_buf);

    // ---- Final edge MLP ----
    mlp_kernel<<<(EE + 255) / 256, 256, 0, stream>>>(ei, act_buf, ea, yr, qt,
                                                     fc1w, fc1b, fc2w, fc2b, outp);
}